// Round 8
// baseline (668.824 us; speedup 1.0000x reference)
//
#include <hip/hip_runtime.h>

typedef unsigned short u16;
typedef unsigned int   u32;
typedef unsigned long long u64;

typedef __attribute__((ext_vector_type(8))) short bf8_t;   // 8 x bf16
typedef __attribute__((ext_vector_type(4))) float f4_t;

#define DEVI __device__ __forceinline__
#define MFMA16(a,b,c) __builtin_amdgcn_mfma_f32_16x16x32_bf16((a),(b),(c),0,0,0)

#define BB   2
#define TT   2048
#define HIDN 1024
#define L0f  (-3.4657359027997265f)   // ln(1/32)
#define DLf  (-0.3960841031714215f)   // (ln(1/512)-ln(1/32))/7
#define SCL  (0.08838834764831845f)   // 128^-0.5

DEVI u16 f2b(float f) {                 // f32 -> bf16 RNE
    u32 u = __float_as_uint(f);
    u += 0x7FFFu + ((u >> 16) & 1u);
    return (u16)(u >> 16);
}
DEVI float b2f(u16 u) { return __uint_as_float(((u32)u) << 16); }

// async global->LDS, 16B per lane; lds dest = wave-uniform base + lane*16
DEVI void gll16(const void* g, void* l) {
    __builtin_amdgcn_global_load_lds((const __attribute__((address_space(1))) void*)g,
                                     (__attribute__((address_space(3))) void*)l, 16, 0, 0);
}

// ------- packed xPos tables (blocks 0..4095) + gamma tables (blocks 4096..4161) -------
__global__ __launch_bounds__(256) void k_tables(u32* __restrict__ cqp, u32* __restrict__ ckp,
                                                float* __restrict__ gt, float* __restrict__ gk) {
    int bx = blockIdx.x;
    if (bx >= 4096) {                                // gamma tables
        int i = (bx - 4096) * 256 + threadIdx.x;     // 16896 entries
        if (i < 16384) {                             // gtab[h][t] = g^(2047-t)
            int h = i >> 11, t = i & 2047;
            float lg2 = log2f(1.f - expf(L0f + (float)h * DLf));
            gt[i] = exp2f((float)(2047 - t) * lg2);
        } else {                                     // gk[h][d] = g^-d
            int idx = i - 16384;                     // 512 entries
            int h = idx >> 6, d = idx & 63;
            float lg2 = log2f(1.f - expf(L0f + (float)h * DLf));
            gk[idx] = exp2f(-(float)d * lg2);
        }
        return;
    }
    int idx = bx * 256 + threadIdx.x;                // t*512 + m
    int t = idx >> 9, m = idx & 511;
    float base = (2.f * (float)m + 409.6f) * (1.f / 1433.6f);
    float s = exp2f(log2f(base) * ((float)t * (1.f / 512.f)));
    float invf = exp2f(-(float)m * (13.287712379549449f / 512.f)); // 10000^{-m/512}
    float sn, cs;
    sincosf((float)t * invf, &sn, &cs);
    int h = m >> 6;
    float lg2h = log2f(1.f - expf(L0f + (float)h * DLf));
    float qf = s * SCL * exp2f((float)(t & 63) * lg2h);
    cqp[idx] = (u32)f2b(cs * qf) | ((u32)f2b(sn * qf) << 16);
    float is = 1.f / s;
    ckp[idx] = (u32)f2b(cs * is) | ((u32)f2b(sn * is) << 16);
}

// ---------------- f32 -> bf16 convert (x) ----------------
__global__ __launch_bounds__(256) void k_cvt(const float* __restrict__ in, u16* __restrict__ out) {
    int i = blockIdx.x * 256 + threadIdx.x;
    float4 v = ((const float4*)in)[i];
    u64 pk = (u64)f2b(v.x) | ((u64)f2b(v.y) << 16) | ((u64)f2b(v.z) << 32) | ((u64)f2b(v.w) << 48);
    ((u64*)out)[i] = pk;
}

// ------- fused transpose+convert of all 3 weights: in[R][C] f32 -> out[C][R] bf16 -------
__global__ __launch_bounds__(256) void k_tposeF(const float* __restrict__ Wqkv,
                                                const float* __restrict__ Wg,
                                                const float* __restrict__ Wp,
                                                u16* __restrict__ oQ, u16* __restrict__ oG,
                                                u16* __restrict__ oP) {
    __shared__ float tile[32][33];
    int bx = blockIdx.x;
    const float* in; u16* out; int R, C, cx, ry;
    if (bx < 4096)      { in = Wqkv; out = oQ; R = 1024; C = 4096; cx = bx & 127;        ry = bx >> 7; }
    else if (bx < 6144) { int b2 = bx - 4096; in = Wg; out = oG; R = 1024; C = 2048; cx = b2 & 63; ry = b2 >> 6; }
    else                { int b2 = bx - 6144; in = Wp; out = oP; R = 2048; C = 1024; cx = b2 & 31; ry = b2 >> 5; }
    int c0 = cx * 32, r0 = ry * 32;
    int tx = threadIdx.x, ty = threadIdx.y;          // (32,8)
#pragma unroll
    for (int i = 0; i < 4; i++)
        tile[ty * 4 + i][tx] = in[(size_t)(r0 + ty * 4 + i) * C + c0 + tx];
    __syncthreads();
#pragma unroll
    for (int i = 0; i < 4; i++)
        out[(size_t)(c0 + ty * 4 + i) * R + r0 + tx] = f2b(tile[tx][ty * 4 + i]);
}

// =============== 256x256 8-wave, BK=32, dbuf 64KB (2 blocks/CU), GEMM1 ===============
DEVI void stage32(const u16* __restrict__ A, const u16* __restrict__ B,
                  int m0, int n0, int kt, char* buf, int lane, int wid) {
#pragma unroll
    for (int q = 0; q < 2; q++) {
        int flat = (wid * 2 + q) * 1024 + lane * 16;
        int row = flat >> 6, byt = (flat & 63) ^ ((row & 3) << 4);
        gll16((const char*)A + (size_t)(m0 + row) * 2048 + kt * 64 + byt,
              buf + (wid * 2 + q) * 1024);
        gll16((const char*)B + (size_t)(n0 + row) * 2048 + kt * 64 + byt,
              buf + 16384 + (wid * 2 + q) * 1024);
    }
}

#define QPHASE32(fmh, LOADB)                                                          \
    {                                                                                 \
        bf8_t a_[4];                                                                  \
        _Pragma("unroll")                                                             \
        for (int f = 0; f < 4; f++) {                                                 \
            int ra = 128 * wr + ((fmh) * 4 + f) * 16 + lr;                            \
            a_[f] = *(const bf8_t*)(bA + ra * 64 + ((lg * 16) ^ ((ra & 3) << 4)));    \
        }                                                                             \
        if (LOADB) {                                                                  \
            _Pragma("unroll")                                                         \
            for (int f = 0; f < 4; f++) {                                             \
                int rb = 64 * wc + f * 16 + lr;                                       \
                breg[f] = *(const bf8_t*)(bB + rb * 64 + ((lg * 16) ^ ((rb & 3) << 4))); \
            }                                                                         \
        }                                                                             \
        __builtin_amdgcn_s_barrier();                                                 \
        __builtin_amdgcn_s_setprio(1);                                                \
        _Pragma("unroll")                                                             \
        for (int f = 0; f < 4; f++)                                                   \
            _Pragma("unroll")                                                         \
            for (int j = 0; j < 4; j++)                                               \
                acc[(fmh) * 4 + f][j] = MFMA16(a_[f], breg[j], acc[(fmh) * 4 + f][j]); \
        __builtin_amdgcn_s_setprio(0);                                                \
        __builtin_amdgcn_s_barrier();                                                 \
    }

__global__ __launch_bounds__(512, 4) void k_gemm_qkvg8(
    const u16* __restrict__ xb, const u16* __restrict__ Wcat,
    const u32* __restrict__ cqp, const u32* __restrict__ ckp, const float* __restrict__ gkt,
    u16* __restrict__ qw, u16* __restrict__ kw, u16* __restrict__ kT, u16* __restrict__ vT,
    u16* __restrict__ gateb) {
    __shared__ __align__(16) char L[65536];          // 2 x (A 16KB + B 16KB)
    int flat = blockIdx.x;
    int swz = (flat & 7) * 48 + (flat >> 3);         // XCD-bijective (384 = 8*48)
    int m0 = (swz / 24) * 256, n0 = (swz % 24) * 256;
    int tid = threadIdx.x, lane = tid & 63, wid = tid >> 6;
    int wr = wid >> 2, wc = wid & 3, lr = lane & 15, lg = lane >> 4;
    f4_t acc[8][4];
#pragma unroll
    for (int i = 0; i < 8; i++)
#pragma unroll
        for (int j = 0; j < 4; j++)
#pragma unroll
            for (int e = 0; e < 4; e++) acc[i][j][e] = 0.f;
    stage32(xb, Wcat, m0, n0, 0, L, lane, wid);
    __syncthreads();
    for (int kt = 0; kt < 32; ++kt) {
        const char* bA = L + (kt & 1) * 32768;
        const char* bB = bA + 16384;
        if (kt < 31) stage32(xb, Wcat, m0, n0, kt + 1, L + ((kt + 1) & 1) * 32768, lane, wid);
        bf8_t breg[4];
        QPHASE32(0, 1)
        QPHASE32(1, 0)
        __syncthreads();                             // drain next-tile stage; release this buf
    }
    // ------- epilogue: two 64KB passes (p = 128-row half owned by waves wr==p) -------
    char* SP = L;
    int b = m0 >> 11, t0 = m0 & 2047;
    if (n0 >= 2048 && n0 < 4096) {                   // ---- v: stage transposed [dv][t-half] ----
        int h = (n0 - 2048) >> 8;
#pragma unroll
        for (int p = 0; p < 2; p++) {
            if (p) __syncthreads();
            if (wr == p) {
#pragma unroll
                for (int fm = 0; fm < 8; fm++)
#pragma unroll
                    for (int fn = 0; fn < 4; fn++) {
                        int dv = wc * 64 + fn * 16 + lr;
                        int tl = fm * 16 + lg * 4;
                        u64 pk = 0;
#pragma unroll
                        for (int r = 0; r < 4; r++) pk |= ((u64)f2b(acc[fm][fn][r])) << (16 * r);
                        *(u64*)(SP + dv * 256 + ((tl * 2) ^ ((dv & 15) << 4))) = pk;
                    }
            }
            __syncthreads();
#pragma unroll
            for (int it = 0; it < 8; it++) {
                int chunk = it * 512 + tid;
                int dv = chunk >> 4, j = chunk & 15;
                uint4 v = *(const uint4*)(SP + dv * 256 + ((j * 16) ^ ((dv & 15) << 4)));
                *(uint4*)(vT + ((size_t)((b * 8 + h) * 256 + dv)) * 2048 + t0 + p * 128 + j * 8) = v;
            }
        }
    } else if (n0 < 2048) {                          // ---- q or k: rotate (+prescale) ----
        int isK = n0 >= 1024;
        const u32* cT = isK ? ckp : cqp;
        int hb = (n0 >> 7) & 7;
#pragma unroll
        for (int p = 0; p < 2; p++) {
            if (p) __syncthreads();
            if (wr == p) {
#pragma unroll
                for (int fm = 0; fm < 8; fm++)
#pragma unroll
                    for (int fn = 0; fn < 4; fn++) {
                        int col = wc * 64 + fn * 16 + lr;
                        int gq = (n0 & 1023) + col;
                        int mi = gq >> 1, h = gq >> 7;
                        u64 pk = 0;
#pragma unroll
                        for (int r = 0; r < 4; r++) {
                            int rowl = fm * 16 + lg * 4 + r;
                            int t = t0 + p * 128 + rowl;
                            float v = acc[fm][fn][r];
                            float pv = __shfl_xor(v, 1);
                            u32 cp = cT[t * 512 + mi];
                            float cs = b2f((u16)cp), sn = b2f((u16)(cp >> 16));
                            float o = (col & 1) ? (v * cs + pv * sn) : (v * cs - pv * sn);
                            if (isK) {
                                pk |= ((u64)f2b(o)) << (16 * r);
                                o *= gkt[h * 64 + (t & 63)];
                            }
                            *(u16*)(SP + rowl * 512 + ((col * 2) ^ ((rowl & 15) << 4))) = f2b(o);
                        }
                        if (isK)
                            *(u64*)&kT[((size_t)((b * 8 + h) * 128 + (gq & 127))) * 2048 + t0 + p * 128 + fm * 16 + lg * 4] = pk;
                    }
            }
            __syncthreads();
#pragma unroll
            for (int it = 0; it < 8; it++) {
                int chunk = it * 512 + tid;
                int r = chunk >> 5, j = chunk & 31;
                uint4 v = *(const uint4*)(SP + r * 512 + ((j * 16) ^ ((r & 15) << 4)));
                int hh = hb + (j >> 4);
                u16* g = (isK ? kw : qw) + ((size_t)((b * 8 + hh) * 2048 + t0 + p * 128 + r)) * 128 + (j & 15) * 8;
                *(uint4*)g = v;
            }
        }
    } else {                                         // ---- gate: silu ----
        int c0 = n0 - 4096;
#pragma unroll
        for (int p = 0; p < 2; p++) {
            if (p) __syncthreads();
            if (wr == p) {
#pragma unroll
                for (int fm = 0; fm < 8; fm++)
#pragma unroll
                    for (int fn = 0; fn < 4; fn++) {
                        int col = wc * 64 + fn * 16 + lr;
#pragma unroll
                        for (int r = 0; r < 4; r++) {
                            int rowl = fm * 16 + lg * 4 + r;
                            float gg = acc[fm][fn][r];
                            *(u16*)(SP + rowl * 512 + ((col * 2) ^ ((rowl & 15) << 4))) = f2b(gg / (1.f + expf(-gg)));
                        }
                    }
            }
            __syncthreads();
#pragma unroll
            for (int it = 0; it < 8; it++) {
                int chunk = it * 512 + tid;
                int r = chunk >> 5, j = chunk & 31;
                uint4 v = *(const uint4*)(SP + r * 512 + ((j * 16) ^ ((r & 15) << 4)));
                *(uint4*)(gateb + (size_t)(b * 2048 + t0 + p * 128 + r) * 2048 + c0 + j * 8) = v;
            }
        }
    }
}

// ---------------- 128x128 (BK=64) MFMA mainloop (round-5 proven) ----------------
DEVI void gemm_ml(const u16* __restrict__ Ag, const u16* __restrict__ Bg, int Klen, int Kstr,
                  int m0, int n0, u16* As, u16* Bs, f4_t acc[4][4]) {
    int tid = threadIdx.x, lane = tid & 63, wid = tid >> 6;
    int wr = wid >> 1, wc = wid & 1, lr = lane & 15, lg = lane >> 4;
    for (int k0 = 0; k0 < Klen; k0 += 64) {
        __syncthreads();
#pragma unroll
        for (int p = 0; p < 4; p++) {
            int flat = p * 4096 + tid * 16;
            int row = flat >> 7, byt = (flat & 127) ^ ((row & 7) << 4);
            gll16((const char*)Ag + ((size_t)(m0 + row) * Kstr + k0) * 2 + byt,
                  (char*)As + p * 4096 + wid * 1024);
            gll16((const char*)Bg + ((size_t)(n0 + row) * Kstr + k0) * 2 + byt,
                  (char*)Bs + p * 4096 + wid * 1024);
        }
        __syncthreads();
#pragma unroll
        for (int kk = 0; kk < 2; kk++) {
            bf8_t a[4], b[4];
#pragma unroll
            for (int f = 0; f < 4; f++) {
                int ra = wr * 64 + f * 16 + lr;
                a[f] = *(const bf8_t*)((const char*)As + ra * 128 + ((kk * 64 + lg * 16) ^ ((ra & 7) << 4)));
                int rb = wc * 64 + f * 16 + lr;
                b[f] = *(const bf8_t*)((const char*)Bs + rb * 128 + ((kk * 64 + lg * 16) ^ ((rb & 7) << 4)));
            }
#pragma unroll
            for (int i = 0; i < 4; i++)
#pragma unroll
                for (int j = 0; j < 4; j++)
                    acc[i][j] = MFMA16(a[i], b[j], acc[i][j]);
        }
    }
}

DEVI void acc_zero(f4_t acc[4][4]) {
#pragma unroll
    for (int i = 0; i < 4; i++)
#pragma unroll
        for (int j = 0; j < 4; j++)
#pragma unroll
            for (int e = 0; e < 4; e++) acc[i][j][e] = 0.f;
}

// ---------------- GEMM3 (split-K=2): part[kz] = gated @ Wp slice (round-5 proven) ------
__global__ __launch_bounds__(256) void k_gemm_outp(const u16* __restrict__ gdb, const u16* __restrict__ Wt,
                                                   float* __restrict__ part) {
    __shared__ u16 SM[128 * 128];
    f4_t acc[4][4]; acc_zero(acc);
    int m0 = blockIdx.y * 128, n0 = blockIdx.x * 128, kz = blockIdx.z;
    gemm_ml(gdb + kz * 1024, Wt + kz * 1024, 1024, 2048, m0, n0, SM, SM + 128 * 64, acc);
    int tid = threadIdx.x, lane = tid & 63, wid = tid >> 6;
    int wr = wid >> 1, wc = wid & 1, lr = lane & 15, lg = lane >> 4;
    float* SMf = (float*)SM;
    float* po = part + (size_t)kz * 4096 * 1024;
    __syncthreads();
#pragma unroll
    for (int p = 0; p < 2; p++) {
        if (p) __syncthreads();
        if (wr == p) {
#pragma unroll
            for (int fm = 0; fm < 4; fm++)
#pragma unroll
                for (int fn = 0; fn < 4; fn++) {
                    int col = wc * 64 + fn * 16 + lr;
#pragma unroll
                    for (int r = 0; r < 4; r++) {
                        int rowl = fm * 16 + lg * 4 + r;
                        *(float*)((char*)SMf + rowl * 512 + ((col * 4) ^ ((rowl & 7) << 6))) = acc[fm][fn][r];
                    }
                }
        }
        __syncthreads();
#pragma unroll
        for (int it2 = 0; it2 < 8; it2++) {
            int chunk = it2 * 256 + tid;
            int rowl = chunk >> 5, j = chunk & 31;
            f4_t v = *(const f4_t*)((const char*)SMf + rowl * 512 + ((j * 16) ^ ((rowl & 7) << 6)));
            *(f4_t*)((char*)po + ((size_t)(m0 + p * 64 + rowl) * 1024 + n0) * 4 + j * 16) = v;
        }
    }
}

__global__ __launch_bounds__(256) void k_outred(const float* __restrict__ part, const float* __restrict__ bp,
                                                float* __restrict__ outp) {
    int i = blockIdx.x * 256 + threadIdx.x;          // 1M x f4
    f4_t a = ((const f4_t*)part)[i];
    f4_t c = ((const f4_t*)(part + (size_t)4096 * 1024))[i];
    f4_t bb = *(const f4_t*)(bp + ((i * 4) & 1023));
#pragma unroll
    for (int e = 0; e < 4; e++) a[e] += c[e] + bb[e];
    ((f4_t*)outp)[i] = a;
}

// ---------------- retention: Q in regs, factorized decay, wave-local PV ----------------
__global__ __launch_bounds__(256, 3) void k_retention(const u16* __restrict__ qws, const u16* __restrict__ kws,
                                                      const u16* __restrict__ vTws,
                                                      u16* __restrict__ ret0, u16* __restrict__ ret1) {
    __shared__ u16 SMr[64 * 128 + 256 * 64];         // 48KB
    u16* Ks = SMr;                                   // 16KB; P aliases it
    u16* Vs = SMr + 64 * 128;                        // 32KB; output staging aliases it
    int x = blockIdx.x;
    int it, jlo, jhi, toret1;
    if (x < 16)      { it = 15 - x;  jlo = 0;              jhi = it + 1;         toret1 = 0; }
    else if (x < 32) { it = x;       jlo = 0;              jhi = (it + 2) >> 1;  toret1 = 0; }
    else             { it = x - 16;  jlo = (it + 2) >> 1;  jhi = it + 1;         toret1 = 1; }
    int h = blockIdx.y, b = blockIdx.z;
    int bh = b * 8 + h;
    float lg2 = log2f(1.f - expf(L0f + (float)h * DLf));
    int i0 = it * 64;
    const u16* qbase = qws + (size_t)bh * 2048 * 128;
    const u16* kbase = kws + (size_t)bh * 2048 * 128;
    const u16* vbase = vTws + (size_t)bh * 256 * 2048;
    int tid = threadIdx.x, lane = tid & 63, w = tid >> 6, lr = lane & 15, lg = lane >> 4;
    bf8_t aq[4];
#pragma unroll
    for (int kk = 0; kk < 4; kk++)
        aq[kk] = *(const bf8_t*)((const char*)qbase + (size_t)(i0 + w * 16 + lr) * 256 + kk * 64 + lg * 16);
    f4_t racc[16];
#pragma unroll
    for (int f = 0; f < 16; f++)
#pragma unroll
        for (int e = 0; e < 4; e++) racc[f][e] = 0.f;
    for (int jt = jlo; jt < jhi; jt++) {
        int j0 = jt * 64;
        int diag = (jt == it);
        float tf = exp2f(64.f * (float)(it - jt) * lg2);
        __syncthreads();
#pragma unroll
        for (int p = 0; p < 4; p++) {                // stage K tile [64][128]
            int flat = p * 4096 + tid * 16;
            int row = flat >> 8, byt = (flat & 255) ^ ((row & 7) << 4);
            gll16((const char*)kbase + (size_t)(j0 + row) * 256 + byt, (char*)Ks + p * 4096 + w * 1024);
        }
#pragma unroll
        for (int p = 0; p < 8; p++) {                // stage Vt tile [256][64]
            int flat = p * 4096 + tid * 16;
            int row = flat >> 7, byt = (flat & 127) ^ ((row & 7) << 4);
            gll16((const char*)vbase + (size_t)row * 4096 + (size_t)j0 * 2 + byt,
                  (char*)Vs + p * 4096 + w * 1024);
        }
        __syncthreads();
        f4_t sacc[4];
#pragma unroll
        for (int f = 0; f < 4; f++)
#pragma unroll
            for (int e = 0; e < 4; e++) sacc[f][e] = 0.f;
#pragma unroll
        for (int kk = 0; kk < 4; kk++)
#pragma unroll
            for (int fn = 0; fn < 4; fn++) {
                int rb = fn * 16 + lr;
                bf8_t bb = *(const bf8_t*)((const char*)Ks + rb * 256 + ((kk * 64 + lg * 16) ^ ((rb & 7) << 4)));
                sacc[fn] = MFMA16(aq[kk], bb, sacc[fn]);
            }
        __syncthreads();                             // K reads done; alias Ks as P
#pragma unroll
        for (int fn = 0; fn < 4; fn++)
#pragma unroll
            for (int r = 0; r < 4; r++) {
                int i_loc = w * 16 + lg * 4 + r;
                int col = fn * 16 + lr;
                float v = diag ? ((i_loc - col >= 0) ? sacc[fn][r] : 0.f) : sacc[fn][r] * tf;
                *(u16*)((char*)Ks + i_loc * 128 + ((col * 2) ^ ((i_loc & 7) << 4))) = f2b(v);
            }
#pragma unroll
        for (int kk = 0; kk < 2; kk++) {
            int ra = w * 16 + lr;
            bf8_t ap = *(const bf8_t*)((const char*)Ks + ra * 128 + ((kk * 64 + lg * 16) ^ ((ra & 7) << 4)));
#pragma unroll
            for (int fn2 = 0; fn2 < 16; fn2++) {
                int rb = fn2 * 16 + lr;
                bf8_t bv = *(const bf8_t*)((const char*)Vs + rb * 128 + ((kk * 64 + lg * 16) ^ ((rb & 7) << 4)));
                racc[fn2] = MFMA16(ap, bv, racc[fn2]);
            }
        }
    }
    __syncthreads();
    u16* St = Vs;
#pragma unroll
    for (int fn2 = 0; fn2 < 16; fn2++)
#pragma unroll
        for (int r = 0; r < 4; r++) {
            int il = w * 16 + lg * 4 + r;
            int dv = fn2 * 16 + lr;
            *(u16*)((char*)St + il * 512 + ((dv * 2) ^ ((il & 15) << 4))) = f2b(racc[fn2][r]);
        }
    __syncthreads();
#pragma unroll
    for (int it2 = 0; it2 < 8; it2++) {
        int chunk = it2 * 256 + tid;
        int il = chunk >> 5, j = chunk & 31;
        uint4 v = *(const uint4*)((const char*)St + il * 512 + ((j * 16) ^ ((il & 15) << 4)));
        char* dst;
        if (toret1) dst = (char*)ret1 + ((size_t)(b * 1024 + i0 - 1024 + il) * 2048 + h * 256) * 2 + j * 16;
        else        dst = (char*)ret0 + ((size_t)(b * 2048 + i0 + il) * 2048 + h * 256) * 2 + j * 16;
        *(uint4*)dst = v;
    }
}

// ---------------- curr_kv partials: block = (t-range of 512, bh) ----------------
__global__ __launch_bounds__(512) void k_currkv(const u16* __restrict__ kTws, const u16* __restrict__ vTws,
                                                const float* __restrict__ gtab, float* __restrict__ part) {
    __shared__ u16 Ks2[128 * 64];
    __shared__ u16 Vws[256 * 64];
    int tr = blockIdx.x;            // 0..3
    int bh = blockIdx.y;            // 0..15
    int h = bh & 7;
    const u16* kT = kTws + (size_t)bh * 128 * 2048;
    const u16* vT = vTws + (size_t)bh * 256 * 2048;
    const float* gt = gtab + h * 2048;
    int tid = threadIdx.x, lane = tid & 63, wid = tid >> 6;
    int wr = wid >> 2, wc = wid & 3, lr = lane & 15, lg = lane >> 4;
    f4_t acc[4][4]; acc_zero(acc);
    for (int tc = 0; tc < 8; tc++) {
        int t0 = tr * 512 + tc * 64;
        __syncthreads();
#pragma unroll
        for (int p = 0; p < 2; p++) {
            int flat = p * 8192 + tid * 16;
            int row = flat >> 7, byt = (flat & 127) ^ ((row & 7) << 4);
            gll16((const char*)kT + (size_t)row * 4096 + (size_t)t0 * 2 + byt,
                  (char*)Ks2 + p * 8192 + wid * 1024);
        }
#pragma unroll
        for (int p = 0; p < 4; p++) {
            int flat = p * 8192 + tid * 16;
            int row = flat >> 7, byt = flat & 127;
            int tt = t0 + (byt >> 1);
            const u16* src = vT + (size_t)row * 2048 + tt;
            u16 tmp[8]; *(uint4*)tmp = *(const uint4*)src;
            const float* gp = gt + tt;
            u16 op[8];
#pragma unroll
            for (int e = 0; e < 8; e++) op[e] = f2b(b2f(tmp[e]) * gp[e]);
            *(uint4*)((char*)Vws + row * 128 + (byt ^ ((row & 7) << 4))) = *(uint4*)op;
        }
        __syncthreads();
#pragma unroll
        for (int kk = 0; kk < 2; kk++) {
            bf8_t a[4], bb[4];
#pragma unroll
            for (int f = 0; f < 4; f++) {
                int ra = wr * 64 + f * 16 + lr;
                a[f] = *(const bf8_t*)((const char*)Ks2 + ra * 128 + ((kk * 64 + lg * 16) ^ ((ra & 7) << 4)));
                int rb = wc * 64 + f * 16 + lr;
                bb[f] = *(const bf8_t*)((const char*)Vws + rb * 128 + ((kk * 64 + lg * 16) ^ ((rb & 7) << 4)));
            }
#pragma unroll
            for (int i = 0; i < 4; i++)
#pragma unroll
                for (int j = 0; j < 4; j++)
                    acc[i][j] = MFMA16(a[i], bb[j], acc[i][j]);
        }
    }
#pragma unroll
    for (int fm = 0; fm < 4; fm++)
#pragma unroll
        for (int fn = 0; fn < 4; fn++)
#pragma unroll
            for (int r = 0; r < 4; r++) {
                int dk = wr * 64 + fm * 16 + lg * 4 + r;
                int dv = wc * 64 + fn * 16 + lr;
                part[((size_t)(bh * 4 + tr)) * 32768 + (size_t)dk * 256 + dv] = acc[fm][fn][r];
            }
}

__global__ __launch_bounds__(256) void k_reduce_ckv(const float* __restrict__ part, float* __restrict__ outc) {
    int i = blockIdx.x * 256 + threadIdx.x;          // 524288
    int bh = i >> 15, wv = i & 32767;
    float s = 0.f;
#pragma unroll
    for (int tr = 0; tr < 4; tr++) s += part[((size_t)(bh * 4 + tr)) * 32768 + wv];
    outc[i] = s;
}

// ---------------- groupnorm(256) * silu-gate -> bf16 ----------------
__global__ __launch_bounds__(256) void k_gnorm(const u16* __restrict__ ret0, const u16* __restrict__ ret1,
                                               const u16* __restrict__ gateb, u16* __restrict__ gatedb) {
    int g = blockIdx.x * 4 + (threadIdx.x >> 6);     // wave per group
    int lane = threadIdx.x & 63;
    int row = g >> 3, h = g & 7;                     // row = b*2048 + t
    size_t base = (size_t)row * 2048 + h * 256 + lane * 4;
    u64 p0 = *(const u64*)(ret0 + base);
    float e0 = b2f((u16)p0), e1 = b2f((u16)(p0 >> 16)), e2 = b2f((u16)(p0 >> 32)), e3 = b2f((u16)(p0 >> 48));
    if ((row & 2047) >= 1024) {
        size_t b1 = (size_t)((row >> 11) * 1024 + (row & 1023)) * 2048 + h * 256 + lane * 4;
        u64 p1 = *(const u64*)(ret1 + b1);
        e0 += b2f((u16)p1); e1 += b2f((u16)(p1 >> 16)); e2 += b2f((u16)(p1 >> 32)); e3 += b2f((u16)(p1 >> 48));
    }
    float s = e0 + e1 + e2 + e3;
    float sqs = e0 * e0 + e1 * e1 + e2 * e2 + e3 * e3;
#pragma unroll
    for (int m = 1; m < 64; m <<= 1) { s += __shfl_xor(s, m); sqs += __shfl_xor(sqs, m); }
    float mean = s * (1.f / 256.f);
    float var = sqs * (1.f / 256.f) - mean * mean;
    float inv = rsqrtf(var + 1e-5f);
    u64 gp = *(const u64*)(gateb + base);
    u64 pk = (u64)f2b((e0 - mean) * inv * b2f((u16)gp)) |
             ((u64)f2b((e1 - mean) * inv * b2f((u16)(gp >> 16))) << 16) |
             ((u64)f2b((e2 - mean) * inv * b2f((u16)(gp >> 32))) << 32) |
             ((u64)f2b((e3 - mean) * inv * b2f((u16)(gp >> 48))) << 48);
    *(u64*)(gatedb + base) = pk;
}

extern "C" void kernel_launch(void* const* d_in, const int* in_sizes, int n_in,
                              void* d_out, int out_size, void* d_ws, size_t ws_size,
                              hipStream_t stream) {
    const float* x    = (const float*)d_in[0];
    const float* Wqkv = (const float*)d_in[1];
    const float* Wg   = (const float*)d_in[2];
    const float* Wp   = (const float*)d_in[3];
    const float* bp   = (const float*)d_in[4];
    float* outp   = (float*)d_out;
    float* outckv = outp + (size_t)BB * TT * HIDN;

    char* ws = (char*)d_ws;
    const size_t MB = 1024 * 1024;
    u16*   xb     = (u16*)(ws);               // 0..8
    u16*   WqkvT  = (u16*)(ws + 8 * MB);      // 8..16  [4096][1024]
    u16*   WgT    = (u16*)(ws + 16 * MB);     // 16..20 [2048][1024] (contiguous -> Wcat [6144][1024])
    u16*   WpT    = (u16*)(ws + 20 * MB);     // 20..24 [1024][2048]
    u32*   cqp    = (u32*)(ws + 24 * MB);     // 24..28 packed q table
    u32*   ckp    = (u32*)(ws + 28 * MB);     // 28..32 packed k table
    u16*   gateb  = (u16*)(ws + 32 * MB);     // 32..48 [4096][2048]
    u16*   qw     = (u16*)(ws + 48 * MB);     // 48..56 [bh][t][128] prescaled q
    u16*   kw     = (u16*)(ws + 56 * MB);     // 56..64 prescaled k
    u16*   kT     = (u16*)(ws + 64 * MB);     // 64..72 [bh][128][t] unscaled k
    u16*   vT     = (u16*)(ws + 72 * MB);     // 72..88 [bh][256][t]
    u16*   ret0b  = (u16*)(ws + 88 * MB);     // 88..104 bf16 [b][2048][2048]
    u16*   ret1b  = (u16*)(ws + 104 * MB);    // 104..112 bf16 [b][1024][2048]
    float* ckvp   = (float*)(ws + 112 * MB);  // 112..120
    float* gtab   = (float*)(ws + 120 * MB);            // 64KB
    float* gkt    = (float*)(ws + 120 * MB + 65536);    // 2KB
    // aliases:
    u16*   gatedb = (u16*)(ws + 48 * MB);     // 16MB over qw/kw (dead after retention)
    float* opart  = (float*)(ws + 88 * MB);   // 32MB over ret0b/ret1b/ckvp (dead after gnorm)

    hipLaunchKernelGGL(k_tables, dim3(4162), dim3(256), 0, stream, cqp, ckp, gtab, gkt);
    hipLaunchKernelGGL(k_cvt, dim3(4096), dim3(256), 0, stream, x, xb);
    hipLaunchKernelGGL(k_tposeF, dim3(8192), dim3(32, 8), 0, stream, Wqkv, Wg, Wp, WqkvT, WgT, WpT);
    hipLaunchKernelGGL(k_gemm_qkvg8, dim3(384), dim3(512), 0, stream,
                       xb, WqkvT, cqp, ckp, gkt, qw, kw, kT, vT, gateb);
    hipLaunchKernelGGL(k_currkv, dim3(4, 16), dim3(512), 0, stream, kT, vT, gtab, ckvp);
    hipLaunchKernelGGL(k_reduce_ckv, dim3(2048), dim3(256), 0, stream, ckvp, outckv);
    hipLaunchKernelGGL(k_retention, dim3(48, 8, 2), dim3(256), 0, stream, qw, kw, vT, ret0b, ret1b);
    hipLaunchKernelGGL(k_gnorm, dim3(8192), dim3(256), 0, stream, ret0b, ret1b, gateb, gatedb);
    hipLaunchKernelGGL(k_gemm_outp, dim3(8, 32, 2), dim3(256), 0, stream, gatedb, WpT, opart);
    hipLaunchKernelGGL(k_outred, dim3(4096), dim3(256), 0, stream, opart, bp, outp);
}

// Round 9
// 235.217 us; speedup vs baseline: 2.8434x; 2.8434x over previous
//
#include <hip/hip_runtime.h>

typedef unsigned short u16;
typedef unsigned int   u32;
typedef unsigned long long u64;

typedef __attribute__((ext_vector_type(8))) short bf8_t;   // 8 x bf16
typedef __attribute__((ext_vector_type(4))) float f4_t;

#define DEVI __device__ __forceinline__
#define MFMA16(a,b,c) __builtin_amdgcn_mfma_f32_16x16x32_bf16((a),(b),(c),0,0,0)

#define BB   2
#define TT   2048
#define HIDN 1024
#define L0f  (-3.4657359027997265f)   // ln(1/32)
#define DLf  (-0.3960841031714215f)   // (ln(1/512)-ln(1/32))/7
#define SCL  (0.08838834764831845f)   // 128^-0.5

DEVI u16 f2b(float f) {                 // f32 -> bf16 RNE
    u32 u = __float_as_uint(f);
    u += 0x7FFFu + ((u >> 16) & 1u);
    return (u16)(u >> 16);
}
DEVI float b2f(u16 u) { return __uint_as_float(((u32)u) << 16); }

// async global->LDS, 16B per lane; lds dest = wave-uniform base + lane*16
DEVI void gll16(const void* g, void* l) {
    __builtin_amdgcn_global_load_lds((const __attribute__((address_space(1))) void*)g,
                                     (__attribute__((address_space(3))) void*)l, 16, 0, 0);
}

// ------- packed xPos tables (blocks 0..4095) + gamma tables (blocks 4096..4161) -------
__global__ __launch_bounds__(256) void k_tables(u32* __restrict__ cqp, u32* __restrict__ ckp,
                                                float* __restrict__ gt, float* __restrict__ gk) {
    int bx = blockIdx.x;
    if (bx >= 4096) {                                // gamma tables
        int i = (bx - 4096) * 256 + threadIdx.x;     // 16896 entries
        if (i < 16384) {                             // gtab[h][t] = g^(2047-t)
            int h = i >> 11, t = i & 2047;
            float lg2 = log2f(1.f - expf(L0f + (float)h * DLf));
            gt[i] = exp2f((float)(2047 - t) * lg2);
        } else {                                     // gk[h][d] = g^-d
            int idx = i - 16384;                     // 512 entries
            int h = idx >> 6, d = idx & 63;
            float lg2 = log2f(1.f - expf(L0f + (float)h * DLf));
            gk[idx] = exp2f(-(float)d * lg2);
        }
        return;
    }
    int idx = bx * 256 + threadIdx.x;                // t*512 + m
    int t = idx >> 9, m = idx & 511;
    float base = (2.f * (float)m + 409.6f) * (1.f / 1433.6f);
    float s = exp2f(log2f(base) * ((float)t * (1.f / 512.f)));
    float invf = exp2f(-(float)m * (13.287712379549449f / 512.f)); // 10000^{-m/512}
    float sn, cs;
    sincosf((float)t * invf, &sn, &cs);
    int h = m >> 6;
    float lg2h = log2f(1.f - expf(L0f + (float)h * DLf));
    float qf = s * SCL * exp2f((float)(t & 63) * lg2h);
    cqp[idx] = (u32)f2b(cs * qf) | ((u32)f2b(sn * qf) << 16);
    float is = 1.f / s;
    ckp[idx] = (u32)f2b(cs * is) | ((u32)f2b(sn * is) << 16);
}

// ---------------- f32 -> bf16 convert (x) ----------------
__global__ __launch_bounds__(256) void k_cvt(const float* __restrict__ in, u16* __restrict__ out) {
    int i = blockIdx.x * 256 + threadIdx.x;
    float4 v = ((const float4*)in)[i];
    u64 pk = (u64)f2b(v.x) | ((u64)f2b(v.y) << 16) | ((u64)f2b(v.z) << 32) | ((u64)f2b(v.w) << 48);
    ((u64*)out)[i] = pk;
}

// ------- fused transpose+convert of all 3 weights: in[R][C] f32 -> out[C][R] bf16 -------
__global__ __launch_bounds__(256) void k_tposeF(const float* __restrict__ Wqkv,
                                                const float* __restrict__ Wg,
                                                const float* __restrict__ Wp,
                                                u16* __restrict__ oQ, u16* __restrict__ oG,
                                                u16* __restrict__ oP) {
    __shared__ float tile[32][33];
    int bx = blockIdx.x;
    const float* in; u16* out; int R, C, cx, ry;
    if (bx < 4096)      { in = Wqkv; out = oQ; R = 1024; C = 4096; cx = bx & 127;        ry = bx >> 7; }
    else if (bx < 6144) { int b2 = bx - 4096; in = Wg; out = oG; R = 1024; C = 2048; cx = b2 & 63; ry = b2 >> 6; }
    else                { int b2 = bx - 6144; in = Wp; out = oP; R = 2048; C = 1024; cx = b2 & 31; ry = b2 >> 5; }
    int c0 = cx * 32, r0 = ry * 32;
    int tx = threadIdx.x, ty = threadIdx.y;          // (32,8)
#pragma unroll
    for (int i = 0; i < 4; i++)
        tile[ty * 4 + i][tx] = in[(size_t)(r0 + ty * 4 + i) * C + c0 + tx];
    __syncthreads();
#pragma unroll
    for (int i = 0; i < 4; i++)
        out[(size_t)(c0 + ty * 4 + i) * R + r0 + tx] = f2b(tile[tx][ty * 4 + i]);
}

// =============== 128x256 8-wave, BK=64, dbuf 96KB, phase-interleaved GEMM1 ===============
// 768 blocks = exactly 3 scheduling rounds at 1 block/CU (fixes 384-block 1.5-round tail).
DEVI void stage_t(const u16* __restrict__ A, const u16* __restrict__ B,
                  int m0, int n0, int kt, char* buf, int tid, int wid) {
#pragma unroll
    for (int q = 0; q < 2; q++) {                    // A: 128 rows x 128B = 16KB
        int flat = q * 8192 + tid * 16;
        int row = flat >> 7, byt = (flat & 127) ^ ((row & 7) << 4);
        gll16((const char*)A + (size_t)(m0 + row) * 2048 + kt * 128 + byt,
              buf + q * 8192 + wid * 1024);
    }
#pragma unroll
    for (int q = 0; q < 4; q++) {                    // B: 256 rows x 128B = 32KB
        int flat = q * 8192 + tid * 16;
        int row = flat >> 7, byt = (flat & 127) ^ ((row & 7) << 4);
        gll16((const char*)B + (size_t)(n0 + row) * 2048 + kt * 128 + byt,
              buf + 16384 + q * 8192 + wid * 1024);
    }
}

#define QPH(kk)                                                                       \
    {                                                                                 \
        bf8_t a_[4], breg[4];                                                         \
        _Pragma("unroll")                                                             \
        for (int f = 0; f < 4; f++) {                                                 \
            int ra = 64 * wr + f * 16 + lr;                                           \
            a_[f] = *(const bf8_t*)(bA + ra * 128 + (((kk) * 64 + lg * 16) ^ ((ra & 7) << 4))); \
            int rb = 64 * wc + f * 16 + lr;                                           \
            breg[f] = *(const bf8_t*)(bB + rb * 128 + (((kk) * 64 + lg * 16) ^ ((rb & 7) << 4))); \
        }                                                                             \
        __builtin_amdgcn_s_barrier();                                                 \
        __builtin_amdgcn_s_setprio(1);                                                \
        _Pragma("unroll")                                                             \
        for (int f = 0; f < 4; f++)                                                   \
            _Pragma("unroll")                                                         \
            for (int j = 0; j < 4; j++)                                               \
                acc[f][j] = MFMA16(a_[f], breg[j], acc[f][j]);                        \
        __builtin_amdgcn_s_setprio(0);                                                \
        __builtin_amdgcn_s_barrier();                                                 \
    }

__global__ __launch_bounds__(512, 2) void k_gemm_qkvg8(
    const u16* __restrict__ xb, const u16* __restrict__ Wcat,
    const u32* __restrict__ cqp, const u32* __restrict__ ckp, const float* __restrict__ gkt,
    u16* __restrict__ qw, u16* __restrict__ kw, u16* __restrict__ kT, u16* __restrict__ vT,
    u16* __restrict__ gateb) {
    __shared__ __align__(16) char L[98304];          // 2 x (A 16KB + B 32KB)
    int flat = blockIdx.x;
    int swz = (flat & 7) * 96 + (flat >> 3);         // XCD-bijective (768 = 8*96)
    int m0 = (swz / 24) * 128, n0 = (swz % 24) * 256;
    int tid = threadIdx.x, lane = tid & 63, wid = tid >> 6;
    int wr = wid >> 2, wc = wid & 3, lr = lane & 15, lg = lane >> 4;
    f4_t acc[4][4];
#pragma unroll
    for (int i = 0; i < 4; i++)
#pragma unroll
        for (int j = 0; j < 4; j++)
#pragma unroll
            for (int e = 0; e < 4; e++) acc[i][j][e] = 0.f;
    stage_t(xb, Wcat, m0, n0, 0, L, tid, wid);
    __syncthreads();
    for (int kt = 0; kt < 16; ++kt) {
        const char* bA = L + (kt & 1) * 49152;
        const char* bB = bA + 16384;
        if (kt < 15) stage_t(xb, Wcat, m0, n0, kt + 1, L + ((kt + 1) & 1) * 49152, tid, wid);
        QPH(0)
        QPH(1)
        __syncthreads();                             // drain next-tile stage; release this buf
    }
    // ------- epilogue: stage 128x256 tile (64KB) in L, coalesced out -------
    char* SP = L;
    int b = m0 >> 11, t0 = m0 & 2047;
    if (n0 >= 2048 && n0 < 4096) {                   // ---- v: stage transposed [dv][t] ----
        int h = (n0 - 2048) >> 8;
#pragma unroll
        for (int fm = 0; fm < 4; fm++)
#pragma unroll
            for (int fn = 0; fn < 4; fn++) {
                int dv = wc * 64 + fn * 16 + lr;
                int tl = wr * 64 + fm * 16 + lg * 4;
                u64 pk = 0;
#pragma unroll
                for (int r = 0; r < 4; r++) pk |= ((u64)f2b(acc[fm][fn][r])) << (16 * r);
                *(u64*)(SP + dv * 256 + ((tl * 2) ^ ((dv & 15) << 4))) = pk;
            }
        __syncthreads();
#pragma unroll
        for (int it = 0; it < 8; it++) {
            int chunk = it * 512 + tid;
            int dv = chunk >> 4, j = chunk & 15;
            uint4 v = *(const uint4*)(SP + dv * 256 + ((j * 16) ^ ((dv & 15) << 4)));
            *(uint4*)(vT + ((size_t)((b * 8 + h) * 256 + dv)) * 2048 + t0 + j * 8) = v;
        }
    } else if (n0 < 2048) {                          // ---- q or k: rotate (+prescale) ----
        int isK = n0 >= 1024;
        const u32* cT = isK ? ckp : cqp;
        int hb = (n0 >> 7) & 7;
#pragma unroll
        for (int fm = 0; fm < 4; fm++)
#pragma unroll
            for (int fn = 0; fn < 4; fn++) {
                int col = wc * 64 + fn * 16 + lr;
                int gq = (n0 & 1023) + col;
                int mi = gq >> 1, h = gq >> 7;
                u64 pk = 0;
#pragma unroll
                for (int r = 0; r < 4; r++) {
                    int rowl = wr * 64 + fm * 16 + lg * 4 + r;
                    int t = t0 + rowl;
                    float v = acc[fm][fn][r];
                    float pv = __shfl_xor(v, 1);
                    u32 cp = cT[t * 512 + mi];
                    float cs = b2f((u16)cp), sn = b2f((u16)(cp >> 16));
                    float o = (col & 1) ? (v * cs + pv * sn) : (v * cs - pv * sn);
                    if (isK) {
                        pk |= ((u64)f2b(o)) << (16 * r);
                        o *= gkt[h * 64 + (t & 63)];
                    }
                    *(u16*)(SP + rowl * 512 + ((col * 2) ^ ((rowl & 15) << 4))) = f2b(o);
                }
                if (isK)
                    *(u64*)&kT[((size_t)((b * 8 + h) * 128 + (gq & 127))) * 2048 + t0 + wr * 64 + fm * 16 + lg * 4] = pk;
            }
        __syncthreads();
#pragma unroll
        for (int it = 0; it < 8; it++) {
            int chunk = it * 512 + tid;
            int r = chunk >> 5, j = chunk & 31;
            uint4 v = *(const uint4*)(SP + r * 512 + ((j * 16) ^ ((r & 15) << 4)));
            int hh = hb + (j >> 4);
            u16* g = (isK ? kw : qw) + ((size_t)((b * 8 + hh) * 2048 + t0 + r)) * 128 + (j & 15) * 8;
            *(uint4*)g = v;
        }
    } else {                                         // ---- gate: silu ----
        int c0 = n0 - 4096;
#pragma unroll
        for (int fm = 0; fm < 4; fm++)
#pragma unroll
            for (int fn = 0; fn < 4; fn++) {
                int col = wc * 64 + fn * 16 + lr;
#pragma unroll
                for (int r = 0; r < 4; r++) {
                    int rowl = wr * 64 + fm * 16 + lg * 4 + r;
                    float gg = acc[fm][fn][r];
                    *(u16*)(SP + rowl * 512 + ((col * 2) ^ ((rowl & 15) << 4))) = f2b(gg / (1.f + expf(-gg)));
                }
            }
        __syncthreads();
#pragma unroll
        for (int it = 0; it < 8; it++) {
            int chunk = it * 512 + tid;
            int r = chunk >> 5, j = chunk & 31;
            uint4 v = *(const uint4*)(SP + r * 512 + ((j * 16) ^ ((r & 15) << 4)));
            *(uint4*)(gateb + (size_t)(b * 2048 + t0 + r) * 2048 + c0 + j * 8) = v;
        }
    }
}

// ---------------- 128x128 (BK=64) MFMA mainloop (round-5 proven) ----------------
DEVI void gemm_ml(const u16* __restrict__ Ag, const u16* __restrict__ Bg, int Klen, int Kstr,
                  int m0, int n0, u16* As, u16* Bs, f4_t acc[4][4]) {
    int tid = threadIdx.x, lane = tid & 63, wid = tid >> 6;
    int wr = wid >> 1, wc = wid & 1, lr = lane & 15, lg = lane >> 4;
    for (int k0 = 0; k0 < Klen; k0 += 64) {
        __syncthreads();
#pragma unroll
        for (int p = 0; p < 4; p++) {
            int flat = p * 4096 + tid * 16;
            int row = flat >> 7, byt = (flat & 127) ^ ((row & 7) << 4);
            gll16((const char*)Ag + ((size_t)(m0 + row) * Kstr + k0) * 2 + byt,
                  (char*)As + p * 4096 + wid * 1024);
            gll16((const char*)Bg + ((size_t)(n0 + row) * Kstr + k0) * 2 + byt,
                  (char*)Bs + p * 4096 + wid * 1024);
        }
        __syncthreads();
#pragma unroll
        for (int kk = 0; kk < 2; kk++) {
            bf8_t a[4], b[4];
#pragma unroll
            for (int f = 0; f < 4; f++) {
                int ra = wr * 64 + f * 16 + lr;
                a[f] = *(const bf8_t*)((const char*)As + ra * 128 + ((kk * 64 + lg * 16) ^ ((ra & 7) << 4)));
                int rb = wc * 64 + f * 16 + lr;
                b[f] = *(const bf8_t*)((const char*)Bs + rb * 128 + ((kk * 64 + lg * 16) ^ ((rb & 7) << 4)));
            }
#pragma unroll
            for (int i = 0; i < 4; i++)
#pragma unroll
                for (int j = 0; j < 4; j++)
                    acc[i][j] = MFMA16(a[i], b[j], acc[i][j]);
        }
    }
}

DEVI void acc_zero(f4_t acc[4][4]) {
#pragma unroll
    for (int i = 0; i < 4; i++)
#pragma unroll
        for (int j = 0; j < 4; j++)
#pragma unroll
            for (int e = 0; e < 4; e++) acc[i][j][e] = 0.f;
}

// ---------------- GEMM3 (split-K=2): part[kz] = gated @ Wp slice (round-5 proven) ------
__global__ __launch_bounds__(256) void k_gemm_outp(const u16* __restrict__ gdb, const u16* __restrict__ Wt,
                                                   float* __restrict__ part) {
    __shared__ u16 SM[128 * 128];
    f4_t acc[4][4]; acc_zero(acc);
    int m0 = blockIdx.y * 128, n0 = blockIdx.x * 128, kz = blockIdx.z;
    gemm_ml(gdb + kz * 1024, Wt + kz * 1024, 1024, 2048, m0, n0, SM, SM + 128 * 64, acc);
    int tid = threadIdx.x, lane = tid & 63, wid = tid >> 6;
    int wr = wid >> 1, wc = wid & 1, lr = lane & 15, lg = lane >> 4;
    float* SMf = (float*)SM;
    float* po = part + (size_t)kz * 4096 * 1024;
    __syncthreads();
#pragma unroll
    for (int p = 0; p < 2; p++) {
        if (p) __syncthreads();
        if (wr == p) {
#pragma unroll
            for (int fm = 0; fm < 4; fm++)
#pragma unroll
                for (int fn = 0; fn < 4; fn++) {
                    int col = wc * 64 + fn * 16 + lr;
#pragma unroll
                    for (int r = 0; r < 4; r++) {
                        int rowl = fm * 16 + lg * 4 + r;
                        *(float*)((char*)SMf + rowl * 512 + ((col * 4) ^ ((rowl & 7) << 6))) = acc[fm][fn][r];
                    }
                }
        }
        __syncthreads();
#pragma unroll
        for (int it2 = 0; it2 < 8; it2++) {
            int chunk = it2 * 256 + tid;
            int rowl = chunk >> 5, j = chunk & 31;
            f4_t v = *(const f4_t*)((const char*)SMf + rowl * 512 + ((j * 16) ^ ((rowl & 7) << 6)));
            *(f4_t*)((char*)po + ((size_t)(m0 + p * 64 + rowl) * 1024 + n0) * 4 + j * 16) = v;
        }
    }
}

__global__ __launch_bounds__(256) void k_outred(const float* __restrict__ part, const float* __restrict__ bp,
                                                float* __restrict__ outp) {
    int i = blockIdx.x * 256 + threadIdx.x;          // 1M x f4
    f4_t a = ((const f4_t*)part)[i];
    f4_t c = ((const f4_t*)(part + (size_t)4096 * 1024))[i];
    f4_t bb = *(const f4_t*)(bp + ((i * 4) & 1023));
#pragma unroll
    for (int e = 0; e < 4; e++) a[e] += c[e] + bb[e];
    ((f4_t*)outp)[i] = a;
}

// ---------------- retention: Q in regs, factorized decay, wave-local PV ----------------
__global__ __launch_bounds__(256, 3) void k_retention(const u16* __restrict__ qws, const u16* __restrict__ kws,
                                                      const u16* __restrict__ vTws,
                                                      u16* __restrict__ ret0, u16* __restrict__ ret1) {
    __shared__ u16 SMr[64 * 128 + 256 * 64];         // 48KB
    u16* Ks = SMr;                                   // 16KB; P aliases it
    u16* Vs = SMr + 64 * 128;                        // 32KB; output staging aliases it
    int x = blockIdx.x;
    int it, jlo, jhi, toret1;
    if (x < 16)      { it = 15 - x;  jlo = 0;              jhi = it + 1;         toret1 = 0; }
    else if (x < 32) { it = x;       jlo = 0;              jhi = (it + 2) >> 1;  toret1 = 0; }
    else             { it = x - 16;  jlo = (it + 2) >> 1;  jhi = it + 1;         toret1 = 1; }
    int h = blockIdx.y, b = blockIdx.z;
    int bh = b * 8 + h;
    float lg2 = log2f(1.f - expf(L0f + (float)h * DLf));
    int i0 = it * 64;
    const u16* qbase = qws + (size_t)bh * 2048 * 128;
    const u16* kbase = kws + (size_t)bh * 2048 * 128;
    const u16* vbase = vTws + (size_t)bh * 256 * 2048;
    int tid = threadIdx.x, lane = tid & 63, w = tid >> 6, lr = lane & 15, lg = lane >> 4;
    bf8_t aq[4];
#pragma unroll
    for (int kk = 0; kk < 4; kk++)
        aq[kk] = *(const bf8_t*)((const char*)qbase + (size_t)(i0 + w * 16 + lr) * 256 + kk * 64 + lg * 16);
    f4_t racc[16];
#pragma unroll
    for (int f = 0; f < 16; f++)
#pragma unroll
        for (int e = 0; e < 4; e++) racc[f][e] = 0.f;
    for (int jt = jlo; jt < jhi; jt++) {
        int j0 = jt * 64;
        int diag = (jt == it);
        float tf = exp2f(64.f * (float)(it - jt) * lg2);
        __syncthreads();
#pragma unroll
        for (int p = 0; p < 4; p++) {                // stage K tile [64][128]
            int flat = p * 4096 + tid * 16;
            int row = flat >> 8, byt = (flat & 255) ^ ((row & 7) << 4);
            gll16((const char*)kbase + (size_t)(j0 + row) * 256 + byt, (char*)Ks + p * 4096 + w * 1024);
        }
#pragma unroll
        for (int p = 0; p < 8; p++) {                // stage Vt tile [256][64]
            int flat = p * 4096 + tid * 16;
            int row = flat >> 7, byt = (flat & 127) ^ ((row & 7) << 4);
            gll16((const char*)vbase + (size_t)row * 4096 + (size_t)j0 * 2 + byt,
                  (char*)Vs + p * 4096 + w * 1024);
        }
        __syncthreads();
        f4_t sacc[4];
#pragma unroll
        for (int f = 0; f < 4; f++)
#pragma unroll
            for (int e = 0; e < 4; e++) sacc[f][e] = 0.f;
#pragma unroll
        for (int kk = 0; kk < 4; kk++)
#pragma unroll
            for (int fn = 0; fn < 4; fn++) {
                int rb = fn * 16 + lr;
                bf8_t bb = *(const bf8_t*)((const char*)Ks + rb * 256 + ((kk * 64 + lg * 16) ^ ((rb & 7) << 4)));
                sacc[fn] = MFMA16(aq[kk], bb, sacc[fn]);
            }
        __syncthreads();                             // K reads done; alias Ks as P
#pragma unroll
        for (int fn = 0; fn < 4; fn++)
#pragma unroll
            for (int r = 0; r < 4; r++) {
                int i_loc = w * 16 + lg * 4 + r;
                int col = fn * 16 + lr;
                float v = diag ? ((i_loc - col >= 0) ? sacc[fn][r] : 0.f) : sacc[fn][r] * tf;
                *(u16*)((char*)Ks + i_loc * 128 + ((col * 2) ^ ((i_loc & 7) << 4))) = f2b(v);
            }
#pragma unroll
        for (int kk = 0; kk < 2; kk++) {
            int ra = w * 16 + lr;
            bf8_t ap = *(const bf8_t*)((const char*)Ks + ra * 128 + ((kk * 64 + lg * 16) ^ ((ra & 7) << 4)));
#pragma unroll
            for (int fn2 = 0; fn2 < 16; fn2++) {
                int rb = fn2 * 16 + lr;
                bf8_t bv = *(const bf8_t*)((const char*)Vs + rb * 128 + ((kk * 64 + lg * 16) ^ ((rb & 7) << 4)));
                racc[fn2] = MFMA16(ap, bv, racc[fn2]);
            }
        }
    }
    __syncthreads();
    u16* St = Vs;
#pragma unroll
    for (int fn2 = 0; fn2 < 16; fn2++)
#pragma unroll
        for (int r = 0; r < 4; r++) {
            int il = w * 16 + lg * 4 + r;
            int dv = fn2 * 16 + lr;
            *(u16*)((char*)St + il * 512 + ((dv * 2) ^ ((il & 15) << 4))) = f2b(racc[fn2][r]);
        }
    __syncthreads();
#pragma unroll
    for (int it2 = 0; it2 < 8; it2++) {
        int chunk = it2 * 256 + tid;
        int il = chunk >> 5, j = chunk & 31;
        uint4 v = *(const uint4*)((const char*)St + il * 512 + ((j * 16) ^ ((il & 15) << 4)));
        char* dst;
        if (toret1) dst = (char*)ret1 + ((size_t)(b * 1024 + i0 - 1024 + il) * 2048 + h * 256) * 2 + j * 16;
        else        dst = (char*)ret0 + ((size_t)(b * 2048 + i0 + il) * 2048 + h * 256) * 2 + j * 16;
        *(uint4*)dst = v;
    }
}

// ---------------- curr_kv partials: block = (t-range of 512, bh) ----------------
__global__ __launch_bounds__(512) void k_currkv(const u16* __restrict__ kTws, const u16* __restrict__ vTws,
                                                const float* __restrict__ gtab, float* __restrict__ part) {
    __shared__ u16 Ks2[128 * 64];
    __shared__ u16 Vws[256 * 64];
    int tr = blockIdx.x;            // 0..3
    int bh = blockIdx.y;            // 0..15
    int h = bh & 7;
    const u16* kT = kTws + (size_t)bh * 128 * 2048;
    const u16* vT = vTws + (size_t)bh * 256 * 2048;
    const float* gt = gtab + h * 2048;
    int tid = threadIdx.x, lane = tid & 63, wid = tid >> 6;
    int wr = wid >> 2, wc = wid & 3, lr = lane & 15, lg = lane >> 4;
    f4_t acc[4][4]; acc_zero(acc);
    for (int tc = 0; tc < 8; tc++) {
        int t0 = tr * 512 + tc * 64;
        __syncthreads();
#pragma unroll
        for (int p = 0; p < 2; p++) {
            int flat = p * 8192 + tid * 16;
            int row = flat >> 7, byt = (flat & 127) ^ ((row & 7) << 4);
            gll16((const char*)kT + (size_t)row * 4096 + (size_t)t0 * 2 + byt,
                  (char*)Ks2 + p * 8192 + wid * 1024);
        }
#pragma unroll
        for (int p = 0; p < 4; p++) {
            int flat = p * 8192 + tid * 16;
            int row = flat >> 7, byt = flat & 127;
            int tt = t0 + (byt >> 1);
            const u16* src = vT + (size_t)row * 2048 + tt;
            u16 tmp[8]; *(uint4*)tmp = *(const uint4*)src;
            const float* gp = gt + tt;
            u16 op[8];
#pragma unroll
            for (int e = 0; e < 8; e++) op[e] = f2b(b2f(tmp[e]) * gp[e]);
            *(uint4*)((char*)Vws + row * 128 + (byt ^ ((row & 7) << 4))) = *(uint4*)op;
        }
        __syncthreads();
#pragma unroll
        for (int kk = 0; kk < 2; kk++) {
            bf8_t a[4], bb[4];
#pragma unroll
            for (int f = 0; f < 4; f++) {
                int ra = wr * 64 + f * 16 + lr;
                a[f] = *(const bf8_t*)((const char*)Ks2 + ra * 128 + ((kk * 64 + lg * 16) ^ ((ra & 7) << 4)));
                int rb = wc * 64 + f * 16 + lr;
                bb[f] = *(const bf8_t*)((const char*)Vws + rb * 128 + ((kk * 64 + lg * 16) ^ ((rb & 7) << 4)));
            }
#pragma unroll
            for (int i = 0; i < 4; i++)
#pragma unroll
                for (int j = 0; j < 4; j++)
                    acc[i][j] = MFMA16(a[i], bb[j], acc[i][j]);
        }
    }
#pragma unroll
    for (int fm = 0; fm < 4; fm++)
#pragma unroll
        for (int fn = 0; fn < 4; fn++)
#pragma unroll
            for (int r = 0; r < 4; r++) {
                int dk = wr * 64 + fm * 16 + lg * 4 + r;
                int dv = wc * 64 + fn * 16 + lr;
                part[((size_t)(bh * 4 + tr)) * 32768 + (size_t)dk * 256 + dv] = acc[fm][fn][r];
            }
}

__global__ __launch_bounds__(256) void k_reduce_ckv(const float* __restrict__ part, float* __restrict__ outc) {
    int i = blockIdx.x * 256 + threadIdx.x;          // 524288
    int bh = i >> 15, wv = i & 32767;
    float s = 0.f;
#pragma unroll
    for (int tr = 0; tr < 4; tr++) s += part[((size_t)(bh * 4 + tr)) * 32768 + wv];
    outc[i] = s;
}

// ---------------- groupnorm(256) * silu-gate -> bf16 ----------------
__global__ __launch_bounds__(256) void k_gnorm(const u16* __restrict__ ret0, const u16* __restrict__ ret1,
                                               const u16* __restrict__ gateb, u16* __restrict__ gatedb) {
    int g = blockIdx.x * 4 + (threadIdx.x >> 6);     // wave per group
    int lane = threadIdx.x & 63;
    int row = g >> 3, h = g & 7;                     // row = b*2048 + t
    size_t base = (size_t)row * 2048 + h * 256 + lane * 4;
    u64 p0 = *(const u64*)(ret0 + base);
    float e0 = b2f((u16)p0), e1 = b2f((u16)(p0 >> 16)), e2 = b2f((u16)(p0 >> 32)), e3 = b2f((u16)(p0 >> 48));
    if ((row & 2047) >= 1024) {
        size_t b1 = (size_t)((row >> 11) * 1024 + (row & 1023)) * 2048 + h * 256 + lane * 4;
        u64 p1 = *(const u64*)(ret1 + b1);
        e0 += b2f((u16)p1); e1 += b2f((u16)(p1 >> 16)); e2 += b2f((u16)(p1 >> 32)); e3 += b2f((u16)(p1 >> 48));
    }
    float s = e0 + e1 + e2 + e3;
    float sqs = e0 * e0 + e1 * e1 + e2 * e2 + e3 * e3;
#pragma unroll
    for (int m = 1; m < 64; m <<= 1) { s += __shfl_xor(s, m); sqs += __shfl_xor(sqs, m); }
    float mean = s * (1.f / 256.f);
    float var = sqs * (1.f / 256.f) - mean * mean;
    float inv = rsqrtf(var + 1e-5f);
    u64 gp = *(const u64*)(gateb + base);
    u64 pk = (u64)f2b((e0 - mean) * inv * b2f((u16)gp)) |
             ((u64)f2b((e1 - mean) * inv * b2f((u16)(gp >> 16))) << 16) |
             ((u64)f2b((e2 - mean) * inv * b2f((u16)(gp >> 32))) << 32) |
             ((u64)f2b((e3 - mean) * inv * b2f((u16)(gp >> 48))) << 48);
    *(u64*)(gatedb + base) = pk;
}

extern "C" void kernel_launch(void* const* d_in, const int* in_sizes, int n_in,
                              void* d_out, int out_size, void* d_ws, size_t ws_size,
                              hipStream_t stream) {
    const float* x    = (const float*)d_in[0];
    const float* Wqkv = (const float*)d_in[1];
    const float* Wg   = (const float*)d_in[2];
    const float* Wp   = (const float*)d_in[3];
    const float* bp   = (const float*)d_in[4];
    float* outp   = (float*)d_out;
    float* outckv = outp + (size_t)BB * TT * HIDN;

    char* ws = (char*)d_ws;
    const size_t MB = 1024 * 1024;
    u16*   xb     = (u16*)(ws);               // 0..8
    u16*   WqkvT  = (u16*)(ws + 8 * MB);      // 8..16  [4096][1024]
    u16*   WgT    = (u16*)(ws + 16 * MB);     // 16..20 [2048][1024] (contiguous -> Wcat [6144][1024])
    u16*   WpT    = (u16*)(ws + 20 * MB);     // 20..24 [1024][2048]
    u32*   cqp    = (u32*)(ws + 24 * MB);     // 24..28 packed q table
    u32*   ckp    = (u32*)(ws + 28 * MB);     // 28..32 packed k table
    u16*   gateb  = (u16*)(ws + 32 * MB);     // 32..48 [4096][2048]
    u16*   qw     = (u16*)(ws + 48 * MB);     // 48..56 [bh][t][128] prescaled q
    u16*   kw     = (u16*)(ws + 56 * MB);     // 56..64 prescaled k
    u16*   kT     = (u16*)(ws + 64 * MB);     // 64..72 [bh][128][t] unscaled k
    u16*   vT     = (u16*)(ws + 72 * MB);     // 72..88 [bh][256][t]
    u16*   ret0b  = (u16*)(ws + 88 * MB);     // 88..104 bf16 [b][2048][2048]
    u16*   ret1b  = (u16*)(ws + 104 * MB);    // 104..112 bf16 [b][1024][2048]
    float* ckvp   = (float*)(ws + 112 * MB);  // 112..120
    float* gtab   = (float*)(ws + 120 * MB);            // 64KB
    float* gkt    = (float*)(ws + 120 * MB + 65536);    // 2KB
    // aliases:
    u16*   gatedb = (u16*)(ws + 48 * MB);     // 16MB over qw/kw (dead after retention)
    float* opart  = (float*)(ws + 88 * MB);   // 32MB over ret0b/ret1b/ckvp (dead after gnorm)

    hipLaunchKernelGGL(k_tables, dim3(4162), dim3(256), 0, stream, cqp, ckp, gtab, gkt);
    hipLaunchKernelGGL(k_cvt, dim3(4096), dim3(256), 0, stream, x, xb);
    hipLaunchKernelGGL(k_tposeF, dim3(8192), dim3(32, 8), 0, stream, Wqkv, Wg, Wp, WqkvT, WgT, WpT);
    hipLaunchKernelGGL(k_gemm_qkvg8, dim3(768), dim3(512), 0, stream,
                       xb, WqkvT, cqp, ckp, gkt, qw, kw, kT, vT, gateb);
    hipLaunchKernelGGL(k_currkv, dim3(4, 16), dim3(512), 0, stream, kT, vT, gtab, ckvp);
    hipLaunchKernelGGL(k_reduce_ckv, dim3(2048), dim3(256), 0, stream, ckvp, outckv);
    hipLaunchKernelGGL(k_retention, dim3(48, 8, 2), dim3(256), 0, stream, qw, kw, vT, ret0b, ret1b);
    hipLaunchKernelGGL(k_gnorm, dim3(8192), dim3(256), 0, stream, ret0b, ret1b, gateb, gatedb);
    hipLaunchKernelGGL(k_gemm_outp, dim3(8, 32, 2), dim3(256), 0, stream, gatedb, WpT, opart);
    hipLaunchKernelGGL(k_outred, dim3(4096), dim3(256), 0, stream, opart, bp, outp);
}

// Round 10
// 228.438 us; speedup vs baseline: 2.9278x; 1.0297x over previous
//
#include <hip/hip_runtime.h>

typedef unsigned short u16;
typedef unsigned int   u32;
typedef unsigned long long u64;

typedef __attribute__((ext_vector_type(8))) short bf8_t;   // 8 x bf16
typedef __attribute__((ext_vector_type(4))) float f4_t;

#define DEVI __device__ __forceinline__
#define MFMA16(a,b,c) __builtin_amdgcn_mfma_f32_16x16x32_bf16((a),(b),(c),0,0,0)

#define BB   2
#define TT   2048
#define HIDN 1024
#define L0f  (-3.4657359027997265f)   // ln(1/32)
#define DLf  (-0.3960841031714215f)   // (ln(1/512)-ln(1/32))/7
#define SCL  (0.08838834764831845f)   // 128^-0.5

DEVI u16 f2b(float f) {                 // f32 -> bf16 RNE
    u32 u = __float_as_uint(f);
    u += 0x7FFFu + ((u >> 16) & 1u);
    return (u16)(u >> 16);
}
DEVI float b2f(u16 u) { return __uint_as_float(((u32)u) << 16); }

// async global->LDS, 16B per lane; lds dest = wave-uniform base + lane*16
DEVI void gll16(const void* g, void* l) {
    __builtin_amdgcn_global_load_lds((const __attribute__((address_space(1))) void*)g,
                                     (__attribute__((address_space(3))) void*)l, 16, 0, 0);
}

// ------- packed xPos tables (blocks 0..4095) + gamma tables (blocks 4096..4161) -------
__global__ __launch_bounds__(256) void k_tables(u32* __restrict__ cqp, u32* __restrict__ ckp,
                                                float* __restrict__ gt, float* __restrict__ gk) {
    int bx = blockIdx.x;
    if (bx >= 4096) {                                // gamma tables
        int i = (bx - 4096) * 256 + threadIdx.x;     // 16896 entries
        if (i < 16384) {                             // gtab[h][t] = g^(2047-t)
            int h = i >> 11, t = i & 2047;
            float lg2 = log2f(1.f - expf(L0f + (float)h * DLf));
            gt[i] = exp2f((float)(2047 - t) * lg2);
        } else {                                     // gk[h][d] = g^-d
            int idx = i - 16384;                     // 512 entries
            int h = idx >> 6, d = idx & 63;
            float lg2 = log2f(1.f - expf(L0f + (float)h * DLf));
            gk[idx] = exp2f(-(float)d * lg2);
        }
        return;
    }
    int idx = bx * 256 + threadIdx.x;                // t*512 + m
    int t = idx >> 9, m = idx & 511;
    float base = (2.f * (float)m + 409.6f) * (1.f / 1433.6f);
    float s = exp2f(log2f(base) * ((float)t * (1.f / 512.f)));
    float invf = exp2f(-(float)m * (13.287712379549449f / 512.f)); // 10000^{-m/512}
    float sn, cs;
    sincosf((float)t * invf, &sn, &cs);
    int h = m >> 6;
    float lg2h = log2f(1.f - expf(L0f + (float)h * DLf));
    float qf = s * SCL * exp2f((float)(t & 63) * lg2h);
    cqp[idx] = (u32)f2b(cs * qf) | ((u32)f2b(sn * qf) << 16);
    float is = 1.f / s;
    ckp[idx] = (u32)f2b(cs * is) | ((u32)f2b(sn * is) << 16);
}

// ---------------- f32 -> bf16 convert (x) ----------------
__global__ __launch_bounds__(256) void k_cvt(const float* __restrict__ in, u16* __restrict__ out) {
    int i = blockIdx.x * 256 + threadIdx.x;
    float4 v = ((const float4*)in)[i];
    u64 pk = (u64)f2b(v.x) | ((u64)f2b(v.y) << 16) | ((u64)f2b(v.z) << 32) | ((u64)f2b(v.w) << 48);
    ((u64*)out)[i] = pk;
}

// ------- fused transpose+convert of all 3 weights: in[R][C] f32 -> out[C][R] bf16 -------
__global__ __launch_bounds__(256) void k_tposeF(const float* __restrict__ Wqkv,
                                                const float* __restrict__ Wg,
                                                const float* __restrict__ Wp,
                                                u16* __restrict__ oQ, u16* __restrict__ oG,
                                                u16* __restrict__ oP) {
    __shared__ float tile[32][33];
    int bx = blockIdx.x;
    const float* in; u16* out; int R, C, cx, ry;
    if (bx < 4096)      { in = Wqkv; out = oQ; R = 1024; C = 4096; cx = bx & 127;        ry = bx >> 7; }
    else if (bx < 6144) { int b2 = bx - 4096; in = Wg; out = oG; R = 1024; C = 2048; cx = b2 & 63; ry = b2 >> 6; }
    else                { int b2 = bx - 6144; in = Wp; out = oP; R = 2048; C = 1024; cx = b2 & 31; ry = b2 >> 5; }
    int c0 = cx * 32, r0 = ry * 32;
    int tx = threadIdx.x, ty = threadIdx.y;          // (32,8)
#pragma unroll
    for (int i = 0; i < 4; i++)
        tile[ty * 4 + i][tx] = in[(size_t)(r0 + ty * 4 + i) * C + c0 + tx];
    __syncthreads();
#pragma unroll
    for (int i = 0; i < 4; i++)
        out[(size_t)(c0 + ty * 4 + i) * R + r0 + tx] = f2b(tile[tx][ty * 4 + i]);
}

// =============== 256x256 8-wave, BK=64, dbuf-LDS GEMM1: round-7 base + counted vmcnt ========
DEVI void stage_tile(const u16* __restrict__ A, const u16* __restrict__ B,
                     int m0, int n0, int kt, char* buf, int tid, int wid) {
#pragma unroll
    for (int q = 0; q < 4; q++) {
        int flat = q * 8192 + tid * 16;
        int row = flat >> 7, byt = (flat & 127) ^ ((row & 7) << 4);
        gll16((const char*)A + (size_t)(m0 + row) * 2048 + kt * 128 + byt,
              buf + q * 8192 + wid * 1024);
        gll16((const char*)B + (size_t)(n0 + row) * 2048 + kt * 128 + byt,
              buf + 32768 + q * 8192 + wid * 1024);
    }
}

#define QPHASE(kk, fmh, LOADB)                                                        \
    {                                                                                 \
        bf8_t a_[4];                                                                  \
        _Pragma("unroll")                                                             \
        for (int f = 0; f < 4; f++) {                                                 \
            int ra = 128 * wr + ((fmh) * 4 + f) * 16 + lr;                            \
            a_[f] = *(const bf8_t*)(bA + ra * 128 + (((kk) * 64 + lg * 16) ^ ((ra & 7) << 4))); \
        }                                                                             \
        if (LOADB) {                                                                  \
            _Pragma("unroll")                                                         \
            for (int f = 0; f < 4; f++) {                                             \
                int rb = 64 * wc + f * 16 + lr;                                       \
                breg[f] = *(const bf8_t*)(bB + rb * 128 + (((kk) * 64 + lg * 16) ^ ((rb & 7) << 4))); \
            }                                                                         \
        }                                                                             \
        __builtin_amdgcn_s_barrier();                                                 \
        __builtin_amdgcn_s_setprio(1);                                                \
        _Pragma("unroll")                                                             \
        for (int f = 0; f < 4; f++)                                                   \
            _Pragma("unroll")                                                         \
            for (int j = 0; j < 4; j++)                                               \
                acc[(fmh) * 4 + f][j] = MFMA16(a_[f], breg[j], acc[(fmh) * 4 + f][j]); \
        __builtin_amdgcn_s_setprio(0);                                                \
        __builtin_amdgcn_s_barrier();                                                 \
    }

__global__ __launch_bounds__(512, 2) void k_gemm_qkvg8(
    const u16* __restrict__ xb, const u16* __restrict__ Wcat,
    const u32* __restrict__ cqp, const u32* __restrict__ ckp, const float* __restrict__ gkt,
    u16* __restrict__ qw, u16* __restrict__ kw, u16* __restrict__ kT, u16* __restrict__ vT,
    u16* __restrict__ gateb) {
    __shared__ __align__(16) char L[131072];         // 2 x (A 32KB + B 32KB)
    int flat = blockIdx.x;
    int swz = (flat & 7) * 48 + (flat >> 3);         // XCD-bijective (384 = 8*48), m-major (round-7)
    int m0 = (swz / 24) * 256, n0 = (swz % 24) * 256;
    int tid = threadIdx.x, lane = tid & 63, wid = tid >> 6;
    int wr = wid >> 2, wc = wid & 3, lr = lane & 15, lg = lane >> 4;
    f4_t acc[8][4];
#pragma unroll
    for (int i = 0; i < 8; i++)
#pragma unroll
        for (int j = 0; j < 4; j++)
#pragma unroll
            for (int e = 0; e < 4; e++) acc[i][j][e] = 0.f;
    stage_tile(xb, Wcat, m0, n0, 0, L, tid, wid);
    asm volatile("s_waitcnt vmcnt(0)" ::: "memory");
    __builtin_amdgcn_s_barrier();
    for (int kt = 0; kt < 16; ++kt) {
        const char* bA = L + (kt & 1) * 65536;
        const char* bB = bA + 32768;
        if (kt < 15) {
            stage_tile(xb, Wcat, m0, n0, kt + 1, L + ((kt + 1) & 1) * 65536, tid, wid);
            asm volatile("s_waitcnt vmcnt(8)" ::: "memory");   // tile-kt landed; kt+1 stays in flight
        } else {
            asm volatile("s_waitcnt vmcnt(0)" ::: "memory");
        }
        __builtin_amdgcn_s_barrier();                // all waves' tile-kt data in LDS
        bf8_t breg[4];
        QPHASE(0, 0, 1)
        QPHASE(0, 1, 0)
        QPHASE(1, 0, 1)
        QPHASE(1, 1, 0)
        // final QPHASE barrier: all waves done reading buf[kt&1] -> safe to restage next iter
    }
    // ---------------- epilogue: stage 256x256 tile in L (rows of 512B), coalesced out ----------
    char* SP = L;
    int b = m0 >> 11, t0 = m0 & 2047;
    if (n0 < 4096 && n0 >= 2048) {                   // ---- v: stage transposed [dv][t] ----
        int h = (n0 - 2048) >> 8;
#pragma unroll
        for (int fm = 0; fm < 8; fm++)
#pragma unroll
            for (int fn = 0; fn < 4; fn++) {
                int dv = wc * 64 + fn * 16 + lr;
                int rowb = wr * 128 + fm * 16 + lg * 4;
                u64 pk = 0;
#pragma unroll
                for (int r = 0; r < 4; r++) pk |= ((u64)f2b(acc[fm][fn][r])) << (16 * r);
                *(u64*)(SP + dv * 512 + ((rowb * 2) ^ ((dv & 15) << 4))) = pk;
            }
        __syncthreads();
#pragma unroll
        for (int it = 0; it < 16; it++) {
            int chunk = it * 512 + tid;
            int dv = chunk >> 5, j = chunk & 31;
            uint4 v = *(const uint4*)(SP + dv * 512 + ((j * 16) ^ ((dv & 15) << 4)));
            *(uint4*)(vT + ((size_t)((b * 8 + h) * 256 + dv)) * 2048 + t0 + j * 8) = v;
        }
    } else if (n0 < 2048) {                          // ---- q or k: rotate (+prescale) ----
        int isK = n0 >= 1024;
        const u32* cT = isK ? ckp : cqp;
        int hb = (n0 >> 7) & 7;
#pragma unroll
        for (int fm = 0; fm < 8; fm++)
#pragma unroll
            for (int fn = 0; fn < 4; fn++) {
                int col = wc * 64 + fn * 16 + lr;
                int gq = (n0 & 1023) + col;
                int mi = gq >> 1, h = gq >> 7;
                u64 pk = 0;
#pragma unroll
                for (int r = 0; r < 4; r++) {
                    int rowl = wr * 128 + fm * 16 + lg * 4 + r;
                    int t = t0 + rowl;
                    float v = acc[fm][fn][r];
                    float pv = __shfl_xor(v, 1);
                    u32 cp = cT[t * 512 + mi];
                    float cs = b2f((u16)cp), sn = b2f((u16)(cp >> 16));
                    float o = (col & 1) ? (v * cs + pv * sn) : (v * cs - pv * sn);
                    if (isK) {
                        pk |= ((u64)f2b(o)) << (16 * r);
                        o *= gkt[h * 64 + (t & 63)];
                    }
                    *(u16*)(SP + rowl * 512 + ((col * 2) ^ ((rowl & 15) << 4))) = f2b(o);
                }
                if (isK)
                    *(u64*)&kT[((size_t)((b * 8 + h) * 128 + (gq & 127))) * 2048 + t0 + wr * 128 + fm * 16 + lg * 4] = pk;
            }
        __syncthreads();
#pragma unroll
        for (int it = 0; it < 16; it++) {
            int chunk = it * 512 + tid;
            int r = chunk >> 5, j = chunk & 31;
            uint4 v = *(const uint4*)(SP + r * 512 + ((j * 16) ^ ((r & 15) << 4)));
            int hh = hb + (j >> 4);
            u16* g = (isK ? kw : qw) + ((size_t)((b * 8 + hh) * 2048 + t0 + r)) * 128 + (j & 15) * 8;
            *(uint4*)g = v;
        }
    } else {                                         // ---- gate: silu ----
        int c0 = n0 - 4096;
#pragma unroll
        for (int fm = 0; fm < 8; fm++)
#pragma unroll
            for (int fn = 0; fn < 4; fn++) {
                int col = wc * 64 + fn * 16 + lr;
#pragma unroll
                for (int r = 0; r < 4; r++) {
                    int rowl = wr * 128 + fm * 16 + lg * 4 + r;
                    float gg = acc[fm][fn][r];
                    *(u16*)(SP + rowl * 512 + ((col * 2) ^ ((rowl & 15) << 4))) = f2b(gg / (1.f + expf(-gg)));
                }
            }
        __syncthreads();
#pragma unroll
        for (int it = 0; it < 16; it++) {
            int chunk = it * 512 + tid;
            int r = chunk >> 5, j = chunk & 31;
            uint4 v = *(const uint4*)(SP + r * 512 + ((j * 16) ^ ((r & 15) << 4)));
            *(uint4*)(gateb + (size_t)(b * 2048 + t0 + r) * 2048 + c0 + j * 8) = v;
        }
    }
}

// ---------------- 128x128 (BK=64) MFMA mainloop (round-5 proven) ----------------
DEVI void gemm_ml(const u16* __restrict__ Ag, const u16* __restrict__ Bg, int Klen, int Kstr,
                  int m0, int n0, u16* As, u16* Bs, f4_t acc[4][4]) {
    int tid = threadIdx.x, lane = tid & 63, wid = tid >> 6;
    int wr = wid >> 1, wc = wid & 1, lr = lane & 15, lg = lane >> 4;
    for (int k0 = 0; k0 < Klen; k0 += 64) {
        __syncthreads();
#pragma unroll
        for (int p = 0; p < 4; p++) {
            int flat = p * 4096 + tid * 16;
            int row = flat >> 7, byt = (flat & 127) ^ ((row & 7) << 4);
            gll16((const char*)Ag + ((size_t)(m0 + row) * Kstr + k0) * 2 + byt,
                  (char*)As + p * 4096 + wid * 1024);
            gll16((const char*)Bg + ((size_t)(n0 + row) * Kstr + k0) * 2 + byt,
                  (char*)Bs + p * 4096 + wid * 1024);
        }
        __syncthreads();
#pragma unroll
        for (int kk = 0; kk < 2; kk++) {
            bf8_t a[4], b[4];
#pragma unroll
            for (int f = 0; f < 4; f++) {
                int ra = wr * 64 + f * 16 + lr;
                a[f] = *(const bf8_t*)((const char*)As + ra * 128 + ((kk * 64 + lg * 16) ^ ((ra & 7) << 4)));
                int rb = wc * 64 + f * 16 + lr;
                b[f] = *(const bf8_t*)((const char*)Bs + rb * 128 + ((kk * 64 + lg * 16) ^ ((rb & 7) << 4)));
            }
#pragma unroll
            for (int i = 0; i < 4; i++)
#pragma unroll
                for (int j = 0; j < 4; j++)
                    acc[i][j] = MFMA16(a[i], b[j], acc[i][j]);
        }
    }
}

DEVI void acc_zero(f4_t acc[4][4]) {
#pragma unroll
    for (int i = 0; i < 4; i++)
#pragma unroll
        for (int j = 0; j < 4; j++)
#pragma unroll
            for (int e = 0; e < 4; e++) acc[i][j][e] = 0.f;
}

// ---------------- GEMM3 (split-K=2): part[kz] = gated @ Wp slice (round-5 proven) ------
__global__ __launch_bounds__(256) void k_gemm_outp(const u16* __restrict__ gdb, const u16* __restrict__ Wt,
                                                   float* __restrict__ part) {
    __shared__ u16 SM[128 * 128];
    f4_t acc[4][4]; acc_zero(acc);
    int m0 = blockIdx.y * 128, n0 = blockIdx.x * 128, kz = blockIdx.z;
    gemm_ml(gdb + kz * 1024, Wt + kz * 1024, 1024, 2048, m0, n0, SM, SM + 128 * 64, acc);
    int tid = threadIdx.x, lane = tid & 63, wid = tid >> 6;
    int wr = wid >> 1, wc = wid & 1, lr = lane & 15, lg = lane >> 4;
    float* SMf = (float*)SM;
    float* po = part + (size_t)kz * 4096 * 1024;
    __syncthreads();
#pragma unroll
    for (int p = 0; p < 2; p++) {
        if (p) __syncthreads();
        if (wr == p) {
#pragma unroll
            for (int fm = 0; fm < 4; fm++)
#pragma unroll
                for (int fn = 0; fn < 4; fn++) {
                    int col = wc * 64 + fn * 16 + lr;
#pragma unroll
                    for (int r = 0; r < 4; r++) {
                        int rowl = fm * 16 + lg * 4 + r;
                        *(float*)((char*)SMf + rowl * 512 + ((col * 4) ^ ((rowl & 7) << 6))) = acc[fm][fn][r];
                    }
                }
        }
        __syncthreads();
#pragma unroll
        for (int it2 = 0; it2 < 8; it2++) {
            int chunk = it2 * 256 + tid;
            int rowl = chunk >> 5, j = chunk & 31;
            f4_t v = *(const f4_t*)((const char*)SMf + rowl * 512 + ((j * 16) ^ ((rowl & 7) << 6)));
            *(f4_t*)((char*)po + ((size_t)(m0 + p * 64 + rowl) * 1024 + n0) * 4 + j * 16) = v;
        }
    }
}

__global__ __launch_bounds__(256) void k_outred(const float* __restrict__ part, const float* __restrict__ bp,
                                                float* __restrict__ outp) {
    int i = blockIdx.x * 256 + threadIdx.x;          // 1M x f4
    f4_t a = ((const f4_t*)part)[i];
    f4_t c = ((const f4_t*)(part + (size_t)4096 * 1024))[i];
    f4_t bb = *(const f4_t*)(bp + ((i * 4) & 1023));
#pragma unroll
    for (int e = 0; e < 4; e++) a[e] += c[e] + bb[e];
    ((f4_t*)outp)[i] = a;
}

// ---------------- retention: Q in regs, factorized decay, wave-local PV ----------------
__global__ __launch_bounds__(256, 3) void k_retention(const u16* __restrict__ qws, const u16* __restrict__ kws,
                                                      const u16* __restrict__ vTws,
                                                      u16* __restrict__ ret0, u16* __restrict__ ret1) {
    __shared__ u16 SMr[64 * 128 + 256 * 64];         // 48KB
    u16* Ks = SMr;                                   // 16KB; P aliases it
    u16* Vs = SMr + 64 * 128;                        // 32KB; output staging aliases it
    int x = blockIdx.x;
    int it, jlo, jhi, toret1;
    if (x < 16)      { it = 15 - x;  jlo = 0;              jhi = it + 1;         toret1 = 0; }
    else if (x < 32) { it = x;       jlo = 0;              jhi = (it + 2) >> 1;  toret1 = 0; }
    else             { it = x - 16;  jlo = (it + 2) >> 1;  jhi = it + 1;         toret1 = 1; }
    int h = blockIdx.y, b = blockIdx.z;
    int bh = b * 8 + h;
    float lg2 = log2f(1.f - expf(L0f + (float)h * DLf));
    int i0 = it * 64;
    const u16* qbase = qws + (size_t)bh * 2048 * 128;
    const u16* kbase = kws + (size_t)bh * 2048 * 128;
    const u16* vbase = vTws + (size_t)bh * 256 * 2048;
    int tid = threadIdx.x, lane = tid & 63, w = tid >> 6, lr = lane & 15, lg = lane >> 4;
    bf8_t aq[4];
#pragma unroll
    for (int kk = 0; kk < 4; kk++)
        aq[kk] = *(const bf8_t*)((const char*)qbase + (size_t)(i0 + w * 16 + lr) * 256 + kk * 64 + lg * 16);
    f4_t racc[16];
#pragma unroll
    for (int f = 0; f < 16; f++)
#pragma unroll
        for (int e = 0; e < 4; e++) racc[f][e] = 0.f;
    for (int jt = jlo; jt < jhi; jt++) {
        int j0 = jt * 64;
        int diag = (jt == it);
        float tf = exp2f(64.f * (float)(it - jt) * lg2);
        __syncthreads();
#pragma unroll
        for (int p = 0; p < 4; p++) {                // stage K tile [64][128]
            int flat = p * 4096 + tid * 16;
            int row = flat >> 8, byt = (flat & 255) ^ ((row & 7) << 4);
            gll16((const char*)kbase + (size_t)(j0 + row) * 256 + byt, (char*)Ks + p * 4096 + w * 1024);
        }
#pragma unroll
        for (int p = 0; p < 8; p++) {                // stage Vt tile [256][64]
            int flat = p * 4096 + tid * 16;
            int row = flat >> 7, byt = (flat & 127) ^ ((row & 7) << 4);
            gll16((const char*)vbase + (size_t)row * 4096 + (size_t)j0 * 2 + byt,
                  (char*)Vs + p * 4096 + w * 1024);
        }
        __syncthreads();
        f4_t sacc[4];
#pragma unroll
        for (int f = 0; f < 4; f++)
#pragma unroll
            for (int e = 0; e < 4; e++) sacc[f][e] = 0.f;
#pragma unroll
        for (int kk = 0; kk < 4; kk++)
#pragma unroll
            for (int fn = 0; fn < 4; fn++) {
                int rb = fn * 16 + lr;
                bf8_t bb = *(const bf8_t*)((const char*)Ks + rb * 256 + ((kk * 64 + lg * 16) ^ ((rb & 7) << 4)));
                sacc[fn] = MFMA16(aq[kk], bb, sacc[fn]);
            }
        __syncthreads();                             // K reads done; alias Ks as P
#pragma unroll
        for (int fn = 0; fn < 4; fn++)
#pragma unroll
            for (int r = 0; r < 4; r++) {
                int i_loc = w * 16 + lg * 4 + r;
                int col = fn * 16 + lr;
                float v = diag ? ((i_loc - col >= 0) ? sacc[fn][r] : 0.f) : sacc[fn][r] * tf;
                *(u16*)((char*)Ks + i_loc * 128 + ((col * 2) ^ ((i_loc & 7) << 4))) = f2b(v);
            }
#pragma unroll
        for (int kk = 0; kk < 2; kk++) {
            int ra = w * 16 + lr;
            bf8_t ap = *(const bf8_t*)((const char*)Ks + ra * 128 + ((kk * 64 + lg * 16) ^ ((ra & 7) << 4)));
#pragma unroll
            for (int fn2 = 0; fn2 < 16; fn2++) {
                int rb = fn2 * 16 + lr;
                bf8_t bv = *(const bf8_t*)((const char*)Vs + rb * 128 + ((kk * 64 + lg * 16) ^ ((rb & 7) << 4)));
                racc[fn2] = MFMA16(ap, bv, racc[fn2]);
            }
        }
    }
    __syncthreads();
    u16* St = Vs;
#pragma unroll
    for (int fn2 = 0; fn2 < 16; fn2++)
#pragma unroll
        for (int r = 0; r < 4; r++) {
            int il = w * 16 + lg * 4 + r;
            int dv = fn2 * 16 + lr;
            *(u16*)((char*)St + il * 512 + ((dv * 2) ^ ((il & 15) << 4))) = f2b(racc[fn2][r]);
        }
    __syncthreads();
#pragma unroll
    for (int it2 = 0; it2 < 8; it2++) {
        int chunk = it2 * 256 + tid;
        int il = chunk >> 5, j = chunk & 31;
        uint4 v = *(const uint4*)((const char*)St + il * 512 + ((j * 16) ^ ((il & 15) << 4)));
        char* dst;
        if (toret1) dst = (char*)ret1 + ((size_t)(b * 1024 + i0 - 1024 + il) * 2048 + h * 256) * 2 + j * 16;
        else        dst = (char*)ret0 + ((size_t)(b * 2048 + i0 + il) * 2048 + h * 256) * 2 + j * 16;
        *(uint4*)dst = v;
    }
}

// ---------------- curr_kv partials: block = (t-range of 512, bh) ----------------
__global__ __launch_bounds__(512) void k_currkv(const u16* __restrict__ kTws, const u16* __restrict__ vTws,
                                                const float* __restrict__ gtab, float* __restrict__ part) {
    __shared__ u16 Ks2[128 * 64];
    __shared__ u16 Vws[256 * 64];
    int tr = blockIdx.x;            // 0..3
    int bh = blockIdx.y;            // 0..15
    int h = bh & 7;
    const u16* kT = kTws + (size_t)bh * 128 * 2048;
    const u16* vT = vTws + (size_t)bh * 256 * 2048;
    const float* gt = gtab + h * 2048;
    int tid = threadIdx.x, lane = tid & 63, wid = tid >> 6;
    int wr = wid >> 2, wc = wid & 3, lr = lane & 15, lg = lane >> 4;
    f4_t acc[4][4]; acc_zero(acc);
    for (int tc = 0; tc < 8; tc++) {
        int t0 = tr * 512 + tc * 64;
        __syncthreads();
#pragma unroll
        for (int p = 0; p < 2; p++) {
            int flat = p * 8192 + tid * 16;
            int row = flat >> 7, byt = (flat & 127) ^ ((row & 7) << 4);
            gll16((const char*)kT + (size_t)row * 4096 + (size_t)t0 * 2 + byt,
                  (char*)Ks2 + p * 8192 + wid * 1024);
        }
#pragma unroll
        for (int p = 0; p < 4; p++) {
            int flat = p * 8192 + tid * 16;
            int row = flat >> 7, byt = flat & 127;
            int tt = t0 + (byt >> 1);
            const u16* src = vT + (size_t)row * 2048 + tt;
            u16 tmp[8]; *(uint4*)tmp = *(const uint4*)src;
            const float* gp = gt + tt;
            u16 op[8];
#pragma unroll
            for (int e = 0; e < 8; e++) op[e] = f2b(b2f(tmp[e]) * gp[e]);
            *(uint4*)((char*)Vws + row * 128 + (byt ^ ((row & 7) << 4))) = *(uint4*)op;
        }
        __syncthreads();
#pragma unroll
        for (int kk = 0; kk < 2; kk++) {
            bf8_t a[4], bb[4];
#pragma unroll
            for (int f = 0; f < 4; f++) {
                int ra = wr * 64 + f * 16 + lr;
                a[f] = *(const bf8_t*)((const char*)Ks2 + ra * 128 + ((kk * 64 + lg * 16) ^ ((ra & 7) << 4)));
                int rb = wc * 64 + f * 16 + lr;
                bb[f] = *(const bf8_t*)((const char*)Vws + rb * 128 + ((kk * 64 + lg * 16) ^ ((rb & 7) << 4)));
            }
#pragma unroll
            for (int i = 0; i < 4; i++)
#pragma unroll
                for (int j = 0; j < 4; j++)
                    acc[i][j] = MFMA16(a[i], bb[j], acc[i][j]);
        }
    }
#pragma unroll
    for (int fm = 0; fm < 4; fm++)
#pragma unroll
        for (int fn = 0; fn < 4; fn++)
#pragma unroll
            for (int r = 0; r < 4; r++) {
                int dk = wr * 64 + fm * 16 + lg * 4 + r;
                int dv = wc * 64 + fn * 16 + lr;
                part[((size_t)(bh * 4 + tr)) * 32768 + (size_t)dk * 256 + dv] = acc[fm][fn][r];
            }
}

__global__ __launch_bounds__(256) void k_reduce_ckv(const float* __restrict__ part, float* __restrict__ outc) {
    int i = blockIdx.x * 256 + threadIdx.x;          // 524288
    int bh = i >> 15, wv = i & 32767;
    float s = 0.f;
#pragma unroll
    for (int tr = 0; tr < 4; tr++) s += part[((size_t)(bh * 4 + tr)) * 32768 + wv];
    outc[i] = s;
}

// ---------------- groupnorm(256) * silu-gate -> bf16 ----------------
__global__ __launch_bounds__(256) void k_gnorm(const u16* __restrict__ ret0, const u16* __restrict__ ret1,
                                               const u16* __restrict__ gateb, u16* __restrict__ gatedb) {
    int g = blockIdx.x * 4 + (threadIdx.x >> 6);     // wave per group
    int lane = threadIdx.x & 63;
    int row = g >> 3, h = g & 7;                     // row = b*2048 + t
    size_t base = (size_t)row * 2048 + h * 256 + lane * 4;
    u64 p0 = *(const u64*)(ret0 + base);
    float e0 = b2f((u16)p0), e1 = b2f((u16)(p0 >> 16)), e2 = b2f((u16)(p0 >> 32)), e3 = b2f((u16)(p0 >> 48));
    if ((row & 2047) >= 1024) {
        size_t b1 = (size_t)((row >> 11) * 1024 + (row & 1023)) * 2048 + h * 256 + lane * 4;
        u64 p1 = *(const u64*)(ret1 + b1);
        e0 += b2f((u16)p1); e1 += b2f((u16)(p1 >> 16)); e2 += b2f((u16)(p1 >> 32)); e3 += b2f((u16)(p1 >> 48));
    }
    float s = e0 + e1 + e2 + e3;
    float sqs = e0 * e0 + e1 * e1 + e2 * e2 + e3 * e3;
#pragma unroll
    for (int m = 1; m < 64; m <<= 1) { s += __shfl_xor(s, m); sqs += __shfl_xor(sqs, m); }
    float mean = s * (1.f / 256.f);
    float var = sqs * (1.f / 256.f) - mean * mean;
    float inv = rsqrtf(var + 1e-5f);
    u64 gp = *(const u64*)(gateb + base);
    u64 pk = (u64)f2b((e0 - mean) * inv * b2f((u16)gp)) |
             ((u64)f2b((e1 - mean) * inv * b2f((u16)(gp >> 16))) << 16) |
             ((u64)f2b((e2 - mean) * inv * b2f((u16)(gp >> 32))) << 32) |
             ((u64)f2b((e3 - mean) * inv * b2f((u16)(gp >> 48))) << 48);
    *(u64*)(gatedb + base) = pk;
}

extern "C" void kernel_launch(void* const* d_in, const int* in_sizes, int n_in,
                              void* d_out, int out_size, void* d_ws, size_t ws_size,
                              hipStream_t stream) {
    const float* x    = (const float*)d_in[0];
    const float* Wqkv = (const float*)d_in[1];
    const float* Wg   = (const float*)d_in[2];
    const float* Wp   = (const float*)d_in[3];
    const float* bp   = (const float*)d_in[4];
    float* outp   = (float*)d_out;
    float* outckv = outp + (size_t)BB * TT * HIDN;

    char* ws = (char*)d_ws;
    const size_t MB = 1024 * 1024;
    u16*   xb     = (u16*)(ws);               // 0..8
    u16*   WqkvT  = (u16*)(ws + 8 * MB);      // 8..16  [4096][1024]
    u16*   WgT    = (u16*)(ws + 16 * MB);     // 16..20 [2048][1024] (contiguous -> Wcat [6144][1024])
    u16*   WpT    = (u16*)(ws + 20 * MB);     // 20..24 [1024][2048]
    u32*   cqp    = (u32*)(ws + 24 * MB);     // 24..28 packed q table
    u32*   ckp    = (u32*)(ws + 28 * MB);     // 28..32 packed k table
    u16*   gateb  = (u16*)(ws + 32 * MB);     // 32..48 [4096][2048]
    u16*   qw     = (u16*)(ws + 48 * MB);     // 48..56 [bh][t][128] prescaled q
    u16*   kw     = (u16*)(ws + 56 * MB);     // 56..64 prescaled k
    u16*   kT     = (u16*)(ws + 64 * MB);     // 64..72 [bh][128][t] unscaled k
    u16*   vT     = (u16*)(ws + 72 * MB);     // 72..88 [bh][256][t]
    u16*   ret0b  = (u16*)(ws + 88 * MB);     // 88..104 bf16 [b][2048][2048]
    u16*   ret1b  = (u16*)(ws + 104 * MB);    // 104..112 bf16 [b][1024][2048]
    float* ckvp   = (float*)(ws + 112 * MB);  // 112..120
    float* gtab   = (float*)(ws + 120 * MB);            // 64KB
    float* gkt    = (float*)(ws + 120 * MB + 65536);    // 2KB
    // aliases:
    u16*   gatedb = (u16*)(ws + 48 * MB);     // 16MB over qw/kw (dead after retention)
    float* opart  = (float*)(ws + 88 * MB);   // 32MB over ret0b/ret1b/ckvp (dead after gnorm)

    hipLaunchKernelGGL(k_tables, dim3(4162), dim3(256), 0, stream, cqp, ckp, gtab, gkt);
    hipLaunchKernelGGL(k_cvt, dim3(4096), dim3(256), 0, stream, x, xb);
    hipLaunchKernelGGL(k_tposeF, dim3(8192), dim3(32, 8), 0, stream, Wqkv, Wg, Wp, WqkvT, WgT, WpT);
    hipLaunchKernelGGL(k_gemm_qkvg8, dim3(384), dim3(512), 0, stream,
                       xb, WqkvT, cqp, ckp, gkt, qw, kw, kT, vT, gateb);
    hipLaunchKernelGGL(k_currkv, dim3(4, 16), dim3(512), 0, stream, kT, vT, gtab, ckvp);
    hipLaunchKernelGGL(k_reduce_ckv, dim3(2048), dim3(256), 0, stream, ckvp, outckv);
    hipLaunchKernelGGL(k_retention, dim3(48, 8, 2), dim3(256), 0, stream, qw, kw, vT, ret0b, ret1b);
    hipLaunchKernelGGL(k_gnorm, dim3(8192), dim3(256), 0, stream, ret0b, ret1b, gateb, gatedb);
    hipLaunchKernelGGL(k_gemm_outp, dim3(8, 32, 2), dim3(256), 0, stream, gatedb, WpT, opart);
    hipLaunchKernelGGL(k_outred, dim3(4096), dim3(256), 0, stream, opart, bp, outp);
}

// Round 12
// 225.820 us; speedup vs baseline: 2.9618x; 1.0116x over previous
//
#include <hip/hip_runtime.h>

typedef unsigned short u16;
typedef unsigned int   u32;
typedef unsigned long long u64;

typedef __attribute__((ext_vector_type(8))) short bf8_t;   // 8 x bf16
typedef __attribute__((ext_vector_type(4))) float f4_t;

#define DEVI __device__ __forceinline__
#define MFMA16(a,b,c) __builtin_amdgcn_mfma_f32_16x16x32_bf16((a),(b),(c),0,0,0)

#define BB   2
#define TT   2048
#define HIDN 1024
#define L0f  (-3.4657359027997265f)   // ln(1/32)
#define DLf  (-0.3960841031714215f)   // (ln(1/512)-ln(1/32))/7
#define SCL  (0.08838834764831845f)   // 128^-0.5

DEVI u16 f2b(float f) {                 // f32 -> bf16 RNE
    u32 u = __float_as_uint(f);
    u += 0x7FFFu + ((u >> 16) & 1u);
    return (u16)(u >> 16);
}
DEVI float b2f(u16 u) { return __uint_as_float(((u32)u) << 16); }

// async global->LDS, 16B per lane; lds dest = wave-uniform base + lane*16
DEVI void gll16(const void* g, void* l) {
    __builtin_amdgcn_global_load_lds((const __attribute__((address_space(1))) void*)g,
                                     (__attribute__((address_space(3))) void*)l, 16, 0, 0);
}

// ------- packed xPos tables (blocks 0..4095) + gamma tables (blocks 4096..4161) -------
__global__ __launch_bounds__(256) void k_tables(u32* __restrict__ cqp, u32* __restrict__ ckp,
                                                float* __restrict__ gt, float* __restrict__ gk) {
    int bx = blockIdx.x;
    if (bx >= 4096) {                                // gamma tables
        int i = (bx - 4096) * 256 + threadIdx.x;     // 16896 entries
        if (i < 16384) {                             // gtab[h][t] = g^(2047-t)
            int h = i >> 11, t = i & 2047;
            float lg2 = log2f(1.f - expf(L0f + (float)h * DLf));
            gt[i] = exp2f((float)(2047 - t) * lg2);
        } else {                                     // gk[h][d] = g^-d
            int idx = i - 16384;                     // 512 entries
            int h = idx >> 6, d = idx & 63;
            float lg2 = log2f(1.f - expf(L0f + (float)h * DLf));
            gk[idx] = exp2f(-(float)d * lg2);
        }
        return;
    }
    int idx = bx * 256 + threadIdx.x;                // t*512 + m
    int t = idx >> 9, m = idx & 511;
    float base = (2.f * (float)m + 409.6f) * (1.f / 1433.6f);
    float s = exp2f(log2f(base) * ((float)t * (1.f / 512.f)));
    float invf = exp2f(-(float)m * (13.287712379549449f / 512.f)); // 10000^{-m/512}
    float sn, cs;
    sincosf((float)t * invf, &sn, &cs);
    int h = m >> 6;
    float lg2h = log2f(1.f - expf(L0f + (float)h * DLf));
    float qf = s * SCL * exp2f((float)(t & 63) * lg2h);
    cqp[idx] = (u32)f2b(cs * qf) | ((u32)f2b(sn * qf) << 16);
    float is = 1.f / s;
    ckp[idx] = (u32)f2b(cs * is) | ((u32)f2b(sn * is) << 16);
}

// ---------------- f32 -> bf16 convert (x) ----------------
__global__ __launch_bounds__(256) void k_cvt(const float* __restrict__ in, u16* __restrict__ out) {
    int i = blockIdx.x * 256 + threadIdx.x;
    float4 v = ((const float4*)in)[i];
    u64 pk = (u64)f2b(v.x) | ((u64)f2b(v.y) << 16) | ((u64)f2b(v.z) << 32) | ((u64)f2b(v.w) << 48);
    ((u64*)out)[i] = pk;
}

// ------- fused transpose+convert of all 3 weights: in[R][C] f32 -> out[C][R] bf16 -------
__global__ __launch_bounds__(256) void k_tposeF(const float* __restrict__ Wqkv,
                                                const float* __restrict__ Wg,
                                                const float* __restrict__ Wp,
                                                u16* __restrict__ oQ, u16* __restrict__ oG,
                                                u16* __restrict__ oP) {
    __shared__ float tile[32][33];
    int bx = blockIdx.x;
    const float* in; u16* out; int R, C, cx, ry;
    if (bx < 4096)      { in = Wqkv; out = oQ; R = 1024; C = 4096; cx = bx & 127;        ry = bx >> 7; }
    else if (bx < 6144) { int b2 = bx - 4096; in = Wg; out = oG; R = 1024; C = 2048; cx = b2 & 63; ry = b2 >> 6; }
    else                { int b2 = bx - 6144; in = Wp; out = oP; R = 2048; C = 1024; cx = b2 & 31; ry = b2 >> 5; }
    int c0 = cx * 32, r0 = ry * 32;
    int tx = threadIdx.x, ty = threadIdx.y;          // (32,8)
#pragma unroll
    for (int i = 0; i < 4; i++)
        tile[ty * 4 + i][tx] = in[(size_t)(r0 + ty * 4 + i) * C + c0 + tx];
    __syncthreads();
#pragma unroll
    for (int i = 0; i < 4; i++)
        out[(size_t)(c0 + ty * 4 + i) * R + r0 + tx] = f2b(tile[tx][ty * 4 + i]);
}

// =============== 256x256 8-wave, BK=64, dbuf-LDS, fine-grained phase schedule ===============
// Chunks: A-chunk j (id j, j<4) = A rows [64j,64j+64) (8KB); B-chunk j (id 4+j) = B rows.
// UNIFORM issue order for ALL waves: [A0,A2,B4,B5,B6,B7,A1,A3] — first 6 = everything any
// wave reads in phases 0/2; last 2 = phase 1/3's A-chunks. Identical per-wave wait counts +
// barrier => block-wide completeness (fixes round-11 race).
DEVI void stage_chunk(const u16* __restrict__ A, const u16* __restrict__ B,
                      int m0, int n0, int kt, char* buf, int id, int wid, int lane) {
    int j = id & 3;
    int flat = j * 8192 + wid * 1024 + lane * 16;
    int row = flat >> 7, byt = (flat & 127) ^ ((row & 7) << 4);
    if (id < 4)
        gll16((const char*)A + (size_t)(m0 + row) * 2048 + kt * 128 + byt,
              buf + j * 8192 + wid * 1024);
    else
        gll16((const char*)B + (size_t)(n0 + row) * 2048 + kt * 128 + byt,
              buf + 32768 + j * 8192 + wid * 1024);
}

#define QCORE(kk, fmh, LOADB)                                                         \
    {                                                                                 \
        bf8_t a_[4];                                                                  \
        _Pragma("unroll")                                                             \
        for (int f = 0; f < 4; f++) {                                                 \
            int ra = 128 * wr + ((fmh) * 4 + f) * 16 + lr;                            \
            a_[f] = *(const bf8_t*)(bA + ra * 128 + (((kk) * 64 + lg * 16) ^ ((ra & 7) << 4))); \
        }                                                                             \
        if (LOADB) {                                                                  \
            _Pragma("unroll")                                                         \
            for (int f = 0; f < 4; f++) {                                             \
                int rb = 64 * wc + f * 16 + lr;                                       \
                breg[f] = *(const bf8_t*)(bB + rb * 128 + (((kk) * 64 + lg * 16) ^ ((rb & 7) << 4))); \
            }                                                                         \
        }                                                                             \
        __builtin_amdgcn_s_barrier();                                                 \
        __builtin_amdgcn_s_setprio(1);                                                \
        _Pragma("unroll")                                                             \
        for (int f = 0; f < 4; f++)                                                   \
            _Pragma("unroll")                                                         \
            for (int j = 0; j < 4; j++)                                               \
                acc[(fmh) * 4 + f][j] = MFMA16(a_[f], breg[j], acc[(fmh) * 4 + f][j]); \
        __builtin_amdgcn_s_setprio(0);                                                \
    }

__global__ __launch_bounds__(512, 2) void k_gemm_qkvg8(
    const u16* __restrict__ xb, const u16* __restrict__ Wcat,
    const u32* __restrict__ cqp, const u32* __restrict__ ckp, const float* __restrict__ gkt,
    u16* __restrict__ qw, u16* __restrict__ kw, u16* __restrict__ kT, u16* __restrict__ vT,
    u16* __restrict__ gateb) {
    __shared__ __align__(16) char L[131072];         // 2 x (A 32KB + B 32KB)
    int flat = blockIdx.x;
    int swz = (flat & 7) * 48 + (flat >> 3);         // XCD-bijective (384 = 8*48), m-major
    int m0 = (swz / 24) * 256, n0 = (swz % 24) * 256;
    int tid = threadIdx.x, lane = tid & 63, wid = tid >> 6;
    int wr = wid >> 2, wc = wid & 3, lr = lane & 15, lg = lane >> 4;
    f4_t acc[8][4];
#pragma unroll
    for (int i = 0; i < 8; i++)
#pragma unroll
        for (int j = 0; j < 4; j++)
#pragma unroll
            for (int e = 0; e < 4; e++) acc[i][j][e] = 0.f;
    // prologue: issue all 8 chunks of tile 0 in uniform order; ensure first 6
    stage_chunk(xb, Wcat, m0, n0, 0, L, 0, wid, lane);
    stage_chunk(xb, Wcat, m0, n0, 0, L, 2, wid, lane);
    stage_chunk(xb, Wcat, m0, n0, 0, L, 4, wid, lane);
    stage_chunk(xb, Wcat, m0, n0, 0, L, 5, wid, lane);
    stage_chunk(xb, Wcat, m0, n0, 0, L, 6, wid, lane);
    stage_chunk(xb, Wcat, m0, n0, 0, L, 7, wid, lane);
    stage_chunk(xb, Wcat, m0, n0, 0, L, 1, wid, lane);
    stage_chunk(xb, Wcat, m0, n0, 0, L, 3, wid, lane);
    asm volatile("s_waitcnt vmcnt(2)" ::: "memory");
    __builtin_amdgcn_s_barrier();
    for (int kt = 0; kt < 16; ++kt) {
        const char* bA = L + (kt & 1) * 65536;
        const char* bB = bA + 32768;
        char* nbuf = L + ((kt + 1) & 1) * 65536;
        bf8_t breg[4];
        // phase 0: MFMA(kk0,fmh0) reads A0/A2 + B(wc); issue next-tile A0,A2
        if (kt < 15) {
            stage_chunk(xb, Wcat, m0, n0, kt + 1, nbuf, 0, wid, lane);
            stage_chunk(xb, Wcat, m0, n0, kt + 1, nbuf, 2, wid, lane);
        }
        QCORE(0, 0, 1)
        if (kt < 15) { asm volatile("s_waitcnt vmcnt(2)" ::: "memory"); }  // tile-kt A1,A3 done
        else         { asm volatile("s_waitcnt vmcnt(0)" ::: "memory"); }
        __builtin_amdgcn_s_barrier();
        // phase 1: MFMA(kk0,fmh1) reads A1/A3; issue next-tile B4,B5
        if (kt < 15) {
            stage_chunk(xb, Wcat, m0, n0, kt + 1, nbuf, 4, wid, lane);
            stage_chunk(xb, Wcat, m0, n0, kt + 1, nbuf, 5, wid, lane);
        }
        QCORE(0, 1, 0)
        __builtin_amdgcn_s_barrier();
        // phase 2: MFMA(kk1,fmh0); issue next-tile B6,B7
        if (kt < 15) {
            stage_chunk(xb, Wcat, m0, n0, kt + 1, nbuf, 6, wid, lane);
            stage_chunk(xb, Wcat, m0, n0, kt + 1, nbuf, 7, wid, lane);
        }
        QCORE(1, 0, 1)
        __builtin_amdgcn_s_barrier();
        // phase 3: MFMA(kk1,fmh1); issue next-tile A1,A3
        if (kt < 15) {
            stage_chunk(xb, Wcat, m0, n0, kt + 1, nbuf, 1, wid, lane);
            stage_chunk(xb, Wcat, m0, n0, kt + 1, nbuf, 3, wid, lane);
        }
        QCORE(1, 1, 0)
        if (kt < 15) { asm volatile("s_waitcnt vmcnt(2)" ::: "memory"); }  // next tile first-6 done
        __builtin_amdgcn_s_barrier();
    }
    // ---------------- epilogue: stage 256x256 tile in L (rows of 512B), coalesced out ----------
    __syncthreads();                                 // drain remaining loads; release L
    char* SP = L;
    int b = m0 >> 11, t0 = m0 & 2047;
    if (n0 < 4096 && n0 >= 2048) {                   // ---- v: stage transposed [dv][t] ----
        int h = (n0 - 2048) >> 8;
#pragma unroll
        for (int fm = 0; fm < 8; fm++)
#pragma unroll
            for (int fn = 0; fn < 4; fn++) {
                int dv = wc * 64 + fn * 16 + lr;
                int rowb = wr * 128 + fm * 16 + lg * 4;
                u64 pk = 0;
#pragma unroll
                for (int r = 0; r < 4; r++) pk |= ((u64)f2b(acc[fm][fn][r])) << (16 * r);
                *(u64*)(SP + dv * 512 + ((rowb * 2) ^ ((dv & 15) << 4))) = pk;
            }
        __syncthreads();
#pragma unroll
        for (int it = 0; it < 16; it++) {
            int chunk = it * 512 + tid;
            int dv = chunk >> 5, j = chunk & 31;
            uint4 v = *(const uint4*)(SP + dv * 512 + ((j * 16) ^ ((dv & 15) << 4)));
            *(uint4*)(vT + ((size_t)((b * 8 + h) * 256 + dv)) * 2048 + t0 + j * 8) = v;
        }
    } else if (n0 < 2048) {                          // ---- q or k: rotate (+prescale) ----
        int isK = n0 >= 1024;
        const u32* cT = isK ? ckp : cqp;
        int hb = (n0 >> 7) & 7;
#pragma unroll
        for (int fm = 0; fm < 8; fm++)
#pragma unroll
            for (int fn = 0; fn < 4; fn++) {
                int col = wc * 64 + fn * 16 + lr;
                int gq = (n0 & 1023) + col;
                int mi = gq >> 1, h = gq >> 7;
                u64 pk = 0;
#pragma unroll
                for (int r = 0; r < 4; r++) {
                    int rowl = wr * 128 + fm * 16 + lg * 4 + r;
                    int t = t0 + rowl;
                    float v = acc[fm][fn][r];
                    float pv = __shfl_xor(v, 1);
                    u32 cp = cT[t * 512 + mi];
                    float cs = b2f((u16)cp), sn = b2f((u16)(cp >> 16));
                    float o = (col & 1) ? (v * cs + pv * sn) : (v * cs - pv * sn);
                    if (isK) {
                        pk |= ((u64)f2b(o)) << (16 * r);
                        o *= gkt[h * 64 + (t & 63)];
                    }
                    *(u16*)(SP + rowl * 512 + ((col * 2) ^ ((rowl & 15) << 4))) = f2b(o);
                }
                if (isK)
                    *(u64*)&kT[((size_t)((b * 8 + h) * 128 + (gq & 127))) * 2048 + t0 + wr * 128 + fm * 16 + lg * 4] = pk;
            }
        __syncthreads();
#pragma unroll
        for (int it = 0; it < 16; it++) {
            int chunk = it * 512 + tid;
            int r = chunk >> 5, j = chunk & 31;
            uint4 v = *(const uint4*)(SP + r * 512 + ((j * 16) ^ ((r & 15) << 4)));
            int hh = hb + (j >> 4);
            u16* g = (isK ? kw : qw) + ((size_t)((b * 8 + hh) * 2048 + t0 + r)) * 128 + (j & 15) * 8;
            *(uint4*)g = v;
        }
    } else {                                         // ---- gate: silu ----
        int c0 = n0 - 4096;
#pragma unroll
        for (int fm = 0; fm < 8; fm++)
#pragma unroll
            for (int fn = 0; fn < 4; fn++) {
                int col = wc * 64 + fn * 16 + lr;
#pragma unroll
                for (int r = 0; r < 4; r++) {
                    int rowl = wr * 128 + fm * 16 + lg * 4 + r;
                    float gg = acc[fm][fn][r];
                    *(u16*)(SP + rowl * 512 + ((col * 2) ^ ((rowl & 15) << 4))) = f2b(gg / (1.f + expf(-gg)));
                }
            }
        __syncthreads();
#pragma unroll
        for (int it = 0; it < 16; it++) {
            int chunk = it * 512 + tid;
            int r = chunk >> 5, j = chunk & 31;
            uint4 v = *(const uint4*)(SP + r * 512 + ((j * 16) ^ ((r & 15) << 4)));
            *(uint4*)(gateb + (size_t)(b * 2048 + t0 + r) * 2048 + c0 + j * 8) = v;
        }
    }
}

// ---------------- 128x128 (BK=64) MFMA mainloop (round-5 proven) ----------------
DEVI void gemm_ml(const u16* __restrict__ Ag, const u16* __restrict__ Bg, int Klen, int Kstr,
                  int m0, int n0, u16* As, u16* Bs, f4_t acc[4][4]) {
    int tid = threadIdx.x, lane = tid & 63, wid = tid >> 6;
    int wr = wid >> 1, wc = wid & 1, lr = lane & 15, lg = lane >> 4;
    for (int k0 = 0; k0 < Klen; k0 += 64) {
        __syncthreads();
#pragma unroll
        for (int p = 0; p < 4; p++) {
            int flat = p * 4096 + tid * 16;
            int row = flat >> 7, byt = (flat & 127) ^ ((row & 7) << 4);
            gll16((const char*)Ag + ((size_t)(m0 + row) * Kstr + k0) * 2 + byt,
                  (char*)As + p * 4096 + wid * 1024);
            gll16((const char*)Bg + ((size_t)(n0 + row) * Kstr + k0) * 2 + byt,
                  (char*)Bs + p * 4096 + wid * 1024);
        }
        __syncthreads();
#pragma unroll
        for (int kk = 0; kk < 2; kk++) {
            bf8_t a[4], b[4];
#pragma unroll
            for (int f = 0; f < 4; f++) {
                int ra = wr * 64 + f * 16 + lr;
                a[f] = *(const bf8_t*)((const char*)As + ra * 128 + ((kk * 64 + lg * 16) ^ ((ra & 7) << 4)));
                int rb = wc * 64 + f * 16 + lr;
                b[f] = *(const bf8_t*)((const char*)Bs + rb * 128 + ((kk * 64 + lg * 16) ^ ((rb & 7) << 4)));
            }
#pragma unroll
            for (int i = 0; i < 4; i++)
#pragma unroll
                for (int j = 0; j < 4; j++)
                    acc[i][j] = MFMA16(a[i], b[j], acc[i][j]);
        }
    }
}

DEVI void acc_zero(f4_t acc[4][4]) {
#pragma unroll
    for (int i = 0; i < 4; i++)
#pragma unroll
        for (int j = 0; j < 4; j++)
#pragma unroll
            for (int e = 0; e < 4; e++) acc[i][j][e] = 0.f;
}

// ---------------- GEMM3 (split-K=2): part[kz] = gated @ Wp slice (round-5 proven) ------
__global__ __launch_bounds__(256) void k_gemm_outp(const u16* __restrict__ gdb, const u16* __restrict__ Wt,
                                                   float* __restrict__ part) {
    __shared__ u16 SM[128 * 128];
    f4_t acc[4][4]; acc_zero(acc);
    int m0 = blockIdx.y * 128, n0 = blockIdx.x * 128, kz = blockIdx.z;
    gemm_ml(gdb + kz * 1024, Wt + kz * 1024, 1024, 2048, m0, n0, SM, SM + 128 * 64, acc);
    int tid = threadIdx.x, lane = tid & 63, wid = tid >> 6;
    int wr = wid >> 1, wc = wid & 1, lr = lane & 15, lg = lane >> 4;
    float* SMf = (float*)SM;
    float* po = part + (size_t)kz * 4096 * 1024;
    __syncthreads();
#pragma unroll
    for (int p = 0; p < 2; p++) {
        if (p) __syncthreads();
        if (wr == p) {
#pragma unroll
            for (int fm = 0; fm < 4; fm++)
#pragma unroll
                for (int fn = 0; fn < 4; fn++) {
                    int col = wc * 64 + fn * 16 + lr;
#pragma unroll
                    for (int r = 0; r < 4; r++) {
                        int rowl = fm * 16 + lg * 4 + r;
                        *(float*)((char*)SMf + rowl * 512 + ((col * 4) ^ ((rowl & 7) << 6))) = acc[fm][fn][r];
                    }
                }
        }
        __syncthreads();
#pragma unroll
        for (int it2 = 0; it2 < 8; it2++) {
            int chunk = it2 * 256 + tid;
            int rowl = chunk >> 5, j = chunk & 31;
            f4_t v = *(const f4_t*)((const char*)SMf + rowl * 512 + ((j * 16) ^ ((rowl & 7) << 6)));
            *(f4_t*)((char*)po + ((size_t)(m0 + p * 64 + rowl) * 1024 + n0) * 4 + j * 16) = v;
        }
    }
}

__global__ __launch_bounds__(256) void k_outred(const float* __restrict__ part, const float* __restrict__ bp,
                                                float* __restrict__ outp) {
    int i = blockIdx.x * 256 + threadIdx.x;          // 1M x f4
    f4_t a = ((const f4_t*)part)[i];
    f4_t c = ((const f4_t*)(part + (size_t)4096 * 1024))[i];
    f4_t bb = *(const f4_t*)(bp + ((i * 4) & 1023));
#pragma unroll
    for (int e = 0; e < 4; e++) a[e] += c[e] + bb[e];
    ((f4_t*)outp)[i] = a;
}

// ---------------- retention: Q in regs, factorized decay, wave-local PV ----------------
__global__ __launch_bounds__(256, 3) void k_retention(const u16* __restrict__ qws, const u16* __restrict__ kws,
                                                      const u16* __restrict__ vTws,
                                                      u16* __restrict__ ret0, u16* __restrict__ ret1) {
    __shared__ u16 SMr[64 * 128 + 256 * 64];         // 48KB
    u16* Ks = SMr;                                   // 16KB; P aliases it
    u16* Vs = SMr + 64 * 128;                        // 32KB; output staging aliases it
    int x = blockIdx.x;
    int it, jlo, jhi, toret1;
    if (x < 16)      { it = 15 - x;  jlo = 0;              jhi = it + 1;         toret1 = 0; }
    else if (x < 32) { it = x;       jlo = 0;              jhi = (it + 2) >> 1;  toret1 = 0; }
    else             { it = x - 16;  jlo = (it + 2) >> 1;  jhi = it + 1;         toret1 = 1; }
    int h = blockIdx.y, b = blockIdx.z;
    int bh = b * 8 + h;
    float lg2 = log2f(1.f - expf(L0f + (float)h * DLf));
    int i0 = it * 64;
    const u16* qbase = qws + (size_t)bh * 2048 * 128;
    const u16* kbase = kws + (size_t)bh * 2048 * 128;
    const u16* vbase = vTws + (size_t)bh * 256 * 2048;
    int tid = threadIdx.x, lane = tid & 63, w = tid >> 6, lr = lane & 15, lg = lane >> 4;
    bf8_t aq[4];
#pragma unroll
    for (int kk = 0; kk < 4; kk++)
        aq[kk] = *(const bf8_t*)((const char*)qbase + (size_t)(i0 + w * 16 + lr) * 256 + kk * 64 + lg * 16);
    f4_t racc[16];
#pragma unroll
    for (int f = 0; f < 16; f++)
#pragma unroll
        for (int e = 0; e < 4; e++) racc[f][e] = 0.f;
    for (int jt = jlo; jt < jhi; jt++) {
        int j0 = jt * 64;
        int diag = (jt == it);
        float tf = exp2f(64.f * (float)(it - jt) * lg2);
        __syncthreads();
#pragma unroll
        for (int p = 0; p < 4; p++) {                // stage K tile [64][128]
            int flat = p * 4096 + tid * 16;
            int row = flat >> 8, byt = (flat & 255) ^ ((row & 7) << 4);
            gll16((const char*)kbase + (size_t)(j0 + row) * 256 + byt, (char*)Ks + p * 4096 + w * 1024);
        }
#pragma unroll
        for (int p = 0; p < 8; p++) {                // stage Vt tile [256][64]
            int flat = p * 4096 + tid * 16;
            int row = flat >> 7, byt = (flat & 127) ^ ((row & 7) << 4);
            gll16((const char*)vbase + (size_t)row * 4096 + (size_t)j0 * 2 + byt,
                  (char*)Vs + p * 4096 + w * 1024);
        }
        __syncthreads();
        f4_t sacc[4];
#pragma unroll
        for (int f = 0; f < 4; f++)
#pragma unroll
            for (int e = 0; e < 4; e++) sacc[f][e] = 0.f;
#pragma unroll
        for (int kk = 0; kk < 4; kk++)
#pragma unroll
            for (int fn = 0; fn < 4; fn++) {
                int rb = fn * 16 + lr;
                bf8_t bb = *(const bf8_t*)((const char*)Ks + rb * 256 + ((kk * 64 + lg * 16) ^ ((rb & 7) << 4)));
                sacc[fn] = MFMA16(aq[kk], bb, sacc[fn]);
            }
        __syncthreads();                             // K reads done; alias Ks as P
#pragma unroll
        for (int fn = 0; fn < 4; fn++)
#pragma unroll
            for (int r = 0; r < 4; r++) {
                int i_loc = w * 16 + lg * 4 + r;
                int col = fn * 16 + lr;
                float v = diag ? ((i_loc - col >= 0) ? sacc[fn][r] : 0.f) : sacc[fn][r] * tf;
                *(u16*)((char*)Ks + i_loc * 128 + ((col * 2) ^ ((i_loc & 7) << 4))) = f2b(v);
            }
#pragma unroll
        for (int kk = 0; kk < 2; kk++) {
            int ra = w * 16 + lr;
            bf8_t ap = *(const bf8_t*)((const char*)Ks + ra * 128 + ((kk * 64 + lg * 16) ^ ((ra & 7) << 4)));
#pragma unroll
            for (int fn2 = 0; fn2 < 16; fn2++) {
                int rb = fn2 * 16 + lr;
                bf8_t bv = *(const bf8_t*)((const char*)Vs + rb * 128 + ((kk * 64 + lg * 16) ^ ((rb & 7) << 4)));
                racc[fn2] = MFMA16(ap, bv, racc[fn2]);
            }
        }
    }
    __syncthreads();
    u16* St = Vs;
#pragma unroll
    for (int fn2 = 0; fn2 < 16; fn2++)
#pragma unroll
        for (int r = 0; r < 4; r++) {
            int il = w * 16 + lg * 4 + r;
            int dv = fn2 * 16 + lr;
            *(u16*)((char*)St + il * 512 + ((dv * 2) ^ ((il & 15) << 4))) = f2b(racc[fn2][r]);
        }
    __syncthreads();
#pragma unroll
    for (int it2 = 0; it2 < 8; it2++) {
        int chunk = it2 * 256 + tid;
        int il = chunk >> 5, j = chunk & 31;
        uint4 v = *(const uint4*)((const char*)St + il * 512 + ((j * 16) ^ ((il & 15) << 4)));
        char* dst;
        if (toret1) dst = (char*)ret1 + ((size_t)(b * 1024 + i0 - 1024 + il) * 2048 + h * 256) * 2 + j * 16;
        else        dst = (char*)ret0 + ((size_t)(b * 2048 + i0 + il) * 2048 + h * 256) * 2 + j * 16;
        *(uint4*)dst = v;
    }
}

// ---------------- curr_kv partials: block = (t-range of 512, bh) ----------------
__global__ __launch_bounds__(512) void k_currkv(const u16* __restrict__ kTws, const u16* __restrict__ vTws,
                                                const float* __restrict__ gtab, float* __restrict__ part) {
    __shared__ u16 Ks2[128 * 64];
    __shared__ u16 Vws[256 * 64];
    int tr = blockIdx.x;            // 0..3
    int bh = blockIdx.y;            // 0..15
    int h = bh & 7;
    const u16* kT = kTws + (size_t)bh * 128 * 2048;
    const u16* vT = vTws + (size_t)bh * 256 * 2048;
    const float* gt = gtab + h * 2048;
    int tid = threadIdx.x, lane = tid & 63, wid = tid >> 6;
    int wr = wid >> 2, wc = wid & 3, lr = lane & 15, lg = lane >> 4;
    f4_t acc[4][4]; acc_zero(acc);
    for (int tc = 0; tc < 8; tc++) {
        int t0 = tr * 512 + tc * 64;
        __syncthreads();
#pragma unroll
        for (int p = 0; p < 2; p++) {
            int flat = p * 8192 + tid * 16;
            int row = flat >> 7, byt = (flat & 127) ^ ((row & 7) << 4);
            gll16((const char*)kT + (size_t)row * 4096 + (size_t)t0 * 2 + byt,
                  (char*)Ks2 + p * 8192 + wid * 1024);
        }
#pragma unroll
        for (int p = 0; p < 4; p++) {
            int flat = p * 8192 + tid * 16;
            int row = flat >> 7, byt = flat & 127;
            int tt = t0 + (byt >> 1);
            const u16* src = vT + (size_t)row * 2048 + tt;
            u16 tmp[8]; *(uint4*)tmp = *(const uint4*)src;
            const float* gp = gt + tt;
            u16 op[8];
#pragma unroll
            for (int e = 0; e < 8; e++) op[e] = f2b(b2f(tmp[e]) * gp[e]);
            *(uint4*)((char*)Vws + row * 128 + (byt ^ ((row & 7) << 4))) = *(uint4*)op;
        }
        __syncthreads();
#pragma unroll
        for (int kk = 0; kk < 2; kk++) {
            bf8_t a[4], bb[4];
#pragma unroll
            for (int f = 0; f < 4; f++) {
                int ra = wr * 64 + f * 16 + lr;
                a[f] = *(const bf8_t*)((const char*)Ks2 + ra * 128 + ((kk * 64 + lg * 16) ^ ((ra & 7) << 4)));
                int rb = wc * 64 + f * 16 + lr;
                bb[f] = *(const bf8_t*)((const char*)Vws + rb * 128 + ((kk * 64 + lg * 16) ^ ((rb & 7) << 4)));
            }
#pragma unroll
            for (int i = 0; i < 4; i++)
#pragma unroll
                for (int j = 0; j < 4; j++)
                    acc[i][j] = MFMA16(a[i], bb[j], acc[i][j]);
        }
    }
#pragma unroll
    for (int fm = 0; fm < 4; fm++)
#pragma unroll
        for (int fn = 0; fn < 4; fn++)
#pragma unroll
            for (int r = 0; r < 4; r++) {
                int dk = wr * 64 + fm * 16 + lg * 4 + r;
                int dv = wc * 64 + fn * 16 + lr;
                part[((size_t)(bh * 4 + tr)) * 32768 + (size_t)dk * 256 + dv] = acc[fm][fn][r];
            }
}

__global__ __launch_bounds__(256) void k_reduce_ckv(const float* __restrict__ part, float* __restrict__ outc) {
    int i = blockIdx.x * 256 + threadIdx.x;          // 524288
    int bh = i >> 15, wv = i & 32767;
    float s = 0.f;
#pragma unroll
    for (int tr = 0; tr < 4; tr++) s += part[((size_t)(bh * 4 + tr)) * 32768 + wv];
    outc[i] = s;
}

// ---------------- groupnorm(256) * silu-gate -> bf16 ----------------
__global__ __launch_bounds__(256) void k_gnorm(const u16* __restrict__ ret0, const u16* __restrict__ ret1,
                                               const u16* __restrict__ gateb, u16* __restrict__ gatedb) {
    int g = blockIdx.x * 4 + (threadIdx.x >> 6);     // wave per group
    int lane = threadIdx.x & 63;
    int row = g >> 3, h = g & 7;                     // row = b*2048 + t
    size_t base = (size_t)row * 2048 + h * 256 + lane * 4;
    u64 p0 = *(const u64*)(ret0 + base);
    float e0 = b2f((u16)p0), e1 = b2f((u16)(p0 >> 16)), e2 = b2f((u16)(p0 >> 32)), e3 = b2f((u16)(p0 >> 48));
    if ((row & 2047) >= 1024) {
        size_t b1 = (size_t)((row >> 11) * 1024 + (row & 1023)) * 2048 + h * 256 + lane * 4;
        u64 p1 = *(const u64*)(ret1 + b1);
        e0 += b2f((u16)p1); e1 += b2f((u16)(p1 >> 16)); e2 += b2f((u16)(p1 >> 32)); e3 += b2f((u16)(p1 >> 48));
    }
    float s = e0 + e1 + e2 + e3;
    float sqs = e0 * e0 + e1 * e1 + e2 * e2 + e3 * e3;
#pragma unroll
    for (int m = 1; m < 64; m <<= 1) { s += __shfl_xor(s, m); sqs += __shfl_xor(sqs, m); }
    float mean = s * (1.f / 256.f);
    float var = sqs * (1.f / 256.f) - mean * mean;
    float inv = rsqrtf(var + 1e-5f);
    u64 gp = *(const u64*)(gateb + base);
    u64 pk = (u64)f2b((e0 - mean) * inv * b2f((u16)gp)) |
             ((u64)f2b((e1 - mean) * inv * b2f((u16)(gp >> 16))) << 16) |
             ((u64)f2b((e2 - mean) * inv * b2f((u16)(gp >> 32))) << 32) |
             ((u64)f2b((e3 - mean) * inv * b2f((u16)(gp >> 48))) << 48);
    *(u64*)(gatedb + base) = pk;
}

extern "C" void kernel_launch(void* const* d_in, const int* in_sizes, int n_in,
                              void* d_out, int out_size, void* d_ws, size_t ws_size,
                              hipStream_t stream) {
    const float* x    = (const float*)d_in[0];
    const float* Wqkv = (const float*)d_in[1];
    const float* Wg   = (const float*)d_in[2];
    const float* Wp   = (const float*)d_in[3];
    const float* bp   = (const float*)d_in[4];
    float* outp   = (float*)d_out;
    float* outckv = outp + (size_t)BB * TT * HIDN;

    char* ws = (char*)d_ws;
    const size_t MB = 1024 * 1024;
    u16*   xb     = (u16*)(ws);               // 0..8
    u16*   WqkvT  = (u16*)(ws + 8 * MB);      // 8..16  [4096][1024]
    u16*   WgT    = (u16*)(ws + 16 * MB);     // 16..20 [2048][1024] (contiguous -> Wcat [6144][1024])
    u16*   WpT    = (u16*)(ws + 20 * MB);     // 20..24 [1024][2048]
    u32*   cqp    = (u32*)(ws + 24 * MB);     // 24..28 packed q table
    u32*   ckp    = (u32*)(ws + 28 * MB);     // 28..32 packed k table
    u16*   gateb  = (u16*)(ws + 32 * MB);     // 32..48 [4096][2048]
    u16*   qw     = (u16*)(ws + 48 * MB);     // 48..56 [bh][t][128] prescaled q
    u16*   kw     = (u16*)(ws + 56 * MB);     // 56..64 prescaled k
    u16*   kT     = (u16*)(ws + 64 * MB);     // 64..72 [bh][128][t] unscaled k
    u16*   vT     = (u16*)(ws + 72 * MB);     // 72..88 [bh][256][t]
    u16*   ret0b  = (u16*)(ws + 88 * MB);     // 88..104 bf16 [b][2048][2048]
    u16*   ret1b  = (u16*)(ws + 104 * MB);    // 104..112 bf16 [b][1024][2048]
    float* ckvp   = (float*)(ws + 112 * MB);  // 112..120
    float* gtab   = (float*)(ws + 120 * MB);            // 64KB
    float* gkt    = (float*)(ws + 120 * MB + 65536);    // 2KB
    // aliases:
    u16*   gatedb = (u16*)(ws + 48 * MB);     // 16MB over qw/kw (dead after retention)
    float* opart  = (float*)(ws + 88 * MB);   // 32MB over ret0b/ret1b/ckvp (dead after gnorm)

    hipLaunchKernelGGL(k_tables, dim3(4162), dim3(256), 0, stream, cqp, ckp, gtab, gkt);
    hipLaunchKernelGGL(k_cvt, dim3(4096), dim3(256), 0, stream, x, xb);
    hipLaunchKernelGGL(k_tposeF, dim3(8192), dim3(32, 8), 0, stream, Wqkv, Wg, Wp, WqkvT, WgT, WpT);
    hipLaunchKernelGGL(k_gemm_qkvg8, dim3(384), dim3(512), 0, stream,
                       xb, WqkvT, cqp, ckp, gkt, qw, kw, kT, vT, gateb);
    hipLaunchKernelGGL(k_currkv, dim3(4, 16), dim3(512), 0, stream, kT, vT, gtab, ckvp);
    hipLaunchKernelGGL(k_reduce_ckv, dim3(2048), dim3(256), 0, stream, ckvp, outckv);
    hipLaunchKernelGGL(k_retention, dim3(48, 8, 2), dim3(256), 0, stream, qw, kw, vT, ret0b, ret1b);
    hipLaunchKernelGGL(k_gnorm, dim3(8192), dim3(256), 0, stream, ret0b, ret1b, gateb, gatedb);
    hipLaunchKernelGGL(k_gemm_outp, dim3(8, 32, 2), dim3(256), 0, stream, gatedb, WpT, opart);
    hipLaunchKernelGGL(k_outred, dim3(4096), dim3(256), 0, stream, opart, bp, outp);
}

// Round 13
// 216.662 us; speedup vs baseline: 3.0870x; 1.0423x over previous
//
#include <hip/hip_runtime.h>

typedef unsigned short u16;
typedef unsigned int   u32;
typedef unsigned long long u64;

typedef __attribute__((ext_vector_type(8))) short bf8_t;   // 8 x bf16
typedef __attribute__((ext_vector_type(4))) float f4_t;

#define DEVI __device__ __forceinline__
#define MFMA16(a,b,c) __builtin_amdgcn_mfma_f32_16x16x32_bf16((a),(b),(c),0,0,0)

#define BB   2
#define TT   2048
#define HIDN 1024
#define L0f  (-3.4657359027997265f)   // ln(1/32)
#define DLf  (-0.3960841031714215f)   // (ln(1/512)-ln(1/32))/7
#define SCL  (0.08838834764831845f)   // 128^-0.5

DEVI u16 f2b(float f) {                 // f32 -> bf16 RNE
    u32 u = __float_as_uint(f);
    u += 0x7FFFu + ((u >> 16) & 1u);
    return (u16)(u >> 16);
}
DEVI float b2f(u16 u) { return __uint_as_float(((u32)u) << 16); }

// async global->LDS, 16B per lane; lds dest = wave-uniform base + lane*16
DEVI void gll16(const void* g, void* l) {
    __builtin_amdgcn_global_load_lds((const __attribute__((address_space(1))) void*)g,
                                     (__attribute__((address_space(3))) void*)l, 16, 0, 0);
}

// ------- packed xPos tables (blocks 0..4095) + gamma tables (blocks 4096..4161) -------
__global__ __launch_bounds__(256) void k_tables(u32* __restrict__ cqp, u32* __restrict__ ckp,
                                                float* __restrict__ gt, float* __restrict__ gk) {
    int bx = blockIdx.x;
    if (bx >= 4096) {                                // gamma tables
        int i = (bx - 4096) * 256 + threadIdx.x;     // 16896 entries
        if (i < 16384) {                             // gtab[h][t] = g^(2047-t)
            int h = i >> 11, t = i & 2047;
            float lg2 = log2f(1.f - expf(L0f + (float)h * DLf));
            gt[i] = exp2f((float)(2047 - t) * lg2);
        } else {                                     // gk[h][d] = g^-d
            int idx = i - 16384;                     // 512 entries
            int h = idx >> 6, d = idx & 63;
            float lg2 = log2f(1.f - expf(L0f + (float)h * DLf));
            gk[idx] = exp2f(-(float)d * lg2);
        }
        return;
    }
    int idx = bx * 256 + threadIdx.x;                // t*512 + m
    int t = idx >> 9, m = idx & 511;
    float base = (2.f * (float)m + 409.6f) * (1.f / 1433.6f);
    float s = exp2f(log2f(base) * ((float)t * (1.f / 512.f)));
    float invf = exp2f(-(float)m * (13.287712379549449f / 512.f)); // 10000^{-m/512}
    float sn, cs;
    sincosf((float)t * invf, &sn, &cs);
    int h = m >> 6;
    float lg2h = log2f(1.f - expf(L0f + (float)h * DLf));
    float qf = s * SCL * exp2f((float)(t & 63) * lg2h);
    cqp[idx] = (u32)f2b(cs * qf) | ((u32)f2b(sn * qf) << 16);
    float is = 1.f / s;
    ckp[idx] = (u32)f2b(cs * is) | ((u32)f2b(sn * is) << 16);
}

// ---------------- f32 -> bf16 convert (x) ----------------
__global__ __launch_bounds__(256) void k_cvt(const float* __restrict__ in, u16* __restrict__ out) {
    int i = blockIdx.x * 256 + threadIdx.x;
    float4 v = ((const float4*)in)[i];
    u64 pk = (u64)f2b(v.x) | ((u64)f2b(v.y) << 16) | ((u64)f2b(v.z) << 32) | ((u64)f2b(v.w) << 48);
    ((u64*)out)[i] = pk;
}

// ------- fused transpose+convert of all 3 weights: in[R][C] f32 -> out[C][R] bf16 -------
__global__ __launch_bounds__(256) void k_tposeF(const float* __restrict__ Wqkv,
                                                const float* __restrict__ Wg,
                                                const float* __restrict__ Wp,
                                                u16* __restrict__ oQ, u16* __restrict__ oG,
                                                u16* __restrict__ oP) {
    __shared__ float tile[32][33];
    int bx = blockIdx.x;
    const float* in; u16* out; int R, C, cx, ry;
    if (bx < 4096)      { in = Wqkv; out = oQ; R = 1024; C = 4096; cx = bx & 127;        ry = bx >> 7; }
    else if (bx < 6144) { int b2 = bx - 4096; in = Wg; out = oG; R = 1024; C = 2048; cx = b2 & 63; ry = b2 >> 6; }
    else                { int b2 = bx - 6144; in = Wp; out = oP; R = 2048; C = 1024; cx = b2 & 31; ry = b2 >> 5; }
    int c0 = cx * 32, r0 = ry * 32;
    int tx = threadIdx.x, ty = threadIdx.y;          // (32,8)
#pragma unroll
    for (int i = 0; i < 4; i++)
        tile[ty * 4 + i][tx] = in[(size_t)(r0 + ty * 4 + i) * C + c0 + tx];
    __syncthreads();
#pragma unroll
    for (int i = 0; i < 4; i++)
        out[(size_t)(c0 + ty * 4 + i) * R + r0 + tx] = f2b(tile[tx][ty * 4 + i]);
}

// =============== 256x256 8-wave, BK=64, dbuf-LDS, fine-grained phase schedule ===============
DEVI void stage_chunk(const u16* __restrict__ A, const u16* __restrict__ B,
                      int m0, int n0, int kt, char* buf, int id, int wid, int lane) {
    int j = id & 3;
    int flat = j * 8192 + wid * 1024 + lane * 16;
    int row = flat >> 7, byt = (flat & 127) ^ ((row & 7) << 4);
    if (id < 4)
        gll16((const char*)A + (size_t)(m0 + row) * 2048 + kt * 128 + byt,
              buf + j * 8192 + wid * 1024);
    else
        gll16((const char*)B + (size_t)(n0 + row) * 2048 + kt * 128 + byt,
              buf + 32768 + j * 8192 + wid * 1024);
}

#define QCORE(kk, fmh, LOADB)                                                         \
    {                                                                                 \
        bf8_t a_[4];                                                                  \
        _Pragma("unroll")                                                             \
        for (int f = 0; f < 4; f++) {                                                 \
            int ra = 128 * wr + ((fmh) * 4 + f) * 16 + lr;                            \
            a_[f] = *(const bf8_t*)(bA + ra * 128 + (((kk) * 64 + lg * 16) ^ ((ra & 7) << 4))); \
        }                                                                             \
        if (LOADB) {                                                                  \
            _Pragma("unroll")                                                         \
            for (int f = 0; f < 4; f++) {                                             \
                int rb = 64 * wc + f * 16 + lr;                                       \
                breg[f] = *(const bf8_t*)(bB + rb * 128 + (((kk) * 64 + lg * 16) ^ ((rb & 7) << 4))); \
            }                                                                         \
        }                                                                             \
        __builtin_amdgcn_s_barrier();                                                 \
        __builtin_amdgcn_s_setprio(1);                                                \
        _Pragma("unroll")                                                             \
        for (int f = 0; f < 4; f++)                                                   \
            _Pragma("unroll")                                                         \
            for (int j = 0; j < 4; j++)                                               \
                acc[(fmh) * 4 + f][j] = MFMA16(a_[f], breg[j], acc[(fmh) * 4 + f][j]); \
        __builtin_amdgcn_s_setprio(0);                                                \
    }

__global__ __launch_bounds__(512, 2) void k_gemm_qkvg8(
    const u16* __restrict__ xb, const u16* __restrict__ Wcat,
    const u32* __restrict__ cqp, const u32* __restrict__ ckp, const float* __restrict__ gkt,
    u16* __restrict__ qw, u16* __restrict__ kw, u16* __restrict__ kT, u16* __restrict__ vT,
    u16* __restrict__ gateb) {
    __shared__ __align__(16) char L[131072];         // 2 x (A 32KB + B 32KB)
    int flat = blockIdx.x;
    int swz = (flat & 7) * 48 + (flat >> 3);         // XCD-bijective (384 = 8*48), m-major
    int m0 = (swz / 24) * 256, n0 = (swz % 24) * 256;
    int tid = threadIdx.x, lane = tid & 63, wid = tid >> 6;
    int wr = wid >> 2, wc = wid & 3, lr = lane & 15, lg = lane >> 4;
    f4_t acc[8][4];
#pragma unroll
    for (int i = 0; i < 8; i++)
#pragma unroll
        for (int j = 0; j < 4; j++)
#pragma unroll
            for (int e = 0; e < 4; e++) acc[i][j][e] = 0.f;
    // prologue: issue all 8 chunks of tile 0 in uniform order; ensure first 6
    stage_chunk(xb, Wcat, m0, n0, 0, L, 0, wid, lane);
    stage_chunk(xb, Wcat, m0, n0, 0, L, 2, wid, lane);
    stage_chunk(xb, Wcat, m0, n0, 0, L, 4, wid, lane);
    stage_chunk(xb, Wcat, m0, n0, 0, L, 5, wid, lane);
    stage_chunk(xb, Wcat, m0, n0, 0, L, 6, wid, lane);
    stage_chunk(xb, Wcat, m0, n0, 0, L, 7, wid, lane);
    stage_chunk(xb, Wcat, m0, n0, 0, L, 1, wid, lane);
    stage_chunk(xb, Wcat, m0, n0, 0, L, 3, wid, lane);
    asm volatile("s_waitcnt vmcnt(2)" ::: "memory");
    __builtin_amdgcn_s_barrier();
    for (int kt = 0; kt < 16; ++kt) {
        const char* bA = L + (kt & 1) * 65536;
        const char* bB = bA + 32768;
        char* nbuf = L + ((kt + 1) & 1) * 65536;
        bf8_t breg[4];
        // phase 0: MFMA(kk0,fmh0) reads A0/A2 + B(wc); issue next-tile A0,A2
        if (kt < 15) {
            stage_chunk(xb, Wcat, m0, n0, kt + 1, nbuf, 0, wid, lane);
            stage_chunk(xb, Wcat, m0, n0, kt + 1, nbuf, 2, wid, lane);
        }
        QCORE(0, 0, 1)
        if (kt < 15) { asm volatile("s_waitcnt vmcnt(2)" ::: "memory"); }  // tile-kt A1,A3 done
        else         { asm volatile("s_waitcnt vmcnt(0)" ::: "memory"); }
        __builtin_amdgcn_s_barrier();
        // phase 1: MFMA(kk0,fmh1) reads A1/A3; issue next-tile B4,B5
        if (kt < 15) {
            stage_chunk(xb, Wcat, m0, n0, kt + 1, nbuf, 4, wid, lane);
            stage_chunk(xb, Wcat, m0, n0, kt + 1, nbuf, 5, wid, lane);
        }
        QCORE(0, 1, 0)
        __builtin_amdgcn_s_barrier();
        // phase 2: MFMA(kk1,fmh0); issue next-tile B6,B7
        if (kt < 15) {
            stage_chunk(xb, Wcat, m0, n0, kt + 1, nbuf, 6, wid, lane);
            stage_chunk(xb, Wcat, m0, n0, kt + 1, nbuf, 7, wid, lane);
        }
        QCORE(1, 0, 1)
        __builtin_amdgcn_s_barrier();
        // phase 3: MFMA(kk1,fmh1); issue next-tile A1,A3
        if (kt < 15) {
            stage_chunk(xb, Wcat, m0, n0, kt + 1, nbuf, 1, wid, lane);
            stage_chunk(xb, Wcat, m0, n0, kt + 1, nbuf, 3, wid, lane);
        }
        QCORE(1, 1, 0)
        if (kt < 15) { asm volatile("s_waitcnt vmcnt(2)" ::: "memory"); }  // next tile first-6 done
        __builtin_amdgcn_s_barrier();
    }
    // ---------------- epilogue: stage 256x256 tile in L (rows of 512B), coalesced out ----------
    __syncthreads();                                 // drain remaining loads; release L
    char* SP = L;
    int b = m0 >> 11, t0 = m0 & 2047;
    if (n0 < 4096 && n0 >= 2048) {                   // ---- v: stage transposed [dv][t] ----
        int h = (n0 - 2048) >> 8;
#pragma unroll
        for (int fm = 0; fm < 8; fm++)
#pragma unroll
            for (int fn = 0; fn < 4; fn++) {
                int dv = wc * 64 + fn * 16 + lr;
                int rowb = wr * 128 + fm * 16 + lg * 4;
                u64 pk = 0;
#pragma unroll
                for (int r = 0; r < 4; r++) pk |= ((u64)f2b(acc[fm][fn][r])) << (16 * r);
                *(u64*)(SP + dv * 512 + ((rowb * 2) ^ ((dv & 15) << 4))) = pk;
            }
        __syncthreads();
#pragma unroll
        for (int it = 0; it < 16; it++) {
            int chunk = it * 512 + tid;
            int dv = chunk >> 5, j = chunk & 31;
            uint4 v = *(const uint4*)(SP + dv * 512 + ((j * 16) ^ ((dv & 15) << 4)));
            *(uint4*)(vT + ((size_t)((b * 8 + h) * 256 + dv)) * 2048 + t0 + j * 8) = v;
        }
    } else if (n0 < 2048) {                          // ---- q or k: rotate (+prescale) ----
        int isK = n0 >= 1024;
        const u32* cT = isK ? ckp : cqp;
        int hb = (n0 >> 7) & 7;
#pragma unroll
        for (int fm = 0; fm < 8; fm++)
#pragma unroll
            for (int fn = 0; fn < 4; fn++) {
                int col = wc * 64 + fn * 16 + lr;
                int gq = (n0 & 1023) + col;
                int mi = gq >> 1, h = gq >> 7;
                u64 pk = 0;
#pragma unroll
                for (int r = 0; r < 4; r++) {
                    int rowl = wr * 128 + fm * 16 + lg * 4 + r;
                    int t = t0 + rowl;
                    float v = acc[fm][fn][r];
                    float pv = __shfl_xor(v, 1);
                    u32 cp = cT[t * 512 + mi];
                    float cs = b2f((u16)cp), sn = b2f((u16)(cp >> 16));
                    float o = (col & 1) ? (v * cs + pv * sn) : (v * cs - pv * sn);
                    if (isK) {
                        pk |= ((u64)f2b(o)) << (16 * r);
                        o *= gkt[h * 64 + (t & 63)];
                    }
                    *(u16*)(SP + rowl * 512 + ((col * 2) ^ ((rowl & 15) << 4))) = f2b(o);
                }
                if (isK)
                    *(u64*)&kT[((size_t)((b * 8 + h) * 128 + (gq & 127))) * 2048 + t0 + wr * 128 + fm * 16 + lg * 4] = pk;
            }
        __syncthreads();
#pragma unroll
        for (int it = 0; it < 16; it++) {
            int chunk = it * 512 + tid;
            int r = chunk >> 5, j = chunk & 31;
            uint4 v = *(const uint4*)(SP + r * 512 + ((j * 16) ^ ((r & 15) << 4)));
            int hh = hb + (j >> 4);
            u16* g = (isK ? kw : qw) + ((size_t)((b * 8 + hh) * 2048 + t0 + r)) * 128 + (j & 15) * 8;
            *(uint4*)g = v;
        }
    } else {                                         // ---- gate: silu ----
        int c0 = n0 - 4096;
#pragma unroll
        for (int fm = 0; fm < 8; fm++)
#pragma unroll
            for (int fn = 0; fn < 4; fn++) {
                int col = wc * 64 + fn * 16 + lr;
#pragma unroll
                for (int r = 0; r < 4; r++) {
                    int rowl = wr * 128 + fm * 16 + lg * 4 + r;
                    float gg = acc[fm][fn][r];
                    *(u16*)(SP + rowl * 512 + ((col * 2) ^ ((rowl & 15) << 4))) = f2b(gg / (1.f + expf(-gg)));
                }
            }
        __syncthreads();
#pragma unroll
        for (int it = 0; it < 16; it++) {
            int chunk = it * 512 + tid;
            int r = chunk >> 5, j = chunk & 31;
            uint4 v = *(const uint4*)(SP + r * 512 + ((j * 16) ^ ((r & 15) << 4)));
            *(uint4*)(gateb + (size_t)(b * 2048 + t0 + r) * 2048 + c0 + j * 8) = v;
        }
    }
}

// ======== GEMM3: out = gated @ Wp^T + bp, 128x128 tile, full K=2048, fine schedule ========
// 8 waves (512 thr): wave (wr=wid>>1, wc=wid&1) owns rows 32wr..+32, cols 64wc..+64.
// 4 chunks/tile (A0,A1,B0,B1 of 8KB); issue all 4 next-tile chunks at tile top; one
// vmcnt(0)+barrier per tile (loads get the whole tile's MFMA to land).
DEVI void stage_o(const u16* __restrict__ A, const u16* __restrict__ B,
                  int m0, int n0, int kt, char* buf, int id, int wid, int lane) {
    int j = id & 1;
    int flat = j * 8192 + wid * 1024 + lane * 16;
    int row = flat >> 7, byt = (flat & 127) ^ ((row & 7) << 4);
    if (id < 2)
        gll16((const char*)A + (size_t)(m0 + row) * 4096 + kt * 128 + byt,
              buf + j * 8192 + wid * 1024);
    else
        gll16((const char*)B + (size_t)(n0 + row) * 4096 + kt * 128 + byt,
              buf + 16384 + j * 8192 + wid * 1024);
}

__global__ __launch_bounds__(512, 2) void k_gemm_out2(const u16* __restrict__ gdb,
                                                      const u16* __restrict__ Wt,
                                                      const float* __restrict__ bp,
                                                      float* __restrict__ outp) {
    __shared__ __align__(16) char Lo[65536];         // 2 x (A 16KB + B 16KB)
    int m0 = blockIdx.y * 128, n0 = blockIdx.x * 128;
    int tid = threadIdx.x, lane = tid & 63, wid = tid >> 6;
    int wr = wid >> 1, wc = wid & 1, lr = lane & 15, lg = lane >> 4;
    f4_t acc[2][4];
#pragma unroll
    for (int i = 0; i < 2; i++)
#pragma unroll
        for (int j = 0; j < 4; j++)
#pragma unroll
            for (int e = 0; e < 4; e++) acc[i][j][e] = 0.f;
    stage_o(gdb, Wt, m0, n0, 0, Lo, 0, wid, lane);
    stage_o(gdb, Wt, m0, n0, 0, Lo, 1, wid, lane);
    stage_o(gdb, Wt, m0, n0, 0, Lo, 2, wid, lane);
    stage_o(gdb, Wt, m0, n0, 0, Lo, 3, wid, lane);
    asm volatile("s_waitcnt vmcnt(0)" ::: "memory");
    __builtin_amdgcn_s_barrier();
    for (int kt = 0; kt < 32; ++kt) {
        const char* bA = Lo + (kt & 1) * 32768;
        const char* bB = bA + 16384;
        char* nbuf = Lo + ((kt + 1) & 1) * 32768;
        if (kt < 31) {
            stage_o(gdb, Wt, m0, n0, kt + 1, nbuf, 0, wid, lane);
            stage_o(gdb, Wt, m0, n0, kt + 1, nbuf, 1, wid, lane);
            stage_o(gdb, Wt, m0, n0, kt + 1, nbuf, 2, wid, lane);
            stage_o(gdb, Wt, m0, n0, kt + 1, nbuf, 3, wid, lane);
        }
        __builtin_amdgcn_s_setprio(1);
#pragma unroll
        for (int kk = 0; kk < 2; kk++) {
            bf8_t a[2], b[4];
#pragma unroll
            for (int f = 0; f < 2; f++) {
                int ra = wr * 32 + f * 16 + lr;
                a[f] = *(const bf8_t*)(bA + ra * 128 + ((kk * 64 + lg * 16) ^ ((ra & 7) << 4)));
            }
#pragma unroll
            for (int f = 0; f < 4; f++) {
                int rb = wc * 64 + f * 16 + lr;
                b[f] = *(const bf8_t*)(bB + rb * 128 + ((kk * 64 + lg * 16) ^ ((rb & 7) << 4)));
            }
#pragma unroll
            for (int i = 0; i < 2; i++)
#pragma unroll
                for (int j = 0; j < 4; j++)
                    acc[i][j] = MFMA16(a[i], b[j], acc[i][j]);
        }
        __builtin_amdgcn_s_setprio(0);
        asm volatile("s_waitcnt vmcnt(0)" ::: "memory");   // next-tile chunks landed
        __builtin_amdgcn_s_barrier();
    }
    // ---- epilogue: stage f32 tile 128x512B in Lo (+bias), coalesced out ----
    __syncthreads();
    float* SMf = (float*)Lo;
    float bv[4];
#pragma unroll
    for (int fn = 0; fn < 4; fn++) bv[fn] = bp[n0 + wc * 64 + fn * 16 + lr];
#pragma unroll
    for (int fm = 0; fm < 2; fm++)
#pragma unroll
        for (int fn = 0; fn < 4; fn++) {
            int col = wc * 64 + fn * 16 + lr;
#pragma unroll
            for (int r = 0; r < 4; r++) {
                int rowl = wr * 32 + fm * 16 + lg * 4 + r;
                *(float*)((char*)SMf + rowl * 512 + ((col * 4) ^ ((rowl & 7) << 6))) = acc[fm][fn][r] + bv[fn];
            }
        }
    __syncthreads();
#pragma unroll
    for (int it2 = 0; it2 < 8; it2++) {
        int chunk = it2 * 512 + tid;
        int rowl = chunk >> 5, j = chunk & 31;
        f4_t v = *(const f4_t*)((const char*)SMf + rowl * 512 + ((j * 16) ^ ((rowl & 7) << 6)));
        *(f4_t*)((char*)outp + ((size_t)(m0 + rowl) * 1024 + n0) * 4 + j * 16) = v;
    }
}

DEVI void acc_zero(f4_t acc[4][4]) {
#pragma unroll
    for (int i = 0; i < 4; i++)
#pragma unroll
        for (int j = 0; j < 4; j++)
#pragma unroll
            for (int e = 0; e < 4; e++) acc[i][j][e] = 0.f;
}

// ---------------- retention: Q in regs, factorized decay, wave-local PV ----------------
__global__ __launch_bounds__(256, 3) void k_retention(const u16* __restrict__ qws, const u16* __restrict__ kws,
                                                      const u16* __restrict__ vTws,
                                                      u16* __restrict__ ret0, u16* __restrict__ ret1) {
    __shared__ u16 SMr[64 * 128 + 256 * 64];         // 48KB
    u16* Ks = SMr;                                   // 16KB; P aliases it
    u16* Vs = SMr + 64 * 128;                        // 32KB; output staging aliases it
    int x = blockIdx.x;
    int it, jlo, jhi, toret1;
    if (x < 16)      { it = 15 - x;  jlo = 0;              jhi = it + 1;         toret1 = 0; }
    else if (x < 32) { it = x;       jlo = 0;              jhi = (it + 2) >> 1;  toret1 = 0; }
    else             { it = x - 16;  jlo = (it + 2) >> 1;  jhi = it + 1;         toret1 = 1; }
    int h = blockIdx.y, b = blockIdx.z;
    int bh = b * 8 + h;
    float lg2 = log2f(1.f - expf(L0f + (float)h * DLf));
    int i0 = it * 64;
    const u16* qbase = qws + (size_t)bh * 2048 * 128;
    const u16* kbase = kws + (size_t)bh * 2048 * 128;
    const u16* vbase = vTws + (size_t)bh * 256 * 2048;
    int tid = threadIdx.x, lane = tid & 63, w = tid >> 6, lr = lane & 15, lg = lane >> 4;
    bf8_t aq[4];
#pragma unroll
    for (int kk = 0; kk < 4; kk++)
        aq[kk] = *(const bf8_t*)((const char*)qbase + (size_t)(i0 + w * 16 + lr) * 256 + kk * 64 + lg * 16);
    f4_t racc[16];
#pragma unroll
    for (int f = 0; f < 16; f++)
#pragma unroll
        for (int e = 0; e < 4; e++) racc[f][e] = 0.f;
    for (int jt = jlo; jt < jhi; jt++) {
        int j0 = jt * 64;
        int diag = (jt == it);
        float tf = exp2f(64.f * (float)(it - jt) * lg2);
        __syncthreads();
#pragma unroll
        for (int p = 0; p < 4; p++) {                // stage K tile [64][128]
            int flat = p * 4096 + tid * 16;
            int row = flat >> 8, byt = (flat & 255) ^ ((row & 7) << 4);
            gll16((const char*)kbase + (size_t)(j0 + row) * 256 + byt, (char*)Ks + p * 4096 + w * 1024);
        }
#pragma unroll
        for (int p = 0; p < 8; p++) {                // stage Vt tile [256][64]
            int flat = p * 4096 + tid * 16;
            int row = flat >> 7, byt = (flat & 127) ^ ((row & 7) << 4);
            gll16((const char*)vbase + (size_t)row * 4096 + (size_t)j0 * 2 + byt,
                  (char*)Vs + p * 4096 + w * 1024);
        }
        __syncthreads();
        f4_t sacc[4];
#pragma unroll
        for (int f = 0; f < 4; f++)
#pragma unroll
            for (int e = 0; e < 4; e++) sacc[f][e] = 0.f;
#pragma unroll
        for (int kk = 0; kk < 4; kk++)
#pragma unroll
            for (int fn = 0; fn < 4; fn++) {
                int rb = fn * 16 + lr;
                bf8_t bb = *(const bf8_t*)((const char*)Ks + rb * 256 + ((kk * 64 + lg * 16) ^ ((rb & 7) << 4)));
                sacc[fn] = MFMA16(aq[kk], bb, sacc[fn]);
            }
        __syncthreads();                             // K reads done; alias Ks as P
#pragma unroll
        for (int fn = 0; fn < 4; fn++)
#pragma unroll
            for (int r = 0; r < 4; r++) {
                int i_loc = w * 16 + lg * 4 + r;
                int col = fn * 16 + lr;
                float v = diag ? ((i_loc - col >= 0) ? sacc[fn][r] : 0.f) : sacc[fn][r] * tf;
                *(u16*)((char*)Ks + i_loc * 128 + ((col * 2) ^ ((i_loc & 7) << 4))) = f2b(v);
            }
#pragma unroll
        for (int kk = 0; kk < 2; kk++) {
            int ra = w * 16 + lr;
            bf8_t ap = *(const bf8_t*)((const char*)Ks + ra * 128 + ((kk * 64 + lg * 16) ^ ((ra & 7) << 4)));
#pragma unroll
            for (int fn2 = 0; fn2 < 16; fn2++) {
                int rb = fn2 * 16 + lr;
                bf8_t bv = *(const bf8_t*)((const char*)Vs + rb * 128 + ((kk * 64 + lg * 16) ^ ((rb & 7) << 4)));
                racc[fn2] = MFMA16(ap, bv, racc[fn2]);
            }
        }
    }
    __syncthreads();
    u16* St = Vs;
#pragma unroll
    for (int fn2 = 0; fn2 < 16; fn2++)
#pragma unroll
        for (int r = 0; r < 4; r++) {
            int il = w * 16 + lg * 4 + r;
            int dv = fn2 * 16 + lr;
            *(u16*)((char*)St + il * 512 + ((dv * 2) ^ ((il & 15) << 4))) = f2b(racc[fn2][r]);
        }
    __syncthreads();
#pragma unroll
    for (int it2 = 0; it2 < 8; it2++) {
        int chunk = it2 * 256 + tid;
        int il = chunk >> 5, j = chunk & 31;
        uint4 v = *(const uint4*)((const char*)St + il * 512 + ((j * 16) ^ ((il & 15) << 4)));
        char* dst;
        if (toret1) dst = (char*)ret1 + ((size_t)(b * 1024 + i0 - 1024 + il) * 2048 + h * 256) * 2 + j * 16;
        else        dst = (char*)ret0 + ((size_t)(b * 2048 + i0 + il) * 2048 + h * 256) * 2 + j * 16;
        *(uint4*)dst = v;
    }
}

// ---------------- curr_kv partials: block = (t-range of 512, bh) ----------------
__global__ __launch_bounds__(512) void k_currkv(const u16* __restrict__ kTws, const u16* __restrict__ vTws,
                                                const float* __restrict__ gtab, float* __restrict__ part) {
    __shared__ u16 Ks2[128 * 64];
    __shared__ u16 Vws[256 * 64];
    int tr = blockIdx.x;            // 0..3
    int bh = blockIdx.y;            // 0..15
    int h = bh & 7;
    const u16* kT = kTws + (size_t)bh * 128 * 2048;
    const u16* vT = vTws + (size_t)bh * 256 * 2048;
    const float* gt = gtab + h * 2048;
    int tid = threadIdx.x, lane = tid & 63, wid = tid >> 6;
    int wr = wid >> 2, wc = wid & 3, lr = lane & 15, lg = lane >> 4;
    f4_t acc[4][4]; acc_zero(acc);
    for (int tc = 0; tc < 8; tc++) {
        int t0 = tr * 512 + tc * 64;
        __syncthreads();
#pragma unroll
        for (int p = 0; p < 2; p++) {
            int flat = p * 8192 + tid * 16;
            int row = flat >> 7, byt = (flat & 127) ^ ((row & 7) << 4);
            gll16((const char*)kT + (size_t)row * 4096 + (size_t)t0 * 2 + byt,
                  (char*)Ks2 + p * 8192 + wid * 1024);
        }
#pragma unroll
        for (int p = 0; p < 4; p++) {
            int flat = p * 8192 + tid * 16;
            int row = flat >> 7, byt = flat & 127;
            int tt = t0 + (byt >> 1);
            const u16* src = vT + (size_t)row * 2048 + tt;
            u16 tmp[8]; *(uint4*)tmp = *(const uint4*)src;
            const float* gp = gt + tt;
            u16 op[8];
#pragma unroll
            for (int e = 0; e < 8; e++) op[e] = f2b(b2f(tmp[e]) * gp[e]);
            *(uint4*)((char*)Vws + row * 128 + (byt ^ ((row & 7) << 4))) = *(uint4*)op;
        }
        __syncthreads();
#pragma unroll
        for (int kk = 0; kk < 2; kk++) {
            bf8_t a[4], bb[4];
#pragma unroll
            for (int f = 0; f < 4; f++) {
                int ra = wr * 64 + f * 16 + lr;
                a[f] = *(const bf8_t*)((const char*)Ks2 + ra * 128 + ((kk * 64 + lg * 16) ^ ((ra & 7) << 4)));
                int rb = wc * 64 + f * 16 + lr;
                bb[f] = *(const bf8_t*)((const char*)Vws + rb * 128 + ((kk * 64 + lg * 16) ^ ((rb & 7) << 4)));
            }
#pragma unroll
            for (int i = 0; i < 4; i++)
#pragma unroll
                for (int j = 0; j < 4; j++)
                    acc[i][j] = MFMA16(a[i], bb[j], acc[i][j]);
        }
    }
#pragma unroll
    for (int fm = 0; fm < 4; fm++)
#pragma unroll
        for (int fn = 0; fn < 4; fn++)
#pragma unroll
            for (int r = 0; r < 4; r++) {
                int dk = wr * 64 + fm * 16 + lg * 4 + r;
                int dv = wc * 64 + fn * 16 + lr;
                part[((size_t)(bh * 4 + tr)) * 32768 + (size_t)dk * 256 + dv] = acc[fm][fn][r];
            }
}

__global__ __launch_bounds__(256) void k_reduce_ckv(const float* __restrict__ part, float* __restrict__ outc) {
    int i = blockIdx.x * 256 + threadIdx.x;          // 524288
    int bh = i >> 15, wv = i & 32767;
    float s = 0.f;
#pragma unroll
    for (int tr = 0; tr < 4; tr++) s += part[((size_t)(bh * 4 + tr)) * 32768 + wv];
    outc[i] = s;
}

// ---------------- groupnorm(256) * silu-gate -> bf16 ----------------
__global__ __launch_bounds__(256) void k_gnorm(const u16* __restrict__ ret0, const u16* __restrict__ ret1,
                                               const u16* __restrict__ gateb, u16* __restrict__ gatedb) {
    int g = blockIdx.x * 4 + (threadIdx.x >> 6);     // wave per group
    int lane = threadIdx.x & 63;
    int row = g >> 3, h = g & 7;                     // row = b*2048 + t
    size_t base = (size_t)row * 2048 + h * 256 + lane * 4;
    u64 p0 = *(const u64*)(ret0 + base);
    float e0 = b2f((u16)p0), e1 = b2f((u16)(p0 >> 16)), e2 = b2f((u16)(p0 >> 32)), e3 = b2f((u16)(p0 >> 48));
    if ((row & 2047) >= 1024) {
        size_t b1 = (size_t)((row >> 11) * 1024 + (row & 1023)) * 2048 + h * 256 + lane * 4;
        u64 p1 = *(const u64*)(ret1 + b1);
        e0 += b2f((u16)p1); e1 += b2f((u16)(p1 >> 16)); e2 += b2f((u16)(p1 >> 32)); e3 += b2f((u16)(p1 >> 48));
    }
    float s = e0 + e1 + e2 + e3;
    float sqs = e0 * e0 + e1 * e1 + e2 * e2 + e3 * e3;
#pragma unroll
    for (int m = 1; m < 64; m <<= 1) { s += __shfl_xor(s, m); sqs += __shfl_xor(sqs, m); }
    float mean = s * (1.f / 256.f);
    float var = sqs * (1.f / 256.f) - mean * mean;
    float inv = rsqrtf(var + 1e-5f);
    u64 gp = *(const u64*)(gateb + base);
    u64 pk = (u64)f2b((e0 - mean) * inv * b2f((u16)gp)) |
             ((u64)f2b((e1 - mean) * inv * b2f((u16)(gp >> 16))) << 16) |
             ((u64)f2b((e2 - mean) * inv * b2f((u16)(gp >> 32))) << 32) |
             ((u64)f2b((e3 - mean) * inv * b2f((u16)(gp >> 48))) << 48);
    *(u64*)(gatedb + base) = pk;
}

extern "C" void kernel_launch(void* const* d_in, const int* in_sizes, int n_in,
                              void* d_out, int out_size, void* d_ws, size_t ws_size,
                              hipStream_t stream) {
    const float* x    = (const float*)d_in[0];
    const float* Wqkv = (const float*)d_in[1];
    const float* Wg   = (const float*)d_in[2];
    const float* Wp   = (const float*)d_in[3];
    const float* bp   = (const float*)d_in[4];
    float* outp   = (float*)d_out;
    float* outckv = outp + (size_t)BB * TT * HIDN;

    char* ws = (char*)d_ws;
    const size_t MB = 1024 * 1024;
    u16*   xb     = (u16*)(ws);               // 0..8
    u16*   WqkvT  = (u16*)(ws + 8 * MB);      // 8..16  [4096][1024]
    u16*   WgT    = (u16*)(ws + 16 * MB);     // 16..20 [2048][1024] (contiguous -> Wcat [6144][1024])
    u16*   WpT    = (u16*)(ws + 20 * MB);     // 20..24 [1024][2048]
    u32*   cqp    = (u32*)(ws + 24 * MB);     // 24..28 packed q table
    u32*   ckp    = (u32*)(ws + 28 * MB);     // 28..32 packed k table
    u16*   gateb  = (u16*)(ws + 32 * MB);     // 32..48 [4096][2048]
    u16*   qw     = (u16*)(ws + 48 * MB);     // 48..56 [bh][t][128] prescaled q
    u16*   kw     = (u16*)(ws + 56 * MB);     // 56..64 prescaled k
    u16*   kT     = (u16*)(ws + 64 * MB);     // 64..72 [bh][128][t] unscaled k
    u16*   vT     = (u16*)(ws + 72 * MB);     // 72..88 [bh][256][t]
    u16*   ret0b  = (u16*)(ws + 88 * MB);     // 88..104 bf16 [b][2048][2048]
    u16*   ret1b  = (u16*)(ws + 104 * MB);    // 104..112 bf16 [b][1024][2048]
    float* ckvp   = (float*)(ws + 112 * MB);  // 112..120
    float* gtab   = (float*)(ws + 120 * MB);            // 64KB
    float* gkt    = (float*)(ws + 120 * MB + 65536);    // 2KB
    // aliases:
    u16*   gatedb = (u16*)(ws + 48 * MB);     // 16MB over qw/kw (dead after retention)

    hipLaunchKernelGGL(k_tables, dim3(4162), dim3(256), 0, stream, cqp, ckp, gtab, gkt);
    hipLaunchKernelGGL(k_cvt, dim3(4096), dim3(256), 0, stream, x, xb);
    hipLaunchKernelGGL(k_tposeF, dim3(8192), dim3(32, 8), 0, stream, Wqkv, Wg, Wp, WqkvT, WgT, WpT);
    hipLaunchKernelGGL(k_gemm_qkvg8, dim3(384), dim3(512), 0, stream,
                       xb, WqkvT, cqp, ckp, gkt, qw, kw, kT, vT, gateb);
    hipLaunchKernelGGL(k_currkv, dim3(4, 16), dim3(512), 0, stream, kT, vT, gtab, ckvp);
    hipLaunchKernelGGL(k_reduce_ckv, dim3(2048), dim3(256), 0, stream, ckvp, outckv);
    hipLaunchKernelGGL(k_retention, dim3(48, 8, 2), dim3(256), 0, stream, qw, kw, vT, ret0b, ret1b);
    hipLaunchKernelGGL(k_gnorm, dim3(8192), dim3(256), 0, stream, ret0b, ret1b, gateb, gatedb);
    hipLaunchKernelGGL(k_gemm_out2, dim3(8, 32), dim3(512), 0, stream, gatedb, WpT, bp, outp);
}

// Round 14
// 208.547 us; speedup vs baseline: 3.2071x; 1.0389x over previous
//
#include <hip/hip_runtime.h>

typedef unsigned short u16;
typedef unsigned int   u32;
typedef unsigned long long u64;

typedef __attribute__((ext_vector_type(8))) short bf8_t;   // 8 x bf16
typedef __attribute__((ext_vector_type(4))) float f4_t;

#define DEVI __device__ __forceinline__
#define MFMA16(a,b,c) __builtin_amdgcn_mfma_f32_16x16x32_bf16((a),(b),(c),0,0,0)

#define BB   2
#define TT   2048
#define HIDN 1024
#define L0f  (-3.4657359027997265f)   // ln(1/32)
#define DLf  (-0.3960841031714215f)   // (ln(1/512)-ln(1/32))/7
#define SCL  (0.08838834764831845f)   // 128^-0.5

DEVI u16 f2b(float f) {                 // f32 -> bf16 RNE
    u32 u = __float_as_uint(f);
    u += 0x7FFFu + ((u >> 16) & 1u);
    return (u16)(u >> 16);
}
DEVI float b2f(u16 u) { return __uint_as_float(((u32)u) << 16); }

// async global->LDS, 16B per lane; lds dest = wave-uniform base + lane*16
DEVI void gll16(const void* g, void* l) {
    __builtin_amdgcn_global_load_lds((const __attribute__((address_space(1))) void*)g,
                                     (__attribute__((address_space(3))) void*)l, 16, 0, 0);
}

// ------- packed xPos tables (blocks 0..4095) + gamma tables (blocks 4096..4161) -------
__global__ __launch_bounds__(256) void k_tables(u32* __restrict__ cqp, u32* __restrict__ ckp,
                                                float* __restrict__ gt, float* __restrict__ gk) {
    int bx = blockIdx.x;
    if (bx >= 4096) {                                // gamma tables
        int i = (bx - 4096) * 256 + threadIdx.x;     // 16896 entries
        if (i < 16384) {                             // gtab[h][t] = g^(2047-t)
            int h = i >> 11, t = i & 2047;
            float lg2 = log2f(1.f - expf(L0f + (float)h * DLf));
            gt[i] = exp2f((float)(2047 - t) * lg2);
        } else {                                     // gk[h][d] = g^-d
            int idx = i - 16384;                     // 512 entries
            int h = idx >> 6, d = idx & 63;
            float lg2 = log2f(1.f - expf(L0f + (float)h * DLf));
            gk[idx] = exp2f(-(float)d * lg2);
        }
        return;
    }
    int idx = bx * 256 + threadIdx.x;                // t*512 + m
    int t = idx >> 9, m = idx & 511;
    float base = (2.f * (float)m + 409.6f) * (1.f / 1433.6f);
    float s = exp2f(log2f(base) * ((float)t * (1.f / 512.f)));
    float invf = exp2f(-(float)m * (13.287712379549449f / 512.f)); // 10000^{-m/512}
    float sn, cs;
    sincosf((float)t * invf, &sn, &cs);
    int h = m >> 6;
    float lg2h = log2f(1.f - expf(L0f + (float)h * DLf));
    float qf = s * SCL * exp2f((float)(t & 63) * lg2h);
    cqp[idx] = (u32)f2b(cs * qf) | ((u32)f2b(sn * qf) << 16);
    float is = 1.f / s;
    ckp[idx] = (u32)f2b(cs * is) | ((u32)f2b(sn * is) << 16);
}

// ---------------- f32 -> bf16 convert (x) ----------------
__global__ __launch_bounds__(256) void k_cvt(const float* __restrict__ in, u16* __restrict__ out) {
    int i = blockIdx.x * 256 + threadIdx.x;
    float4 v = ((const float4*)in)[i];
    u64 pk = (u64)f2b(v.x) | ((u64)f2b(v.y) << 16) | ((u64)f2b(v.z) << 32) | ((u64)f2b(v.w) << 48);
    ((u64*)out)[i] = pk;
}

// ------- fused transpose+convert of all 3 weights: in[R][C] f32 -> out[C][R] bf16 -------
__global__ __launch_bounds__(256) void k_tposeF(const float* __restrict__ Wqkv,
                                                const float* __restrict__ Wg,
                                                const float* __restrict__ Wp,
                                                u16* __restrict__ oQ, u16* __restrict__ oG,
                                                u16* __restrict__ oP) {
    __shared__ float tile[32][33];
    int bx = blockIdx.x;
    const float* in; u16* out; int R, C, cx, ry;
    if (bx < 4096)      { in = Wqkv; out = oQ; R = 1024; C = 4096; cx = bx & 127;        ry = bx >> 7; }
    else if (bx < 6144) { int b2 = bx - 4096; in = Wg; out = oG; R = 1024; C = 2048; cx = b2 & 63; ry = b2 >> 6; }
    else                { int b2 = bx - 6144; in = Wp; out = oP; R = 2048; C = 1024; cx = b2 & 31; ry = b2 >> 5; }
    int c0 = cx * 32, r0 = ry * 32;
    int tx = threadIdx.x, ty = threadIdx.y;          // (32,8)
#pragma unroll
    for (int i = 0; i < 4; i++)
        tile[ty * 4 + i][tx] = in[(size_t)(r0 + ty * 4 + i) * C + c0 + tx];
    __syncthreads();
#pragma unroll
    for (int i = 0; i < 4; i++)
        out[(size_t)(c0 + ty * 4 + i) * R + r0 + tx] = f2b(tile[tx][ty * 4 + i]);
}

// =============== 256x256 8-wave, BK=64, dbuf-LDS, fine-grained phase schedule ===============
DEVI void stage_chunk(const u16* __restrict__ A, const u16* __restrict__ B,
                      int m0, int n0, int kt, char* buf, int id, int wid, int lane) {
    int j = id & 3;
    int flat = j * 8192 + wid * 1024 + lane * 16;
    int row = flat >> 7, byt = (flat & 127) ^ ((row & 7) << 4);
    if (id < 4)
        gll16((const char*)A + (size_t)(m0 + row) * 2048 + kt * 128 + byt,
              buf + j * 8192 + wid * 1024);
    else
        gll16((const char*)B + (size_t)(n0 + row) * 2048 + kt * 128 + byt,
              buf + 32768 + j * 8192 + wid * 1024);
}

#define QCORE(kk, fmh, LOADB)                                                         \
    {                                                                                 \
        bf8_t a_[4];                                                                  \
        _Pragma("unroll")                                                             \
        for (int f = 0; f < 4; f++) {                                                 \
            int ra = 128 * wr + ((fmh) * 4 + f) * 16 + lr;                            \
            a_[f] = *(const bf8_t*)(bA + ra * 128 + (((kk) * 64 + lg * 16) ^ ((ra & 7) << 4))); \
        }                                                                             \
        if (LOADB) {                                                                  \
            _Pragma("unroll")                                                         \
            for (int f = 0; f < 4; f++) {                                             \
                int rb = 64 * wc + f * 16 + lr;                                       \
                breg[f] = *(const bf8_t*)(bB + rb * 128 + (((kk) * 64 + lg * 16) ^ ((rb & 7) << 4))); \
            }                                                                         \
        }                                                                             \
        __builtin_amdgcn_s_barrier();                                                 \
        __builtin_amdgcn_s_setprio(1);                                                \
        _Pragma("unroll")                                                             \
        for (int f = 0; f < 4; f++)                                                   \
            _Pragma("unroll")                                                         \
            for (int j = 0; j < 4; j++)                                               \
                acc[(fmh) * 4 + f][j] = MFMA16(a_[f], breg[j], acc[(fmh) * 4 + f][j]); \
        __builtin_amdgcn_s_setprio(0);                                                \
    }

__global__ __launch_bounds__(512, 2) void k_gemm_qkvg8(
    const u16* __restrict__ xb, const u16* __restrict__ Wcat,
    const u32* __restrict__ cqp, const u32* __restrict__ ckp, const float* __restrict__ gkt,
    u16* __restrict__ qw, u16* __restrict__ kw, u16* __restrict__ kT, u16* __restrict__ vT,
    u16* __restrict__ gateb) {
    __shared__ __align__(16) char L[131072];         // 2 x (A 32KB + B 32KB)
    int flat = blockIdx.x;
    int swz = (flat & 7) * 48 + (flat >> 3);         // XCD-bijective (384 = 8*48), m-major
    int m0 = (swz / 24) * 256, n0 = (swz % 24) * 256;
    int tid = threadIdx.x, lane = tid & 63, wid = tid >> 6;
    int wr = wid >> 2, wc = wid & 3, lr = lane & 15, lg = lane >> 4;
    f4_t acc[8][4];
#pragma unroll
    for (int i = 0; i < 8; i++)
#pragma unroll
        for (int j = 0; j < 4; j++)
#pragma unroll
            for (int e = 0; e < 4; e++) acc[i][j][e] = 0.f;
    // prologue: issue all 8 chunks of tile 0 in uniform order; ensure first 6
    stage_chunk(xb, Wcat, m0, n0, 0, L, 0, wid, lane);
    stage_chunk(xb, Wcat, m0, n0, 0, L, 2, wid, lane);
    stage_chunk(xb, Wcat, m0, n0, 0, L, 4, wid, lane);
    stage_chunk(xb, Wcat, m0, n0, 0, L, 5, wid, lane);
    stage_chunk(xb, Wcat, m0, n0, 0, L, 6, wid, lane);
    stage_chunk(xb, Wcat, m0, n0, 0, L, 7, wid, lane);
    stage_chunk(xb, Wcat, m0, n0, 0, L, 1, wid, lane);
    stage_chunk(xb, Wcat, m0, n0, 0, L, 3, wid, lane);
    asm volatile("s_waitcnt vmcnt(2)" ::: "memory");
    __builtin_amdgcn_s_barrier();
    for (int kt = 0; kt < 16; ++kt) {
        const char* bA = L + (kt & 1) * 65536;
        const char* bB = bA + 32768;
        char* nbuf = L + ((kt + 1) & 1) * 65536;
        bf8_t breg[4];
        // phase 0: MFMA(kk0,fmh0) reads A0/A2 + B(wc); issue next-tile A0,A2
        if (kt < 15) {
            stage_chunk(xb, Wcat, m0, n0, kt + 1, nbuf, 0, wid, lane);
            stage_chunk(xb, Wcat, m0, n0, kt + 1, nbuf, 2, wid, lane);
        }
        QCORE(0, 0, 1)
        if (kt < 15) { asm volatile("s_waitcnt vmcnt(2)" ::: "memory"); }  // tile-kt A1,A3 done
        else         { asm volatile("s_waitcnt vmcnt(0)" ::: "memory"); }
        __builtin_amdgcn_s_barrier();
        // phase 1: MFMA(kk0,fmh1) reads A1/A3; issue next-tile B4,B5
        if (kt < 15) {
            stage_chunk(xb, Wcat, m0, n0, kt + 1, nbuf, 4, wid, lane);
            stage_chunk(xb, Wcat, m0, n0, kt + 1, nbuf, 5, wid, lane);
        }
        QCORE(0, 1, 0)
        __builtin_amdgcn_s_barrier();
        // phase 2: MFMA(kk1,fmh0); issue next-tile B6,B7
        if (kt < 15) {
            stage_chunk(xb, Wcat, m0, n0, kt + 1, nbuf, 6, wid, lane);
            stage_chunk(xb, Wcat, m0, n0, kt + 1, nbuf, 7, wid, lane);
        }
        QCORE(1, 0, 1)
        __builtin_amdgcn_s_barrier();
        // phase 3: MFMA(kk1,fmh1); issue next-tile A1,A3
        if (kt < 15) {
            stage_chunk(xb, Wcat, m0, n0, kt + 1, nbuf, 1, wid, lane);
            stage_chunk(xb, Wcat, m0, n0, kt + 1, nbuf, 3, wid, lane);
        }
        QCORE(1, 1, 0)
        if (kt < 15) { asm volatile("s_waitcnt vmcnt(2)" ::: "memory"); }  // next tile first-6 done
        __builtin_amdgcn_s_barrier();
    }
    // ---------------- epilogue: stage 256x256 tile in L (rows of 512B), coalesced out ----------
    __syncthreads();                                 // drain remaining loads; release L
    char* SP = L;
    int b = m0 >> 11, t0 = m0 & 2047;
    if (n0 < 4096 && n0 >= 2048) {                   // ---- v: stage transposed [dv][t] ----
        int h = (n0 - 2048) >> 8;
#pragma unroll
        for (int fm = 0; fm < 8; fm++)
#pragma unroll
            for (int fn = 0; fn < 4; fn++) {
                int dv = wc * 64 + fn * 16 + lr;
                int rowb = wr * 128 + fm * 16 + lg * 4;
                u64 pk = 0;
#pragma unroll
                for (int r = 0; r < 4; r++) pk |= ((u64)f2b(acc[fm][fn][r])) << (16 * r);
                *(u64*)(SP + dv * 512 + ((rowb * 2) ^ ((dv & 15) << 4))) = pk;
            }
        __syncthreads();
#pragma unroll
        for (int it = 0; it < 16; it++) {
            int chunk = it * 512 + tid;
            int dv = chunk >> 5, j = chunk & 31;
            uint4 v = *(const uint4*)(SP + dv * 512 + ((j * 16) ^ ((dv & 15) << 4)));
            *(uint4*)(vT + ((size_t)((b * 8 + h) * 256 + dv)) * 2048 + t0 + j * 8) = v;
        }
    } else if (n0 < 2048) {                          // ---- q or k: rotate (+prescale) ----
        int isK = n0 >= 1024;
        const u32* cT = isK ? ckp : cqp;
        int hb = (n0 >> 7) & 7;
#pragma unroll
        for (int fm = 0; fm < 8; fm++)
#pragma unroll
            for (int fn = 0; fn < 4; fn++) {
                int col = wc * 64 + fn * 16 + lr;
                int gq = (n0 & 1023) + col;
                int mi = gq >> 1, h = gq >> 7;
                u64 pk = 0;
#pragma unroll
                for (int r = 0; r < 4; r++) {
                    int rowl = wr * 128 + fm * 16 + lg * 4 + r;
                    int t = t0 + rowl;
                    float v = acc[fm][fn][r];
                    float pv = __shfl_xor(v, 1);
                    u32 cp = cT[t * 512 + mi];
                    float cs = b2f((u16)cp), sn = b2f((u16)(cp >> 16));
                    float o = (col & 1) ? (v * cs + pv * sn) : (v * cs - pv * sn);
                    if (isK) {
                        pk |= ((u64)f2b(o)) << (16 * r);
                        o *= gkt[h * 64 + (t & 63)];
                    }
                    *(u16*)(SP + rowl * 512 + ((col * 2) ^ ((rowl & 15) << 4))) = f2b(o);
                }
                if (isK)
                    *(u64*)&kT[((size_t)((b * 8 + h) * 128 + (gq & 127))) * 2048 + t0 + wr * 128 + fm * 16 + lg * 4] = pk;
            }
        __syncthreads();
#pragma unroll
        for (int it = 0; it < 16; it++) {
            int chunk = it * 512 + tid;
            int r = chunk >> 5, j = chunk & 31;
            uint4 v = *(const uint4*)(SP + r * 512 + ((j * 16) ^ ((r & 15) << 4)));
            int hh = hb + (j >> 4);
            u16* g = (isK ? kw : qw) + ((size_t)((b * 8 + hh) * 2048 + t0 + r)) * 128 + (j & 15) * 8;
            *(uint4*)g = v;
        }
    } else {                                         // ---- gate: silu ----
        int c0 = n0 - 4096;
#pragma unroll
        for (int fm = 0; fm < 8; fm++)
#pragma unroll
            for (int fn = 0; fn < 4; fn++) {
                int col = wc * 64 + fn * 16 + lr;
#pragma unroll
                for (int r = 0; r < 4; r++) {
                    int rowl = wr * 128 + fm * 16 + lg * 4 + r;
                    float gg = acc[fm][fn][r];
                    *(u16*)(SP + rowl * 512 + ((col * 2) ^ ((rowl & 15) << 4))) = f2b(gg / (1.f + expf(-gg)));
                }
            }
        __syncthreads();
#pragma unroll
        for (int it = 0; it < 16; it++) {
            int chunk = it * 512 + tid;
            int r = chunk >> 5, j = chunk & 31;
            uint4 v = *(const uint4*)(SP + r * 512 + ((j * 16) ^ ((r & 15) << 4)));
            *(uint4*)(gateb + (size_t)(b * 2048 + t0 + r) * 2048 + c0 + j * 8) = v;
        }
    }
}

// ======== GEMM3: out = gated @ Wp^T + bp, 128x128, full K=2048, lag-2 triple buffer ========
DEVI void stage_o(const u16* __restrict__ A, const u16* __restrict__ B,
                  int m0, int n0, int kt, char* buf, int id, int wid, int lane) {
    int j = id & 1;
    int flat = j * 8192 + wid * 1024 + lane * 16;
    int row = flat >> 7, byt = (flat & 127) ^ ((row & 7) << 4);
    if (id < 2)
        gll16((const char*)A + (size_t)(m0 + row) * 4096 + kt * 128 + byt,
              buf + j * 8192 + wid * 1024);
    else
        gll16((const char*)B + (size_t)(n0 + row) * 4096 + kt * 128 + byt,
              buf + 16384 + j * 8192 + wid * 1024);
}

__global__ __launch_bounds__(512, 2) void k_gemm_out2(const u16* __restrict__ gdb,
                                                      const u16* __restrict__ Wt,
                                                      const float* __restrict__ bp,
                                                      float* __restrict__ outp) {
    __shared__ __align__(16) char Lo[98304];         // 3 x (A 16KB + B 16KB)
    int m0 = blockIdx.y * 128, n0 = blockIdx.x * 128;
    int tid = threadIdx.x, lane = tid & 63, wid = tid >> 6;
    int wr = wid >> 1, wc = wid & 1, lr = lane & 15, lg = lane >> 4;
    f4_t acc[2][4];
#pragma unroll
    for (int i = 0; i < 2; i++)
#pragma unroll
        for (int j = 0; j < 4; j++)
#pragma unroll
            for (int e = 0; e < 4; e++) acc[i][j][e] = 0.f;
    // prologue: tiles 0 and 1 in flight; ensure tile 0
#pragma unroll
    for (int c = 0; c < 4; c++) stage_o(gdb, Wt, m0, n0, 0, Lo, c, wid, lane);
#pragma unroll
    for (int c = 0; c < 4; c++) stage_o(gdb, Wt, m0, n0, 1, Lo + 32768, c, wid, lane);
    asm volatile("s_waitcnt vmcnt(4)" ::: "memory");
    __builtin_amdgcn_s_barrier();
    for (int kt = 0; kt < 32; ++kt) {
        const char* bA = Lo + (kt % 3) * 32768;
        const char* bB = bA + 16384;
        if (kt < 30) {
            char* nbuf = Lo + ((kt + 2) % 3) * 32768;
#pragma unroll
            for (int c = 0; c < 4; c++) stage_o(gdb, Wt, m0, n0, kt + 2, nbuf, c, wid, lane);
        }
        __builtin_amdgcn_s_setprio(1);
#pragma unroll
        for (int kk = 0; kk < 2; kk++) {
            bf8_t a[2], b[4];
#pragma unroll
            for (int f = 0; f < 2; f++) {
                int ra = wr * 32 + f * 16 + lr;
                a[f] = *(const bf8_t*)(bA + ra * 128 + ((kk * 64 + lg * 16) ^ ((ra & 7) << 4)));
            }
#pragma unroll
            for (int f = 0; f < 4; f++) {
                int rb = wc * 64 + f * 16 + lr;
                b[f] = *(const bf8_t*)(bB + rb * 128 + ((kk * 64 + lg * 16) ^ ((rb & 7) << 4)));
            }
#pragma unroll
            for (int i = 0; i < 2; i++)
#pragma unroll
                for (int j = 0; j < 4; j++)
                    acc[i][j] = MFMA16(a[i], b[j], acc[i][j]);
        }
        __builtin_amdgcn_s_setprio(0);
        if (kt < 30) { asm volatile("s_waitcnt vmcnt(4)" ::: "memory"); }  // tile kt+1 landed
        else         { asm volatile("s_waitcnt vmcnt(0)" ::: "memory"); }
        __builtin_amdgcn_s_barrier();
    }
    // ---- epilogue: stage f32 tile 128x512B in Lo (+bias), coalesced out ----
    __syncthreads();
    float* SMf = (float*)Lo;
    float bv[4];
#pragma unroll
    for (int fn = 0; fn < 4; fn++) bv[fn] = bp[n0 + wc * 64 + fn * 16 + lr];
#pragma unroll
    for (int fm = 0; fm < 2; fm++)
#pragma unroll
        for (int fn = 0; fn < 4; fn++) {
            int col = wc * 64 + fn * 16 + lr;
#pragma unroll
            for (int r = 0; r < 4; r++) {
                int rowl = wr * 32 + fm * 16 + lg * 4 + r;
                *(float*)((char*)SMf + rowl * 512 + ((col * 4) ^ ((rowl & 7) << 6))) = acc[fm][fn][r] + bv[fn];
            }
        }
    __syncthreads();
#pragma unroll
    for (int it2 = 0; it2 < 8; it2++) {
        int chunk = it2 * 512 + tid;
        int rowl = chunk >> 5, j = chunk & 31;
        f4_t v = *(const f4_t*)((const char*)SMf + rowl * 512 + ((j * 16) ^ ((rowl & 7) << 6)));
        *(f4_t*)((char*)outp + ((size_t)(m0 + rowl) * 1024 + n0) * 4 + j * 16) = v;
    }
}

DEVI void acc_zero(f4_t acc[4][4]) {
#pragma unroll
    for (int i = 0; i < 4; i++)
#pragma unroll
        for (int j = 0; j < 4; j++)
#pragma unroll
            for (int e = 0; e < 4; e++) acc[i][j][e] = 0.f;
}

// ---------------- retention: Q in regs, factorized decay, wave-local PV ----------------
__global__ __launch_bounds__(256, 3) void k_retention(const u16* __restrict__ qws, const u16* __restrict__ kws,
                                                      const u16* __restrict__ vTws,
                                                      u16* __restrict__ ret0, u16* __restrict__ ret1) {
    __shared__ u16 SMr[64 * 128 + 256 * 64];         // 48KB
    u16* Ks = SMr;                                   // 16KB; P aliases it
    u16* Vs = SMr + 64 * 128;                        // 32KB; output staging aliases it
    int x = blockIdx.x;
    int it, jlo, jhi, toret1;
    if (x < 16)      { it = 15 - x;  jlo = 0;              jhi = it + 1;         toret1 = 0; }
    else if (x < 32) { it = x;       jlo = 0;              jhi = (it + 2) >> 1;  toret1 = 0; }
    else             { it = x - 16;  jlo = (it + 2) >> 1;  jhi = it + 1;         toret1 = 1; }
    int h = blockIdx.y, b = blockIdx.z;
    int bh = b * 8 + h;
    float lg2 = log2f(1.f - expf(L0f + (float)h * DLf));
    int i0 = it * 64;
    const u16* qbase = qws + (size_t)bh * 2048 * 128;
    const u16* kbase = kws + (size_t)bh * 2048 * 128;
    const u16* vbase = vTws + (size_t)bh * 256 * 2048;
    int tid = threadIdx.x, lane = tid & 63, w = tid >> 6, lr = lane & 15, lg = lane >> 4;
    bf8_t aq[4];
#pragma unroll
    for (int kk = 0; kk < 4; kk++)
        aq[kk] = *(const bf8_t*)((const char*)qbase + (size_t)(i0 + w * 16 + lr) * 256 + kk * 64 + lg * 16);
    f4_t racc[16];
#pragma unroll
    for (int f = 0; f < 16; f++)
#pragma unroll
        for (int e = 0; e < 4; e++) racc[f][e] = 0.f;
    for (int jt = jlo; jt < jhi; jt++) {
        int j0 = jt * 64;
        int diag = (jt == it);
        float tf = exp2f(64.f * (float)(it - jt) * lg2);
        __syncthreads();
#pragma unroll
        for (int p = 0; p < 4; p++) {                // stage K tile [64][128]
            int flat = p * 4096 + tid * 16;
            int row = flat >> 8, byt = (flat & 255) ^ ((row & 7) << 4);
            gll16((const char*)kbase + (size_t)(j0 + row) * 256 + byt, (char*)Ks + p * 4096 + w * 1024);
        }
#pragma unroll
        for (int p = 0; p < 8; p++) {                // stage Vt tile [256][64]
            int flat = p * 4096 + tid * 16;
            int row = flat >> 7, byt = (flat & 127) ^ ((row & 7) << 4);
            gll16((const char*)vbase + (size_t)row * 4096 + (size_t)j0 * 2 + byt,
                  (char*)Vs + p * 4096 + w * 1024);
        }
        __syncthreads();
        f4_t sacc[4];
#pragma unroll
        for (int f = 0; f < 4; f++)
#pragma unroll
            for (int e = 0; e < 4; e++) sacc[f][e] = 0.f;
#pragma unroll
        for (int kk = 0; kk < 4; kk++)
#pragma unroll
            for (int fn = 0; fn < 4; fn++) {
                int rb = fn * 16 + lr;
                bf8_t bb = *(const bf8_t*)((const char*)Ks + rb * 256 + ((kk * 64 + lg * 16) ^ ((rb & 7) << 4)));
                sacc[fn] = MFMA16(aq[kk], bb, sacc[fn]);
            }
        __syncthreads();                             // K reads done; alias Ks as P
#pragma unroll
        for (int fn = 0; fn < 4; fn++)
#pragma unroll
            for (int r = 0; r < 4; r++) {
                int i_loc = w * 16 + lg * 4 + r;
                int col = fn * 16 + lr;
                float v = diag ? ((i_loc - col >= 0) ? sacc[fn][r] : 0.f) : sacc[fn][r] * tf;
                *(u16*)((char*)Ks + i_loc * 128 + ((col * 2) ^ ((i_loc & 7) << 4))) = f2b(v);
            }
#pragma unroll
        for (int kk = 0; kk < 2; kk++) {
            int ra = w * 16 + lr;
            bf8_t ap = *(const bf8_t*)((const char*)Ks + ra * 128 + ((kk * 64 + lg * 16) ^ ((ra & 7) << 4)));
#pragma unroll
            for (int fn2 = 0; fn2 < 16; fn2++) {
                int rb = fn2 * 16 + lr;
                bf8_t bv = *(const bf8_t*)((const char*)Vs + rb * 128 + ((kk * 64 + lg * 16) ^ ((rb & 7) << 4)));
                racc[fn2] = MFMA16(ap, bv, racc[fn2]);
            }
        }
    }
    __syncthreads();
    u16* St = Vs;
#pragma unroll
    for (int fn2 = 0; fn2 < 16; fn2++)
#pragma unroll
        for (int r = 0; r < 4; r++) {
            int il = w * 16 + lg * 4 + r;
            int dv = fn2 * 16 + lr;
            *(u16*)((char*)St + il * 512 + ((dv * 2) ^ ((il & 15) << 4))) = f2b(racc[fn2][r]);
        }
    __syncthreads();
#pragma unroll
    for (int it2 = 0; it2 < 8; it2++) {
        int chunk = it2 * 256 + tid;
        int il = chunk >> 5, j = chunk & 31;
        uint4 v = *(const uint4*)((const char*)St + il * 512 + ((j * 16) ^ ((il & 15) << 4)));
        char* dst;
        if (toret1) dst = (char*)ret1 + ((size_t)(b * 1024 + i0 - 1024 + il) * 2048 + h * 256) * 2 + j * 16;
        else        dst = (char*)ret0 + ((size_t)(b * 2048 + i0 + il) * 2048 + h * 256) * 2 + j * 16;
        *(uint4*)dst = v;
    }
}

// ---------------- curr_kv partials: block = (t-range of 256, bh) ----------------
__global__ __launch_bounds__(512) void k_currkv(const u16* __restrict__ kTws, const u16* __restrict__ vTws,
                                                const float* __restrict__ gtab, float* __restrict__ part) {
    __shared__ u16 Ks2[128 * 64];
    __shared__ u16 Vws[256 * 64];
    int tr = blockIdx.x;            // 0..7
    int bh = blockIdx.y;            // 0..15
    int h = bh & 7;
    const u16* kT = kTws + (size_t)bh * 128 * 2048;
    const u16* vT = vTws + (size_t)bh * 256 * 2048;
    const float* gt = gtab + h * 2048;
    int tid = threadIdx.x, lane = tid & 63, wid = tid >> 6;
    int wr = wid >> 2, wc = wid & 3, lr = lane & 15, lg = lane >> 4;
    f4_t acc[4][4]; acc_zero(acc);
    for (int tc = 0; tc < 4; tc++) {
        int t0 = tr * 256 + tc * 64;
        __syncthreads();
#pragma unroll
        for (int p = 0; p < 2; p++) {
            int flat = p * 8192 + tid * 16;
            int row = flat >> 7, byt = (flat & 127) ^ ((row & 7) << 4);
            gll16((const char*)kT + (size_t)row * 4096 + (size_t)t0 * 2 + byt,
                  (char*)Ks2 + p * 8192 + wid * 1024);
        }
#pragma unroll
        for (int p = 0; p < 4; p++) {
            int flat = p * 8192 + tid * 16;
            int row = flat >> 7, byt = flat & 127;
            int tt = t0 + (byt >> 1);
            const u16* src = vT + (size_t)row * 2048 + tt;
            u16 tmp[8]; *(uint4*)tmp = *(const uint4*)src;
            const float* gp = gt + tt;
            u16 op[8];
#pragma unroll
            for (int e = 0; e < 8; e++) op[e] = f2b(b2f(tmp[e]) * gp[e]);
            *(uint4*)((char*)Vws + row * 128 + (byt ^ ((row & 7) << 4))) = *(uint4*)op;
        }
        __syncthreads();
#pragma unroll
        for (int kk = 0; kk < 2; kk++) {
            bf8_t a[4], bb[4];
#pragma unroll
            for (int f = 0; f < 4; f++) {
                int ra = wr * 64 + f * 16 + lr;
                a[f] = *(const bf8_t*)((const char*)Ks2 + ra * 128 + ((kk * 64 + lg * 16) ^ ((ra & 7) << 4)));
                int rb = wc * 64 + f * 16 + lr;
                bb[f] = *(const bf8_t*)((const char*)Vws + rb * 128 + ((kk * 64 + lg * 16) ^ ((rb & 7) << 4)));
            }
#pragma unroll
            for (int i = 0; i < 4; i++)
#pragma unroll
                for (int j = 0; j < 4; j++)
                    acc[i][j] = MFMA16(a[i], bb[j], acc[i][j]);
        }
    }
#pragma unroll
    for (int fm = 0; fm < 4; fm++)
#pragma unroll
        for (int fn = 0; fn < 4; fn++)
#pragma unroll
            for (int r = 0; r < 4; r++) {
                int dk = wr * 64 + fm * 16 + lg * 4 + r;
                int dv = wc * 64 + fn * 16 + lr;
                part[((size_t)(bh * 8 + tr)) * 32768 + (size_t)dk * 256 + dv] = acc[fm][fn][r];
            }
}

__global__ __launch_bounds__(256) void k_reduce_ckv(const float* __restrict__ part, float* __restrict__ outc) {
    int i = blockIdx.x * 256 + threadIdx.x;          // 524288
    int bh = i >> 15, wv = i & 32767;
    float s = 0.f;
#pragma unroll
    for (int tr = 0; tr < 8; tr++) s += part[((size_t)(bh * 8 + tr)) * 32768 + wv];
    outc[i] = s;
}

// ---------------- groupnorm(256) * silu-gate -> bf16 (2 groups/wave, 16B I/O) ----------------
__global__ __launch_bounds__(256) void k_gnorm(const u16* __restrict__ ret0, const u16* __restrict__ ret1,
                                               const u16* __restrict__ gateb, u16* __restrict__ gatedb) {
    int wv = threadIdx.x >> 6, lane = threadIdx.x & 63;
    int g = blockIdx.x * 8 + wv * 2 + (lane >> 5);   // group id (0..32767)
    int l32 = lane & 31;
    int row = g >> 3, h = g & 7;                     // row = b*2048 + t
    size_t base = (size_t)row * 2048 + h * 256 + l32 * 8;
    uint4 p0 = *(const uint4*)(ret0 + base);
    float e[8];
    e[0] = b2f((u16)p0.x); e[1] = b2f((u16)(p0.x >> 16));
    e[2] = b2f((u16)p0.y); e[3] = b2f((u16)(p0.y >> 16));
    e[4] = b2f((u16)p0.z); e[5] = b2f((u16)(p0.z >> 16));
    e[6] = b2f((u16)p0.w); e[7] = b2f((u16)(p0.w >> 16));
    if ((row & 2047) >= 1024) {
        size_t b1 = (size_t)((row >> 11) * 1024 + (row & 1023)) * 2048 + h * 256 + l32 * 8;
        uint4 p1 = *(const uint4*)(ret1 + b1);
        e[0] += b2f((u16)p1.x); e[1] += b2f((u16)(p1.x >> 16));
        e[2] += b2f((u16)p1.y); e[3] += b2f((u16)(p1.y >> 16));
        e[4] += b2f((u16)p1.z); e[5] += b2f((u16)(p1.z >> 16));
        e[6] += b2f((u16)p1.w); e[7] += b2f((u16)(p1.w >> 16));
    }
    float s = 0.f, sqs = 0.f;
#pragma unroll
    for (int i = 0; i < 8; i++) { s += e[i]; sqs += e[i] * e[i]; }
#pragma unroll
    for (int m = 1; m < 32; m <<= 1) { s += __shfl_xor(s, m); sqs += __shfl_xor(sqs, m); }
    float mean = s * (1.f / 256.f);
    float var = sqs * (1.f / 256.f) - mean * mean;
    float inv = rsqrtf(var + 1e-5f);
    uint4 gp = *(const uint4*)(gateb + base);
    u32 gw[4] = {gp.x, gp.y, gp.z, gp.w};
    uint4 ov;
    u32* op = (u32*)&ov;
#pragma unroll
    for (int i = 0; i < 4; i++) {
        float g0 = b2f((u16)gw[i]), g1 = b2f((u16)(gw[i] >> 16));
        op[i] = (u32)f2b((e[2 * i] - mean) * inv * g0) |
                ((u32)f2b((e[2 * i + 1] - mean) * inv * g1) << 16);
    }
    *(uint4*)(gatedb + base) = ov;
}

extern "C" void kernel_launch(void* const* d_in, const int* in_sizes, int n_in,
                              void* d_out, int out_size, void* d_ws, size_t ws_size,
                              hipStream_t stream) {
    const float* x    = (const float*)d_in[0];
    const float* Wqkv = (const float*)d_in[1];
    const float* Wg   = (const float*)d_in[2];
    const float* Wp   = (const float*)d_in[3];
    const float* bp   = (const float*)d_in[4];
    float* outp   = (float*)d_out;
    float* outckv = outp + (size_t)BB * TT * HIDN;

    char* ws = (char*)d_ws;
    const size_t MB = 1024 * 1024;
    u16*   xb     = (u16*)(ws);               // 0..8
    u16*   WqkvT  = (u16*)(ws + 8 * MB);      // 8..16  [4096][1024]
    u16*   WgT    = (u16*)(ws + 16 * MB);     // 16..20 [2048][1024] (contiguous -> Wcat [6144][1024])
    u16*   WpT    = (u16*)(ws + 20 * MB);     // 20..24 [1024][2048]
    u32*   cqp    = (u32*)(ws + 24 * MB);     // 24..28 packed q table
    u32*   ckp    = (u32*)(ws + 28 * MB);     // 28..32 packed k table
    u16*   gateb  = (u16*)(ws + 32 * MB);     // 32..48 [4096][2048]
    u16*   qw     = (u16*)(ws + 48 * MB);     // 48..56 [bh][t][128] prescaled q
    u16*   kw     = (u16*)(ws + 56 * MB);     // 56..64 prescaled k
    u16*   kT     = (u16*)(ws + 64 * MB);     // 64..72 [bh][128][t] unscaled k
    u16*   vT     = (u16*)(ws + 72 * MB);     // 72..88 [bh][256][t]
    u16*   ret0b  = (u16*)(ws + 88 * MB);     // 88..104 bf16 [b][2048][2048] (after reduce_ckv)
    u16*   ret1b  = (u16*)(ws + 104 * MB);    // 104..112 bf16 [b][1024][2048]
    float* ckvp   = (float*)(ws + 88 * MB);   // 16MB partials (dead before retention writes ret0b)
    float* gtab   = (float*)(ws + 120 * MB);            // 64KB
    float* gkt    = (float*)(ws + 120 * MB + 65536);    // 2KB
    // aliases:
    u16*   gatedb = (u16*)(ws + 48 * MB);     // 16MB over qw/kw (dead after retention)

    hipLaunchKernelGGL(k_tables, dim3(4162), dim3(256), 0, stream, cqp, ckp, gtab, gkt);
    hipLaunchKernelGGL(k_cvt, dim3(4096), dim3(256), 0, stream, x, xb);
    hipLaunchKernelGGL(k_tposeF, dim3(8192), dim3(32, 8), 0, stream, Wqkv, Wg, Wp, WqkvT, WgT, WpT);
    hipLaunchKernelGGL(k_gemm_qkvg8, dim3(384), dim3(512), 0, stream,
                       xb, WqkvT, cqp, ckp, gkt, qw, kw, kT, vT, gateb);
    hipLaunchKernelGGL(k_currkv, dim3(8, 16), dim3(512), 0, stream, kT, vT, gtab, ckvp);
    hipLaunchKernelGGL(k_reduce_ckv, dim3(2048), dim3(256), 0, stream, ckvp, outckv);
    hipLaunchKernelGGL(k_retention, dim3(48, 8, 2), dim3(256), 0, stream, qw, kw, vT, ret0b, ret1b);
    hipLaunchKernelGGL(k_gnorm, dim3(4096), dim3(256), 0, stream, ret0b, ret1b, gateb, gatedb);
    hipLaunchKernelGGL(k_gemm_out2, dim3(8, 32), dim3(512), 0, stream, gatedb, WpT, bp, outp);
}

// Round 15
// 204.671 us; speedup vs baseline: 3.2678x; 1.0189x over previous
//
#include <hip/hip_runtime.h>

typedef unsigned short u16;
typedef unsigned int   u32;
typedef unsigned long long u64;

typedef __attribute__((ext_vector_type(8))) short bf8_t;   // 8 x bf16
typedef __attribute__((ext_vector_type(4))) float f4_t;

#define DEVI __device__ __forceinline__
#define MFMA16(a,b,c) __builtin_amdgcn_mfma_f32_16x16x32_bf16((a),(b),(c),0,0,0)

#define BB   2
#define TT   2048
#define HIDN 1024
#define L0f  (-3.4657359027997265f)   // ln(1/32)
#define DLf  (-0.3960841031714215f)   // (ln(1/512)-ln(1/32))/7
#define SCL  (0.08838834764831845f)   // 128^-0.5

DEVI u16 f2b(float f) {                 // f32 -> bf16 RNE
    u32 u = __float_as_uint(f);
    u += 0x7FFFu + ((u >> 16) & 1u);
    return (u16)(u >> 16);
}
DEVI float b2f(u16 u) { return __uint_as_float(((u32)u) << 16); }

// async global->LDS, 16B per lane; lds dest = wave-uniform base + lane*16
DEVI void gll16(const void* g, void* l) {
    __builtin_amdgcn_global_load_lds((const __attribute__((address_space(1))) void*)g,
                                     (__attribute__((address_space(3))) void*)l, 16, 0, 0);
}

// ======== fused preprocessing: xPos/gamma tables + x->bf16 + 3 weight transposes ========
// blocks 0..4161: tables (trig-heavy; issued first so tail overlaps)
// blocks 4162..12353: weight transpose; blocks 12354..16449: x convert
__global__ __launch_bounds__(256) void k_prep(
    const float* __restrict__ x, const float* __restrict__ Wqkv,
    const float* __restrict__ Wg, const float* __restrict__ Wp,
    u32* __restrict__ cqp, u32* __restrict__ ckp,
    float* __restrict__ gt, float* __restrict__ gk,
    u16* __restrict__ xb, u16* __restrict__ oQ, u16* __restrict__ oG, u16* __restrict__ oP) {
    int bx = blockIdx.x;
    if (bx < 4096) {                                 // ---- packed xPos tables ----
        int idx = bx * 256 + threadIdx.x;            // t*512 + m
        int t = idx >> 9, m = idx & 511;
        float base = (2.f * (float)m + 409.6f) * (1.f / 1433.6f);
        float s = exp2f(log2f(base) * ((float)t * (1.f / 512.f)));
        float invf = exp2f(-(float)m * (13.287712379549449f / 512.f)); // 10000^{-m/512}
        float sn, cs;
        sincosf((float)t * invf, &sn, &cs);
        int h = m >> 6;
        float lg2h = log2f(1.f - expf(L0f + (float)h * DLf));
        float qf = s * SCL * exp2f((float)(t & 63) * lg2h);
        cqp[idx] = (u32)f2b(cs * qf) | ((u32)f2b(sn * qf) << 16);
        float is = 1.f / s;
        ckp[idx] = (u32)f2b(cs * is) | ((u32)f2b(sn * is) << 16);
        return;
    }
    if (bx < 4162) {                                 // ---- gamma tables ----
        int i = (bx - 4096) * 256 + threadIdx.x;     // 16896 entries
        if (i < 16384) {                             // gtab[h][t] = g^(2047-t)
            int h = i >> 11, t = i & 2047;
            float lg2 = log2f(1.f - expf(L0f + (float)h * DLf));
            gt[i] = exp2f((float)(2047 - t) * lg2);
        } else {                                     // gk[h][d] = g^-d
            int idx = i - 16384;                     // 512 entries
            int h = idx >> 6, d = idx & 63;
            float lg2 = log2f(1.f - expf(L0f + (float)h * DLf));
            gk[idx] = exp2f(-(float)d * lg2);
        }
        return;
    }
    if (bx < 12354) {                                // ---- weight transpose+convert ----
        __shared__ float tile[32][33];
        int b2 = bx - 4162;
        const float* in; u16* out; int R, C, cx, ry;
        if (b2 < 4096)      { in = Wqkv; out = oQ; R = 1024; C = 4096; cx = b2 & 127; ry = b2 >> 7; }
        else if (b2 < 6144) { int b3 = b2 - 4096; in = Wg; out = oG; R = 1024; C = 2048; cx = b3 & 63; ry = b3 >> 6; }
        else                { int b3 = b2 - 6144; in = Wp; out = oP; R = 2048; C = 1024; cx = b3 & 31; ry = b3 >> 5; }
        int c0 = cx * 32, r0 = ry * 32;
        int tx = threadIdx.x & 31, ty = threadIdx.x >> 5;    // (32,8) flattened
#pragma unroll
        for (int i = 0; i < 4; i++)
            tile[ty * 4 + i][tx] = in[(size_t)(r0 + ty * 4 + i) * C + c0 + tx];
        __syncthreads();
#pragma unroll
        for (int i = 0; i < 4; i++)
            out[(size_t)(c0 + ty * 4 + i) * R + r0 + tx] = f2b(tile[tx][ty * 4 + i]);
        return;
    }
    {                                                // ---- x f32 -> bf16 ----
        int i = (bx - 12354) * 256 + threadIdx.x;
        float4 v = ((const float4*)x)[i];
        u64 pk = (u64)f2b(v.x) | ((u64)f2b(v.y) << 16) | ((u64)f2b(v.z) << 32) | ((u64)f2b(v.w) << 48);
        ((u64*)xb)[i] = pk;
    }
}

// =============== 256x256 8-wave, BK=64, dbuf-LDS, fine-grained phase schedule ===============
DEVI void stage_chunk(const u16* __restrict__ A, const u16* __restrict__ B,
                      int m0, int n0, int kt, char* buf, int id, int wid, int lane) {
    int j = id & 3;
    int flat = j * 8192 + wid * 1024 + lane * 16;
    int row = flat >> 7, byt = (flat & 127) ^ ((row & 7) << 4);
    if (id < 4)
        gll16((const char*)A + (size_t)(m0 + row) * 2048 + kt * 128 + byt,
              buf + j * 8192 + wid * 1024);
    else
        gll16((const char*)B + (size_t)(n0 + row) * 2048 + kt * 128 + byt,
              buf + 32768 + j * 8192 + wid * 1024);
}

#define QCORE(kk, fmh, LOADB)                                                         \
    {                                                                                 \
        bf8_t a_[4];                                                                  \
        _Pragma("unroll")                                                             \
        for (int f = 0; f < 4; f++) {                                                 \
            int ra = 128 * wr + ((fmh) * 4 + f) * 16 + lr;                            \
            a_[f] = *(const bf8_t*)(bA + ra * 128 + (((kk) * 64 + lg * 16) ^ ((ra & 7) << 4))); \
        }                                                                             \
        if (LOADB) {                                                                  \
            _Pragma("unroll")                                                         \
            for (int f = 0; f < 4; f++) {                                             \
                int rb = 64 * wc + f * 16 + lr;                                       \
                breg[f] = *(const bf8_t*)(bB + rb * 128 + (((kk) * 64 + lg * 16) ^ ((rb & 7) << 4))); \
            }                                                                         \
        }                                                                             \
        __builtin_amdgcn_s_barrier();                                                 \
        __builtin_amdgcn_s_setprio(1);                                                \
        _Pragma("unroll")                                                             \
        for (int f = 0; f < 4; f++)                                                   \
            _Pragma("unroll")                                                         \
            for (int j = 0; j < 4; j++)                                               \
                acc[(fmh) * 4 + f][j] = MFMA16(a_[f], breg[j], acc[(fmh) * 4 + f][j]); \
        __builtin_amdgcn_s_setprio(0);                                                \
    }

__global__ __launch_bounds__(512, 2) void k_gemm_qkvg8(
    const u16* __restrict__ xb, const u16* __restrict__ Wcat,
    const u32* __restrict__ cqp, const u32* __restrict__ ckp, const float* __restrict__ gkt,
    u16* __restrict__ qw, u16* __restrict__ kw, u16* __restrict__ kT, u16* __restrict__ vT,
    u16* __restrict__ gateb) {
    __shared__ __align__(16) char L[131072];         // 2 x (A 32KB + B 32KB)
    int flat = blockIdx.x;
    int swz = (flat & 7) * 48 + (flat >> 3);         // XCD-bijective (384 = 8*48), m-major
    int m0 = (swz / 24) * 256, n0 = (swz % 24) * 256;
    int tid = threadIdx.x, lane = tid & 63, wid = tid >> 6;
    int wr = wid >> 2, wc = wid & 3, lr = lane & 15, lg = lane >> 4;
    f4_t acc[8][4];
#pragma unroll
    for (int i = 0; i < 8; i++)
#pragma unroll
        for (int j = 0; j < 4; j++)
#pragma unroll
            for (int e = 0; e < 4; e++) acc[i][j][e] = 0.f;
    // prologue: issue all 8 chunks of tile 0 in uniform order; ensure first 6
    stage_chunk(xb, Wcat, m0, n0, 0, L, 0, wid, lane);
    stage_chunk(xb, Wcat, m0, n0, 0, L, 2, wid, lane);
    stage_chunk(xb, Wcat, m0, n0, 0, L, 4, wid, lane);
    stage_chunk(xb, Wcat, m0, n0, 0, L, 5, wid, lane);
    stage_chunk(xb, Wcat, m0, n0, 0, L, 6, wid, lane);
    stage_chunk(xb, Wcat, m0, n0, 0, L, 7, wid, lane);
    stage_chunk(xb, Wcat, m0, n0, 0, L, 1, wid, lane);
    stage_chunk(xb, Wcat, m0, n0, 0, L, 3, wid, lane);
    asm volatile("s_waitcnt vmcnt(2)" ::: "memory");
    __builtin_amdgcn_s_barrier();
    for (int kt = 0; kt < 16; ++kt) {
        const char* bA = L + (kt & 1) * 65536;
        const char* bB = bA + 32768;
        char* nbuf = L + ((kt + 1) & 1) * 65536;
        bf8_t breg[4];
        // phase 0: MFMA(kk0,fmh0) reads A0/A2 + B(wc); issue next-tile A0,A2
        if (kt < 15) {
            stage_chunk(xb, Wcat, m0, n0, kt + 1, nbuf, 0, wid, lane);
            stage_chunk(xb, Wcat, m0, n0, kt + 1, nbuf, 2, wid, lane);
        }
        QCORE(0, 0, 1)
        if (kt < 15) { asm volatile("s_waitcnt vmcnt(2)" ::: "memory"); }  // tile-kt A1,A3 done
        else         { asm volatile("s_waitcnt vmcnt(0)" ::: "memory"); }
        __builtin_amdgcn_s_barrier();
        // phase 1: MFMA(kk0,fmh1) reads A1/A3; issue next-tile B4,B5
        if (kt < 15) {
            stage_chunk(xb, Wcat, m0, n0, kt + 1, nbuf, 4, wid, lane);
            stage_chunk(xb, Wcat, m0, n0, kt + 1, nbuf, 5, wid, lane);
        }
        QCORE(0, 1, 0)
        __builtin_amdgcn_s_barrier();
        // phase 2: MFMA(kk1,fmh0); issue next-tile B6,B7
        if (kt < 15) {
            stage_chunk(xb, Wcat, m0, n0, kt + 1, nbuf, 6, wid, lane);
            stage_chunk(xb, Wcat, m0, n0, kt + 1, nbuf, 7, wid, lane);
        }
        QCORE(1, 0, 1)
        __builtin_amdgcn_s_barrier();
        // phase 3: MFMA(kk1,fmh1); issue next-tile A1,A3
        if (kt < 15) {
            stage_chunk(xb, Wcat, m0, n0, kt + 1, nbuf, 1, wid, lane);
            stage_chunk(xb, Wcat, m0, n0, kt + 1, nbuf, 3, wid, lane);
        }
        QCORE(1, 1, 0)
        if (kt < 15) { asm volatile("s_waitcnt vmcnt(2)" ::: "memory"); }  // next tile first-6 done
        __builtin_amdgcn_s_barrier();
    }
    // ---------------- epilogue: stage 256x256 tile in L (rows of 512B), coalesced out ----------
    __syncthreads();                                 // drain remaining loads; release L
    char* SP = L;
    int b = m0 >> 11, t0 = m0 & 2047;
    if (n0 < 4096 && n0 >= 2048) {                   // ---- v: stage transposed [dv][t] ----
        int h = (n0 - 2048) >> 8;
#pragma unroll
        for (int fm = 0; fm < 8; fm++)
#pragma unroll
            for (int fn = 0; fn < 4; fn++) {
                int dv = wc * 64 + fn * 16 + lr;
                int rowb = wr * 128 + fm * 16 + lg * 4;
                u64 pk = 0;
#pragma unroll
                for (int r = 0; r < 4; r++) pk |= ((u64)f2b(acc[fm][fn][r])) << (16 * r);
                *(u64*)(SP + dv * 512 + ((rowb * 2) ^ ((dv & 15) << 4))) = pk;
            }
        __syncthreads();
#pragma unroll
        for (int it = 0; it < 16; it++) {
            int chunk = it * 512 + tid;
            int dv = chunk >> 5, j = chunk & 31;
            uint4 v = *(const uint4*)(SP + dv * 512 + ((j * 16) ^ ((dv & 15) << 4)));
            *(uint4*)(vT + ((size_t)((b * 8 + h) * 256 + dv)) * 2048 + t0 + j * 8) = v;
        }
    } else if (n0 < 2048) {                          // ---- q or k: rotate (+prescale) ----
        int isK = n0 >= 1024;
        const u32* cT = isK ? ckp : cqp;
        int hb = (n0 >> 7) & 7;
#pragma unroll
        for (int fm = 0; fm < 8; fm++)
#pragma unroll
            for (int fn = 0; fn < 4; fn++) {
                int col = wc * 64 + fn * 16 + lr;
                int gq = (n0 & 1023) + col;
                int mi = gq >> 1, h = gq >> 7;
                u64 pk = 0;
#pragma unroll
                for (int r = 0; r < 4; r++) {
                    int rowl = wr * 128 + fm * 16 + lg * 4 + r;
                    int t = t0 + rowl;
                    float v = acc[fm][fn][r];
                    float pv = __shfl_xor(v, 1);
                    u32 cp = cT[t * 512 + mi];
                    float cs = b2f((u16)cp), sn = b2f((u16)(cp >> 16));
                    float o = (col & 1) ? (v * cs + pv * sn) : (v * cs - pv * sn);
                    if (isK) {
                        pk |= ((u64)f2b(o)) << (16 * r);
                        o *= gkt[h * 64 + (t & 63)];
                    }
                    *(u16*)(SP + rowl * 512 + ((col * 2) ^ ((rowl & 15) << 4))) = f2b(o);
                }
                if (isK)
                    *(u64*)&kT[((size_t)((b * 8 + h) * 128 + (gq & 127))) * 2048 + t0 + wr * 128 + fm * 16 + lg * 4] = pk;
            }
        __syncthreads();
#pragma unroll
        for (int it = 0; it < 16; it++) {
            int chunk = it * 512 + tid;
            int r = chunk >> 5, j = chunk & 31;
            uint4 v = *(const uint4*)(SP + r * 512 + ((j * 16) ^ ((r & 15) << 4)));
            int hh = hb + (j >> 4);
            u16* g = (isK ? kw : qw) + ((size_t)((b * 8 + hh) * 2048 + t0 + r)) * 128 + (j & 15) * 8;
            *(uint4*)g = v;
        }
    } else {                                         // ---- gate: silu ----
        int c0 = n0 - 4096;
#pragma unroll
        for (int fm = 0; fm < 8; fm++)
#pragma unroll
            for (int fn = 0; fn < 4; fn++) {
                int col = wc * 64 + fn * 16 + lr;
#pragma unroll
                for (int r = 0; r < 4; r++) {
                    int rowl = wr * 128 + fm * 16 + lg * 4 + r;
                    float gg = acc[fm][fn][r];
                    *(u16*)(SP + rowl * 512 + ((col * 2) ^ ((rowl & 15) << 4))) = f2b(gg / (1.f + expf(-gg)));
                }
            }
        __syncthreads();
#pragma unroll
        for (int it = 0; it < 16; it++) {
            int chunk = it * 512 + tid;
            int r = chunk >> 5, j = chunk & 31;
            uint4 v = *(const uint4*)(SP + r * 512 + ((j * 16) ^ ((r & 15) << 4)));
            *(uint4*)(gateb + (size_t)(b * 2048 + t0 + r) * 2048 + c0 + j * 8) = v;
        }
    }
}

// ======== GEMM3: out = gated @ Wp^T + bp, 128x128, full K=2048, lag-2 triple buffer ========
DEVI void stage_o(const u16* __restrict__ A, const u16* __restrict__ B,
                  int m0, int n0, int kt, char* buf, int id, int wid, int lane) {
    int j = id & 1;
    int flat = j * 8192 + wid * 1024 + lane * 16;
    int row = flat >> 7, byt = (flat & 127) ^ ((row & 7) << 4);
    if (id < 2)
        gll16((const char*)A + (size_t)(m0 + row) * 4096 + kt * 128 + byt,
              buf + j * 8192 + wid * 1024);
    else
        gll16((const char*)B + (size_t)(n0 + row) * 4096 + kt * 128 + byt,
              buf + 16384 + j * 8192 + wid * 1024);
}

__global__ __launch_bounds__(512, 2) void k_gemm_out2(const u16* __restrict__ gdb,
                                                      const u16* __restrict__ Wt,
                                                      const float* __restrict__ bp,
                                                      float* __restrict__ outp) {
    __shared__ __align__(16) char Lo[98304];         // 3 x (A 16KB + B 16KB)
    int m0 = blockIdx.y * 128, n0 = blockIdx.x * 128;
    int tid = threadIdx.x, lane = tid & 63, wid = tid >> 6;
    int wr = wid >> 1, wc = wid & 1, lr = lane & 15, lg = lane >> 4;
    f4_t acc[2][4];
#pragma unroll
    for (int i = 0; i < 2; i++)
#pragma unroll
        for (int j = 0; j < 4; j++)
#pragma unroll
            for (int e = 0; e < 4; e++) acc[i][j][e] = 0.f;
    // prologue: tiles 0 and 1 in flight; ensure tile 0
#pragma unroll
    for (int c = 0; c < 4; c++) stage_o(gdb, Wt, m0, n0, 0, Lo, c, wid, lane);
#pragma unroll
    for (int c = 0; c < 4; c++) stage_o(gdb, Wt, m0, n0, 1, Lo + 32768, c, wid, lane);
    asm volatile("s_waitcnt vmcnt(4)" ::: "memory");
    __builtin_amdgcn_s_barrier();
    for (int kt = 0; kt < 32; ++kt) {
        const char* bA = Lo + (kt % 3) * 32768;
        const char* bB = bA + 16384;
        if (kt < 30) {
            char* nbuf = Lo + ((kt + 2) % 3) * 32768;
#pragma unroll
            for (int c = 0; c < 4; c++) stage_o(gdb, Wt, m0, n0, kt + 2, nbuf, c, wid, lane);
        }
        __builtin_amdgcn_s_setprio(1);
#pragma unroll
        for (int kk = 0; kk < 2; kk++) {
            bf8_t a[2], b[4];
#pragma unroll
            for (int f = 0; f < 2; f++) {
                int ra = wr * 32 + f * 16 + lr;
                a[f] = *(const bf8_t*)(bA + ra * 128 + ((kk * 64 + lg * 16) ^ ((ra & 7) << 4)));
            }
#pragma unroll
            for (int f = 0; f < 4; f++) {
                int rb = wc * 64 + f * 16 + lr;
                b[f] = *(const bf8_t*)(bB + rb * 128 + ((kk * 64 + lg * 16) ^ ((rb & 7) << 4)));
            }
#pragma unroll
            for (int i = 0; i < 2; i++)
#pragma unroll
                for (int j = 0; j < 4; j++)
                    acc[i][j] = MFMA16(a[i], b[j], acc[i][j]);
        }
        __builtin_amdgcn_s_setprio(0);
        if (kt < 30) { asm volatile("s_waitcnt vmcnt(4)" ::: "memory"); }  // tile kt+1 landed
        else         { asm volatile("s_waitcnt vmcnt(0)" ::: "memory"); }
        __builtin_amdgcn_s_barrier();
    }
    // ---- epilogue: stage f32 tile 128x512B in Lo (+bias), coalesced out ----
    __syncthreads();
    float* SMf = (float*)Lo;
    float bv[4];
#pragma unroll
    for (int fn = 0; fn < 4; fn++) bv[fn] = bp[n0 + wc * 64 + fn * 16 + lr];
#pragma unroll
    for (int fm = 0; fm < 2; fm++)
#pragma unroll
        for (int fn = 0; fn < 4; fn++) {
            int col = wc * 64 + fn * 16 + lr;
#pragma unroll
            for (int r = 0; r < 4; r++) {
                int rowl = wr * 32 + fm * 16 + lg * 4 + r;
                *(float*)((char*)SMf + rowl * 512 + ((col * 4) ^ ((rowl & 7) << 6))) = acc[fm][fn][r] + bv[fn];
            }
        }
    __syncthreads();
#pragma unroll
    for (int it2 = 0; it2 < 8; it2++) {
        int chunk = it2 * 512 + tid;
        int rowl = chunk >> 5, j = chunk & 31;
        f4_t v = *(const f4_t*)((const char*)SMf + rowl * 512 + ((j * 16) ^ ((rowl & 7) << 6)));
        *(f4_t*)((char*)outp + ((size_t)(m0 + rowl) * 1024 + n0) * 4 + j * 16) = v;
    }
}

DEVI void acc_zero(f4_t acc[4][4]) {
#pragma unroll
    for (int i = 0; i < 4; i++)
#pragma unroll
        for (int j = 0; j < 4; j++)
#pragma unroll
            for (int e = 0; e < 4; e++) acc[i][j][e] = 0.f;
}

// ---------------- retention: Q in regs, factorized decay, wave-local PV ----------------
__global__ __launch_bounds__(256, 3) void k_retention(const u16* __restrict__ qws, const u16* __restrict__ kws,
                                                      const u16* __restrict__ vTws,
                                                      u16* __restrict__ ret0, u16* __restrict__ ret1) {
    __shared__ u16 SMr[64 * 128 + 256 * 64];         // 48KB
    u16* Ks = SMr;                                   // 16KB; P aliases it
    u16* Vs = SMr + 64 * 128;                        // 32KB; output staging aliases it
    int x = blockIdx.x;
    int it, jlo, jhi, toret1;
    if (x < 16)      { it = 15 - x;  jlo = 0;              jhi = it + 1;         toret1 = 0; }
    else if (x < 32) { it = x;       jlo = 0;              jhi = (it + 2) >> 1;  toret1 = 0; }
    else             { it = x - 16;  jlo = (it + 2) >> 1;  jhi = it + 1;         toret1 = 1; }
    int h = blockIdx.y, b = blockIdx.z;
    int bh = b * 8 + h;
    float lg2 = log2f(1.f - expf(L0f + (float)h * DLf));
    int i0 = it * 64;
    const u16* qbase = qws + (size_t)bh * 2048 * 128;
    const u16* kbase = kws + (size_t)bh * 2048 * 128;
    const u16* vbase = vTws + (size_t)bh * 256 * 2048;
    int tid = threadIdx.x, lane = tid & 63, w = tid >> 6, lr = lane & 15, lg = lane >> 4;
    bf8_t aq[4];
#pragma unroll
    for (int kk = 0; kk < 4; kk++)
        aq[kk] = *(const bf8_t*)((const char*)qbase + (size_t)(i0 + w * 16 + lr) * 256 + kk * 64 + lg * 16);
    f4_t racc[16];
#pragma unroll
    for (int f = 0; f < 16; f++)
#pragma unroll
        for (int e = 0; e < 4; e++) racc[f][e] = 0.f;
    for (int jt = jlo; jt < jhi; jt++) {
        int j0 = jt * 64;
        int diag = (jt == it);
        float tf = exp2f(64.f * (float)(it - jt) * lg2);
        __syncthreads();
#pragma unroll
        for (int p = 0; p < 4; p++) {                // stage K tile [64][128]
            int flat = p * 4096 + tid * 16;
            int row = flat >> 8, byt = (flat & 255) ^ ((row & 7) << 4);
            gll16((const char*)kbase + (size_t)(j0 + row) * 256 + byt, (char*)Ks + p * 4096 + w * 1024);
        }
#pragma unroll
        for (int p = 0; p < 8; p++) {                // stage Vt tile [256][64]
            int flat = p * 4096 + tid * 16;
            int row = flat >> 7, byt = (flat & 127) ^ ((row & 7) << 4);
            gll16((const char*)vbase + (size_t)row * 4096 + (size_t)j0 * 2 + byt,
                  (char*)Vs + p * 4096 + w * 1024);
        }
        __syncthreads();
        f4_t sacc[4];
#pragma unroll
        for (int f = 0; f < 4; f++)
#pragma unroll
            for (int e = 0; e < 4; e++) sacc[f][e] = 0.f;
#pragma unroll
        for (int kk = 0; kk < 4; kk++)
#pragma unroll
            for (int fn = 0; fn < 4; fn++) {
                int rb = fn * 16 + lr;
                bf8_t bb = *(const bf8_t*)((const char*)Ks + rb * 256 + ((kk * 64 + lg * 16) ^ ((rb & 7) << 4)));
                sacc[fn] = MFMA16(aq[kk], bb, sacc[fn]);
            }
        __syncthreads();                             // K reads done; alias Ks as P
#pragma unroll
        for (int fn = 0; fn < 4; fn++)
#pragma unroll
            for (int r = 0; r < 4; r++) {
                int i_loc = w * 16 + lg * 4 + r;
                int col = fn * 16 + lr;
                float v = diag ? ((i_loc - col >= 0) ? sacc[fn][r] : 0.f) : sacc[fn][r] * tf;
                *(u16*)((char*)Ks + i_loc * 128 + ((col * 2) ^ ((i_loc & 7) << 4))) = f2b(v);
            }
#pragma unroll
        for (int kk = 0; kk < 2; kk++) {
            int ra = w * 16 + lr;
            bf8_t ap = *(const bf8_t*)((const char*)Ks + ra * 128 + ((kk * 64 + lg * 16) ^ ((ra & 7) << 4)));
#pragma unroll
            for (int fn2 = 0; fn2 < 16; fn2++) {
                int rb = fn2 * 16 + lr;
                bf8_t bv = *(const bf8_t*)((const char*)Vs + rb * 128 + ((kk * 64 + lg * 16) ^ ((rb & 7) << 4)));
                racc[fn2] = MFMA16(ap, bv, racc[fn2]);
            }
        }
    }
    __syncthreads();
    u16* St = Vs;
#pragma unroll
    for (int fn2 = 0; fn2 < 16; fn2++)
#pragma unroll
        for (int r = 0; r < 4; r++) {
            int il = w * 16 + lg * 4 + r;
            int dv = fn2 * 16 + lr;
            *(u16*)((char*)St + il * 512 + ((dv * 2) ^ ((il & 15) << 4))) = f2b(racc[fn2][r]);
        }
    __syncthreads();
#pragma unroll
    for (int it2 = 0; it2 < 8; it2++) {
        int chunk = it2 * 256 + tid;
        int il = chunk >> 5, j = chunk & 31;
        uint4 v = *(const uint4*)((const char*)St + il * 512 + ((j * 16) ^ ((il & 15) << 4)));
        char* dst;
        if (toret1) dst = (char*)ret1 + ((size_t)(b * 1024 + i0 - 1024 + il) * 2048 + h * 256) * 2 + j * 16;
        else        dst = (char*)ret0 + ((size_t)(b * 2048 + i0 + il) * 2048 + h * 256) * 2 + j * 16;
        *(uint4*)dst = v;
    }
}

// ---------------- curr_kv partials: block = (t-range of 256, bh) ----------------
__global__ __launch_bounds__(512) void k_currkv(const u16* __restrict__ kTws, const u16* __restrict__ vTws,
                                                const float* __restrict__ gtab, float* __restrict__ part) {
    __shared__ u16 Ks2[128 * 64];
    __shared__ u16 Vws[256 * 64];
    int tr = blockIdx.x;            // 0..7
    int bh = blockIdx.y;            // 0..15
    int h = bh & 7;
    const u16* kT = kTws + (size_t)bh * 128 * 2048;
    const u16* vT = vTws + (size_t)bh * 256 * 2048;
    const float* gt = gtab + h * 2048;
    int tid = threadIdx.x, lane = tid & 63, wid = tid >> 6;
    int wr = wid >> 2, wc = wid & 3, lr = lane & 15, lg = lane >> 4;
    f4_t acc[4][4]; acc_zero(acc);
    for (int tc = 0; tc < 4; tc++) {
        int t0 = tr * 256 + tc * 64;
        __syncthreads();
#pragma unroll
        for (int p = 0; p < 2; p++) {
            int flat = p * 8192 + tid * 16;
            int row = flat >> 7, byt = (flat & 127) ^ ((row & 7) << 4);
            gll16((const char*)kT + (size_t)row * 4096 + (size_t)t0 * 2 + byt,
                  (char*)Ks2 + p * 8192 + wid * 1024);
        }
#pragma unroll
        for (int p = 0; p < 4; p++) {
            int flat = p * 8192 + tid * 16;
            int row = flat >> 7, byt = flat & 127;
            int tt = t0 + (byt >> 1);
            const u16* src = vT + (size_t)row * 2048 + tt;
            u16 tmp[8]; *(uint4*)tmp = *(const uint4*)src;
            const float* gp = gt + tt;
            u16 op[8];
#pragma unroll
            for (int e = 0; e < 8; e++) op[e] = f2b(b2f(tmp[e]) * gp[e]);
            *(uint4*)((char*)Vws + row * 128 + (byt ^ ((row & 7) << 4))) = *(uint4*)op;
        }
        __syncthreads();
#pragma unroll
        for (int kk = 0; kk < 2; kk++) {
            bf8_t a[4], bb[4];
#pragma unroll
            for (int f = 0; f < 4; f++) {
                int ra = wr * 64 + f * 16 + lr;
                a[f] = *(const bf8_t*)((const char*)Ks2 + ra * 128 + ((kk * 64 + lg * 16) ^ ((ra & 7) << 4)));
                int rb = wc * 64 + f * 16 + lr;
                bb[f] = *(const bf8_t*)((const char*)Vws + rb * 128 + ((kk * 64 + lg * 16) ^ ((rb & 7) << 4)));
            }
#pragma unroll
            for (int i = 0; i < 4; i++)
#pragma unroll
                for (int j = 0; j < 4; j++)
                    acc[i][j] = MFMA16(a[i], bb[j], acc[i][j]);
        }
    }
#pragma unroll
    for (int fm = 0; fm < 4; fm++)
#pragma unroll
        for (int fn = 0; fn < 4; fn++)
#pragma unroll
            for (int r = 0; r < 4; r++) {
                int dk = wr * 64 + fm * 16 + lg * 4 + r;
                int dv = wc * 64 + fn * 16 + lr;
                part[((size_t)(bh * 8 + tr)) * 32768 + (size_t)dk * 256 + dv] = acc[fm][fn][r];
            }
}

__global__ __launch_bounds__(256) void k_reduce_ckv(const float* __restrict__ part, float* __restrict__ outc) {
    int i = blockIdx.x * 256 + threadIdx.x;          // 524288
    int bh = i >> 15, wv = i & 32767;
    float s = 0.f;
#pragma unroll
    for (int tr = 0; tr < 8; tr++) s += part[((size_t)(bh * 8 + tr)) * 32768 + wv];
    outc[i] = s;
}

// ---------------- groupnorm(256) * silu-gate -> bf16 (2 groups/wave, 16B I/O) ----------------
__global__ __launch_bounds__(256) void k_gnorm(const u16* __restrict__ ret0, const u16* __restrict__ ret1,
                                               const u16* __restrict__ gateb, u16* __restrict__ gatedb) {
    int wv = threadIdx.x >> 6, lane = threadIdx.x & 63;
    int g = blockIdx.x * 8 + wv * 2 + (lane >> 5);   // group id (0..32767)
    int l32 = lane & 31;
    int row = g >> 3, h = g & 7;                     // row = b*2048 + t
    size_t base = (size_t)row * 2048 + h * 256 + l32 * 8;
    uint4 p0 = *(const uint4*)(ret0 + base);
    float e[8];
    e[0] = b2f((u16)p0.x); e[1] = b2f((u16)(p0.x >> 16));
    e[2] = b2f((u16)p0.y); e[3] = b2f((u16)(p0.y >> 16));
    e[4] = b2f((u16)p0.z); e[5] = b2f((u16)(p0.z >> 16));
    e[6] = b2f((u16)p0.w); e[7] = b2f((u16)(p0.w >> 16));
    if ((row & 2047) >= 1024) {
        size_t b1 = (size_t)((row >> 11) * 1024 + (row & 1023)) * 2048 + h * 256 + l32 * 8;
        uint4 p1 = *(const uint4*)(ret1 + b1);
        e[0] += b2f((u16)p1.x); e[1] += b2f((u16)(p1.x >> 16));
        e[2] += b2f((u16)p1.y); e[3] += b2f((u16)(p1.y >> 16));
        e[4] += b2f((u16)p1.z); e[5] += b2f((u16)(p1.z >> 16));
        e[6] += b2f((u16)p1.w); e[7] += b2f((u16)(p1.w >> 16));
    }
    float s = 0.f, sqs = 0.f;
#pragma unroll
    for (int i = 0; i < 8; i++) { s += e[i]; sqs += e[i] * e[i]; }
#pragma unroll
    for (int m = 1; m < 32; m <<= 1) { s += __shfl_xor(s, m); sqs += __shfl_xor(sqs, m); }
    float mean = s * (1.f / 256.f);
    float var = sqs * (1.f / 256.f) - mean * mean;
    float inv = rsqrtf(var + 1e-5f);
    uint4 gp = *(const uint4*)(gateb + base);
    u32 gw[4] = {gp.x, gp.y, gp.z, gp.w};
    uint4 ov;
    u32* op = (u32*)&ov;
#pragma unroll
    for (int i = 0; i < 4; i++) {
        float g0 = b2f((u16)gw[i]), g1 = b2f((u16)(gw[i] >> 16));
        op[i] = (u32)f2b((e[2 * i] - mean) * inv * g0) |
                ((u32)f2b((e[2 * i + 1] - mean) * inv * g1) << 16);
    }
    *(uint4*)(gatedb + base) = ov;
}

extern "C" void kernel_launch(void* const* d_in, const int* in_sizes, int n_in,
                              void* d_out, int out_size, void* d_ws, size_t ws_size,
                              hipStream_t stream) {
    const float* x    = (const float*)d_in[0];
    const float* Wqkv = (const float*)d_in[1];
    const float* Wg   = (const float*)d_in[2];
    const float* Wp   = (const float*)d_in[3];
    const float* bp   = (const float*)d_in[4];
    float* outp   = (float*)d_out;
    float* outckv = outp + (size_t)BB * TT * HIDN;

    char* ws = (char*)d_ws;
    const size_t MB = 1024 * 1024;
    u16*   xb     = (u16*)(ws);               // 0..8
    u16*   WqkvT  = (u16*)(ws + 8 * MB);      // 8..16  [4096][1024]
    u16*   WgT    = (u16*)(ws + 16 * MB);     // 16..20 [2048][1024] (contiguous -> Wcat [6144][1024])
    u16*   WpT    = (u16*)(ws + 20 * MB);     // 20..24 [1024][2048]
    u32*   cqp    = (u32*)(ws + 24 * MB);     // 24..28 packed q table
    u32*   ckp    = (u32*)(ws + 28 * MB);     // 28..32 packed k table
    u16*   gateb  = (u16*)(ws + 32 * MB);     // 32..48 [4096][2048]
    u16*   qw     = (u16*)(ws + 48 * MB);     // 48..56 [bh][t][128] prescaled q
    u16*   kw     = (u16*)(ws + 56 * MB);     // 56..64 prescaled k
    u16*   kT     = (u16*)(ws + 64 * MB);     // 64..72 [bh][128][t] unscaled k
    u16*   vT     = (u16*)(ws + 72 * MB);     // 72..88 [bh][256][t]
    u16*   ret0b  = (u16*)(ws + 88 * MB);     // 88..104 bf16 [b][2048][2048] (after reduce_ckv)
    u16*   ret1b  = (u16*)(ws + 104 * MB);    // 104..112 bf16 [b][1024][2048]
    float* ckvp   = (float*)(ws + 88 * MB);   // 16MB partials (dead before retention writes ret0b)
    float* gtab   = (float*)(ws + 120 * MB);            // 64KB
    float* gkt    = (float*)(ws + 120 * MB + 65536);    // 2KB
    // aliases:
    u16*   gatedb = (u16*)(ws + 48 * MB);     // 16MB over qw/kw (dead after retention)

    hipLaunchKernelGGL(k_prep, dim3(16450), dim3(256), 0, stream,
                       x, Wqkv, Wg, Wp, cqp, ckp, gtab, gkt, xb, WqkvT, WgT, WpT);
    hipLaunchKernelGGL(k_gemm_qkvg8, dim3(384), dim3(512), 0, stream,
                       xb, WqkvT, cqp, ckp, gkt, qw, kw, kT, vT, gateb);
    hipLaunchKernelGGL(k_currkv, dim3(8, 16), dim3(512), 0, stream, kT, vT, gtab, ckvp);
    hipLaunchKernelGGL(k_reduce_ckv, dim3(2048), dim3(256), 0, stream, ckvp, outckv);
    hipLaunchKernelGGL(k_retention, dim3(48, 8, 2), dim3(256), 0, stream, qw, kw, vT, ret0b, ret1b);
    hipLaunchKernelGGL(k_gnorm, dim3(4096), dim3(256), 0, stream, ret0b, ret1b, gateb, gatedb);
    hipLaunchKernelGGL(k_gemm_out2, dim3(8, 32), dim3(512), 0, stream, gatedb, WpT, bp, outp);
}